// Round 3
// baseline (10107.101 us; speedup 1.0000x reference)
//
#include <hip/hip_runtime.h>
#include <math.h>

#define LEAKY(x) ((x) > 0.f ? (x) : 0.01f * (x))
static constexpr float BN_SCALE = 0.9999950000374997f;

// ---- fallback sentinel if workspace is too small (diagnostic, not a pass) --
__global__ void fill_out(float* out, int n) {
  int i = blockIdx.x * 256 + threadIdx.x;
  if (i < n) out[i] = 0.25f;
}

// ---- conv1 + leaky + maxpool2 : [1,28,28] -> [20,12,12] -------------------
__global__ void conv1_pool(const float* __restrict__ img, const float* __restrict__ w,
                           const float* __restrict__ b, float* __restrict__ out) {
  int n = blockIdx.x;
  __shared__ float simg[784];
  __shared__ float sw[500];
  __shared__ float sb[20];
  int tid = threadIdx.x;
  for (int i = tid; i < 784; i += 256) simg[i] = img[(size_t)n * 784 + i];
  for (int i = tid; i < 500; i += 256) sw[i] = w[i];
  if (tid < 20) sb[tid] = b[tid];
  __syncthreads();
  for (int o = tid; o < 2880; o += 256) {
    int c = o / 144, rem = o % 144, py = rem / 12, px = rem % 12;
    float m = -1e30f;
    for (int dy = 0; dy < 2; ++dy)
      for (int dx = 0; dx < 2; ++dx) {
        int y = py * 2 + dy, x = px * 2 + dx;
        float acc = sb[c];
        const float* wc = &sw[c * 25];
        #pragma unroll
        for (int ky = 0; ky < 5; ++ky)
          #pragma unroll
          for (int kx = 0; kx < 5; ++kx)
            acc += simg[(y + ky) * 28 + (x + kx)] * wc[ky * 5 + kx];
        acc = LEAKY(acc);
        m = fmaxf(m, acc);
      }
    out[(size_t)n * 2880 + o] = m;
  }
}

// ---- conv2 + leaky + maxpool2 : [20,12,12] -> [50,4,4]=800 ----------------
// fp32 weights (100KB) don't fit LDS: stage 10 input channels at a time.
// Each thread owns up to 4 pooled outputs; 4 pre-pool taps in registers.
__global__ void conv2_pool(const float* __restrict__ h1, const float* __restrict__ w,
                           const float* __restrict__ b, float* __restrict__ out) {
  int n = blockIdx.x;
  __shared__ float sin_[2880];
  __shared__ float sw[12500];  // 50 oc x 10 ic x 25
  __shared__ float sb[50];
  int tid = threadIdx.x;
  for (int i = tid; i < 2880; i += 256) sin_[i] = h1[(size_t)n * 2880 + i];
  if (tid < 50) sb[tid] = b[tid];
  __syncthreads();
  float acc[4][4];  // [group][pool tap]
  #pragma unroll
  for (int g = 0; g < 4; ++g) {
    int o = tid + 256 * g;
    if (o < 800) {
      float bb = sb[o / 16];
      #pragma unroll
      for (int p = 0; p < 4; ++p) acc[g][p] = bb;
    }
  }
  for (int chunk = 0; chunk < 2; ++chunk) {
    __syncthreads();
    for (int i = tid; i < 12500; i += 256) {
      int oc = i / 250, rem = i % 250;
      sw[i] = w[(size_t)oc * 500 + chunk * 250 + rem];
    }
    __syncthreads();
    #pragma unroll
    for (int g = 0; g < 4; ++g) {
      int o = tid + 256 * g;
      if (o >= 800) continue;
      int c = o / 16, rem = o % 16, py = rem / 4, px = rem % 4;
      #pragma unroll
      for (int dy = 0; dy < 2; ++dy)
        #pragma unroll
        for (int dx = 0; dx < 2; ++dx) {
          int y = py * 2 + dy, x = px * 2 + dx;
          float a = 0.f;
          for (int icl = 0; icl < 10; ++icl) {
            int ic = chunk * 10 + icl;
            const float* ip = &sin_[ic * 144 + y * 12 + x];
            const float* wp = &sw[c * 250 + icl * 25];
            #pragma unroll
            for (int ky = 0; ky < 5; ++ky)
              #pragma unroll
              for (int kx = 0; kx < 5; ++kx)
                a += ip[ky * 12 + kx] * wp[ky * 5 + kx];
          }
          acc[g][dy * 2 + dx] += a;
        }
    }
  }
  #pragma unroll
  for (int g = 0; g < 4; ++g) {
    int o = tid + 256 * g;
    if (o >= 800) continue;
    float m = -1e30f;
    #pragma unroll
    for (int p = 0; p < 4; ++p) {
      float v = LEAKY(acc[g][p]);
      m = fmaxf(m, v);
    }
    out[(size_t)n * 800 + o] = m;
  }
}

// ---------------- generic tiled GEMM: C = epi(A[M,K] @ B[N,K]^T + bias) ----
enum { EPI_NONE = 0, EPI_LEAKY = 1, EPI_LEAKY_BN = 2, EPI_TANH = 3, EPI_EUCLID = 4 };

template <int EPI>
__global__ void gemm_nt(const float* __restrict__ A, const float* __restrict__ B,
                        const float* __restrict__ bias, float* __restrict__ C,
                        int M, int N, int Kd,
                        const float* __restrict__ e1, const float* __restrict__ e2) {
  __shared__ float As[16][64];
  __shared__ float Bs[16][64];
  int tid = threadIdx.x;
  int tx = tid & 15, ty = tid >> 4;
  int bm = blockIdx.y * 64, bn = blockIdx.x * 64;
  int row_l = tid >> 2;
  int kq = (tid & 3) * 4;
  float acc[4][4] = {};
  for (int k0 = 0; k0 < Kd; k0 += 16) {
    {
      int m = bm + row_l;
      #pragma unroll
      for (int i = 0; i < 4; ++i) {
        int k = k0 + kq + i;
        As[kq + i][row_l] = (m < M && k < Kd) ? A[(size_t)m * Kd + k] : 0.f;
      }
    }
    {
      int n = bn + row_l;
      #pragma unroll
      for (int i = 0; i < 4; ++i) {
        int k = k0 + kq + i;
        Bs[kq + i][row_l] = (n < N && k < Kd) ? B[(size_t)n * Kd + k] : 0.f;
      }
    }
    __syncthreads();
    #pragma unroll
    for (int kk = 0; kk < 16; ++kk) {
      float av[4], bv[4];
      #pragma unroll
      for (int i = 0; i < 4; ++i) av[i] = As[kk][ty * 4 + i];
      #pragma unroll
      for (int j = 0; j < 4; ++j) bv[j] = Bs[kk][tx * 4 + j];
      #pragma unroll
      for (int i = 0; i < 4; ++i)
        #pragma unroll
        for (int j = 0; j < 4; ++j) acc[i][j] += av[i] * bv[j];
    }
    __syncthreads();
  }
  #pragma unroll
  for (int i = 0; i < 4; ++i) {
    int m = bm + ty * 4 + i;
    if (m >= M) continue;
    #pragma unroll
    for (int j = 0; j < 4; ++j) {
      int n = bn + tx * 4 + j;
      if (n >= N) continue;
      float v = acc[i][j];
      if (EPI == EPI_EUCLID) {
        v = e1[m] + e2[n] - 2.f * v;
        v = sqrtf(fmaxf(v, 0.f));
      } else {
        if (bias) v += bias[n];
        if (EPI == EPI_LEAKY) v = LEAKY(v);
        else if (EPI == EPI_LEAKY_BN) { v = LEAKY(v); v *= BN_SCALE; }
        else if (EPI == EPI_TANH) v = tanhf(v);
      }
      C[(size_t)m * N + n] = v;
    }
  }
}

// ---- GEMM NN with residual: C = A[M,K] @ B[K,N] + R (C==R is safe) --------
__global__ void gemm_nn_res(const float* __restrict__ A, const float* __restrict__ B,
                            const float* __restrict__ R, float* __restrict__ C,
                            int M, int N, int Kd) {
  __shared__ float As[16][64];
  __shared__ float Bs[16][64];
  int tid = threadIdx.x;
  int tx = tid & 15, ty = tid >> 4;
  int bm = blockIdx.y * 64, bn = blockIdx.x * 64;
  int row_l = tid >> 2;
  int kq = (tid & 3) * 4;
  int kk_l = tid >> 4, nn4 = (tid & 15) * 4;
  float acc[4][4] = {};
  for (int k0 = 0; k0 < Kd; k0 += 16) {
    {
      int m = bm + row_l;
      #pragma unroll
      for (int i = 0; i < 4; ++i) {
        int k = k0 + kq + i;
        As[kq + i][row_l] = (m < M && k < Kd) ? A[(size_t)m * Kd + k] : 0.f;
      }
    }
    {
      int k = k0 + kk_l;
      #pragma unroll
      for (int i = 0; i < 4; ++i) {
        int n = bn + nn4 + i;
        Bs[kk_l][nn4 + i] = (k < Kd && n < N) ? B[(size_t)k * N + n] : 0.f;
      }
    }
    __syncthreads();
    #pragma unroll
    for (int kk = 0; kk < 16; ++kk) {
      float av[4], bv[4];
      #pragma unroll
      for (int i = 0; i < 4; ++i) av[i] = As[kk][ty * 4 + i];
      #pragma unroll
      for (int j = 0; j < 4; ++j) bv[j] = Bs[kk][tx * 4 + j];
      #pragma unroll
      for (int i = 0; i < 4; ++i)
        #pragma unroll
        for (int j = 0; j < 4; ++j) acc[i][j] += av[i] * bv[j];
    }
    __syncthreads();
  }
  #pragma unroll
  for (int i = 0; i < 4; ++i) {
    int m = bm + ty * 4 + i;
    if (m >= M) continue;
    #pragma unroll
    for (int j = 0; j < 4; ++j) {
      int n = bn + tx * 4 + j;
      if (n >= N) continue;
      C[(size_t)m * N + n] = acc[i][j] + R[(size_t)m * N + n];
    }
  }
}

// ---- small TN GEMM: C[i,j] = sum_k A[k,i] * B[k,j]  (A,B: [Kd x 128]) ------
__global__ void gemm_tn(const float* __restrict__ A, const float* __restrict__ B,
                        float* __restrict__ C, int Kd, int M, int N) {
  int j = blockIdx.x * 16 + (threadIdx.x & 15);
  int i = blockIdx.y * 16 + (threadIdx.x >> 4);
  if (i >= M || j >= N) return;
  float acc = 0.f;
  for (int k = 0; k < Kd; ++k) acc += A[(size_t)k * M + i] * B[(size_t)k * N + j];
  C[(size_t)i * N + j] = acc;
}

// ---- column softmax (axis 0) in-place, M rows x N cols --------------------
__global__ void softmax_col(float* __restrict__ S, int M, int N) {
  int t = threadIdx.x;
  int cl = t & 63, g = t >> 6;
  int c = blockIdx.x * 64 + cl;
  __shared__ float red[4][64];
  float m = -1e30f;
  for (int r = g; r < M; r += 4) m = fmaxf(m, S[(size_t)r * N + c]);
  red[g][cl] = m;
  __syncthreads();
  m = fmaxf(fmaxf(red[0][cl], red[1][cl]), fmaxf(red[2][cl], red[3][cl]));
  float sum = 0.f;
  for (int r = g; r < M; r += 4) sum += expf(S[(size_t)r * N + c] - m);
  __syncthreads();
  red[g][cl] = sum;
  __syncthreads();
  sum = red[0][cl] + red[1][cl] + red[2][cl] + red[3][cl];
  float inv = 1.f / sum;
  for (int r = g; r < M; r += 4) {
    size_t i = (size_t)r * N + c;
    S[i] = expf(S[i] - m) * inv;
  }
}

// ---- row squared-norms ----------------------------------------------------
__global__ void row_norm(const float* __restrict__ X, float* __restrict__ out, int Kd) {
  int r = blockIdx.x;
  int t = threadIdx.x;
  float s = 0.f;
  for (int k = t; k < Kd; k += 64) { float v = X[(size_t)r * Kd + k]; s += v * v; }
  for (int off = 32; off; off >>= 1) s += __shfl_down(s, off);
  if (t == 0) out[r] = s;
}

// ---- mask scores s[k] = sum_h A3[h,k]*w4[h] + b4 --------------------------
__global__ void mask_score(const float* __restrict__ A3, const float* __restrict__ w4,
                           const float* __restrict__ b4, float* __restrict__ s) {
  int k = blockIdx.x * 256 + threadIdx.x;
  float acc = b4[0];
  for (int h = 0; h < 128; ++h) acc += A3[(size_t)h * 2048 + k] * w4[h];
  s[k] = acc;
}

// ---- stable descending-argsort rank -> top-S indices ----------------------
__global__ void topk_rank(const float* __restrict__ s, int* __restrict__ idx, int K, int S) {
  int j = blockIdx.x * 256 + threadIdx.x;
  if (j >= K) return;
  float sj = s[j];
  int rank = 0;
  for (int i = 0; i < K; ++i) {
    float si = s[i];
    rank += (si > sj) || (si == sj && i < j);
  }
  if (rank < S) idx[rank] = j;
}

// ---- build cat = [B_dt | softmax(aff_s[:,idx],axis=1)] --------------------
__global__ void build_cat(const float* __restrict__ Bdt, const float* __restrict__ affs,
                          const int* __restrict__ idx, float* __restrict__ cat) {
  int r = blockIdx.x, t = threadIdx.x;
  __shared__ float vals[256];
  __shared__ float red[256];
  float v = -1e30f;
  if (t < 204) {
    int ix = idx[t];
    ix = ix < 0 ? 0 : (ix > 2047 ? 2047 : ix);  // fault guard vs poison
    v = affs[(size_t)r * 2048 + ix];
  }
  vals[t] = v;
  red[t] = v;
  __syncthreads();
  for (int off = 128; off; off >>= 1) { if (t < off) red[t] = fmaxf(red[t], red[t + off]); __syncthreads(); }
  float m = red[0];
  __syncthreads();
  float e = (t < 204) ? expf(vals[t] - m) : 0.f;
  red[t] = e;
  __syncthreads();
  for (int off = 128; off; off >>= 1) { if (t < off) red[t] += red[t + off]; __syncthreads(); }
  float inv = 1.f / red[0];
  cat[(size_t)r * 460 + t] = Bdt[(size_t)r * 256 + t];
  if (t < 204) cat[(size_t)r * 460 + 256 + t] = e * inv;
}

// ---- a = leaky((AV*AU) @ aww.T + awb) -------------------------------------
__global__ void attn_gate(const float* __restrict__ AV, const float* __restrict__ AU,
                          const float* __restrict__ aww, const float* __restrict__ awb,
                          float* __restrict__ a, int n) {
  int r = blockIdx.x * 256 + threadIdx.x;
  if (r >= n) return;
  float acc = awb[0];
  for (int d = 0; d < 128; ++d) acc += AV[(size_t)r * 128 + d] * AU[(size_t)r * 128 + d] * aww[d];
  a[r] = LEAKY(acc);
}

// ---- 1-D softmax (single block); writes y and optionally y2 ---------------
__global__ void softmax_vec(const float* __restrict__ x, float* __restrict__ y,
                            float* __restrict__ y2, int n) {
  __shared__ float red[256];
  int t = threadIdx.x;
  float m = -1e30f;
  for (int i = t; i < n; i += 256) m = fmaxf(m, x[i]);
  red[t] = m;
  __syncthreads();
  for (int off = 128; off; off >>= 1) { if (t < off) red[t] = fmaxf(red[t], red[t + off]); __syncthreads(); }
  m = red[0];
  __syncthreads();
  float s = 0.f;
  for (int i = t; i < n; i += 256) s += expf(x[i] - m);
  red[t] = s;
  __syncthreads();
  for (int off = 128; off; off >>= 1) { if (t < off) red[t] += red[t + off]; __syncthreads(); }
  float inv = 1.f / red[0];
  for (int i = t; i < n; i += 256) {
    float v = expf(x[i] - m) * inv;
    y[i] = v;
    if (y2) y2[i] = v;
  }
}

// ---- out[c] = sum_i w[i] * H[i,c], C=256 ----------------------------------
__global__ void weighted_colsum(const float* __restrict__ w, const float* __restrict__ H,
                                float* __restrict__ out, int n) {
  int t = threadIdx.x;
  int c = t & 255, g = t >> 8;
  __shared__ float red[4][256];
  float s = 0.f;
  for (int r = g; r < n; r += 4) s += w[r] * H[(size_t)r * 256 + c];
  red[g][c] = s;
  __syncthreads();
  if (g == 0) out[c] = red[0][c] + red[1][c] + red[2][c] + red[3][c];
}

// ---- small gemv: out[o] = act(sum_k x[k]*W[o,k] + b[o]) -------------------
__global__ void gemv_act(const float* __restrict__ x, const float* __restrict__ W,
                         const float* __restrict__ b, float* __restrict__ out,
                         int O, int Kd, int act) {
  int o = blockIdx.x * blockDim.x + threadIdx.x;
  if (o >= O) return;
  float acc = b ? b[o] : 0.f;
  for (int k = 0; k < Kd; ++k) acc += x[k] * W[(size_t)o * Kd + k];
  if (act == 1) acc = LEAKY(acc);
  out[o] = acc;
}

// ---- cat2 = [B_fuse | tile(M1)] -------------------------------------------
__global__ void build_cat2(const float* __restrict__ Bf, const float* __restrict__ M1,
                           float* __restrict__ cat2) {
  int r = blockIdx.x, t = threadIdx.x; // 512 threads
  cat2[(size_t)r * 512 + t] = (t < 256) ? Bf[(size_t)r * 256 + t] : M1[t - 256];
}

// ---- final head: bvec -> semb -> cls -> Y ---------------------------------
__global__ void final_head(const float* __restrict__ AH2, const float* __restrict__ embw,
                           const float* __restrict__ embb, const float* __restrict__ sembw,
                           const float* __restrict__ sembb, const float* __restrict__ clsw,
                           const float* __restrict__ clsb, float* __restrict__ Yout) {
  __shared__ float bvec[512];
  __shared__ float red[512];
  int t = threadIdx.x; // 512
  float acc = embb[t];
  for (int c = 0; c < 256; ++c) acc += AH2[c] * embw[(size_t)t * 256 + c];
  bvec[t] = LEAKY(acc);
  __syncthreads();
  float p = 0.f;
  if (t < 256) {
    float a2 = sembb[t];
    for (int c = 0; c < 512; ++c) a2 += bvec[c] * sembw[(size_t)t * 512 + c];
    a2 = LEAKY(a2);
    p = a2 * clsw[t];
  }
  red[t] = p;
  __syncthreads();
  for (int off = 256; off; off >>= 1) { if (t < off) red[t] += red[t + off]; __syncthreads(); }
  if (t == 0) {
    float y = red[0] + clsb[0];
    y = 1.f / (1.f + expf(-y));
    y = fminf(fmaxf(y, 1e-5f), 1.f - 1e-5f);
    Yout[0] = y;
  }
}

extern "C" void kernel_launch(void* const* d_in, const int* in_sizes, int n_in,
                              void* d_out, int out_size, void* d_ws, size_t ws_size,
                              hipStream_t stream) {
  auto IN = [&](int i) { return (const float*)d_in[i]; };
  (void)n_in; (void)in_sizes; (void)out_size;

  const int S = 204;
  float* out_f = (float*)d_out;  // out[0]=Y, out[1..2048]=A

  // ---- workspace layout: 16,280,576 floats = 62.1 MB ----
  float* W = (float*)d_ws;
  size_t off = 0;
  auto F = [&](size_t n) { float* p = W + off; off += n; return p; };

  float* dt    = F((size_t)4096 * 256);   // B_dt rows 0..2047, KB_dt rows 2048..4095
  float* Xs    = F((size_t)2048 * 256);
  float* Ks    = F((size_t)2048 * 256);
  float* X1    = F((size_t)2048 * 128);
  float* X2    = F((size_t)2048 * 128);
  float* X3s   = F((size_t)2048 * 256);   // skip1/2 X3; later aliased as Bfuse
  float* aff   = F((size_t)2048 * 2048);  // euclid out; skip3 output IN-PLACE
  float* AV    = F((size_t)2048 * 128);
  float* AU    = F((size_t)2048 * 128);
  float* Mm    = F((size_t)128 * 128);
  float* svec  = F(2048);
  int*   idxb  = (int*)F(256);
  float* avec  = F(2048);
  float* Awv   = F(2048);
  float* AH    = F(256);
  float* M1v   = F(256);
  float* AH2   = F(256);
  float* nx    = F(2048);
  float* ny    = F(2048);
  float* pool  = F((size_t)8388608);      // 32 MB phase-shared pool

  const size_t NEED_BYTES = off * 4;
  if (ws_size < NEED_BYTES) {
    fill_out<<<9, 256, 0, stream>>>(out_f, 2049);
    return;
  }

  // pool members (phase-disjoint)
  float* h1   = pool;                 // conv phase: 2048*2880
  float* h2h  = pool + 5898240;       // conv phase: 2048*800
  float* Smat = pool;                 // skip phases: 2048*2048
  float* X3b  = pool + 4194304;       // skip3 only: 2048*2048
  float* A3   = pool;                 // mask phase: 128*2048
  float* cat  = pool;                 // fuse phase: 2048*460
  float* cat2 = pool + 942080;        // 2048*512
  float* Hbuf = pool + 1990656;       // 2048*256

  float* Bfuse = X3s;                 // X3s dead after skip2

  // ---- data_transform for B (g=0) and KB (g=1) ----
  for (int g = 0; g < 2; ++g) {
    conv1_pool<<<2048, 256, 0, stream>>>(IN(g), IN(2), IN(3), h1);
    conv2_pool<<<2048, 256, 0, stream>>>(h1, IN(4), IN(5), h2h);
    gemm_nt<EPI_LEAKY><<<dim3(4, 32), 256, 0, stream>>>(
        h2h, IN(6), IN(7), dt + (size_t)g * 2048 * 256, 2048, 256, 800, nullptr, nullptr);
  }
  float* B_dt = dt;
  float* KB_dt = dt + (size_t)2048 * 256;

  // ---- skip_block 1 (B_dt -> Xs) and 2 (KB_dt -> Ks) ----
  for (int g = 0; g < 2; ++g) {
    float* Xin = g ? KB_dt : B_dt;
    float* Xout = g ? Ks : Xs;
    int wi = g ? 14 : 8;
    gemm_nt<EPI_LEAKY_BN><<<dim3(2, 32), 256, 0, stream>>>(
        Xin, IN(wi + 0), IN(wi + 1), X1, 2048, 128, 256, nullptr, nullptr);
    gemm_nt<EPI_LEAKY_BN><<<dim3(2, 32), 256, 0, stream>>>(
        Xin, IN(wi + 2), IN(wi + 3), X2, 2048, 128, 256, nullptr, nullptr);
    gemm_nt<EPI_LEAKY_BN><<<dim3(4, 32), 256, 0, stream>>>(
        Xin, IN(wi + 4), IN(wi + 5), X3s, 2048, 256, 256, nullptr, nullptr);
    gemm_nt<EPI_NONE><<<dim3(32, 32), 256, 0, stream>>>(
        X1, X2, nullptr, Smat, 2048, 2048, 128, nullptr, nullptr);
    softmax_col<<<32, 256, 0, stream>>>(Smat, 2048, 2048);
    gemm_nn_res<<<dim3(4, 32), 256, 0, stream>>>(Smat, X3s, Xin, Xout, 2048, 256, 2048);
  }

  // ---- euclid -> aff ----
  row_norm<<<2048, 64, 0, stream>>>(Xs, nx, 256);
  row_norm<<<2048, 64, 0, stream>>>(Ks, ny, 256);
  gemm_nt<EPI_EUCLID><<<dim3(32, 32), 256, 0, stream>>>(
      Xs, Ks, nullptr, aff, 2048, 2048, 256, nx, ny);

  // ---- skip_block 3 (aff -> aff in-place), dd = 2048 ----
  gemm_nt<EPI_LEAKY_BN><<<dim3(2, 32), 256, 0, stream>>>(
      aff, IN(20), IN(21), X1, 2048, 128, 2048, nullptr, nullptr);
  gemm_nt<EPI_LEAKY_BN><<<dim3(2, 32), 256, 0, stream>>>(
      aff, IN(22), IN(23), X2, 2048, 128, 2048, nullptr, nullptr);
  gemm_nt<EPI_LEAKY_BN><<<dim3(32, 32), 256, 0, stream>>>(
      aff, IN(24), IN(25), X3b, 2048, 2048, 2048, nullptr, nullptr);
  gemm_nt<EPI_NONE><<<dim3(32, 32), 256, 0, stream>>>(
      X1, X2, nullptr, Smat, 2048, 2048, 128, nullptr, nullptr);
  softmax_col<<<32, 256, 0, stream>>>(Smat, 2048, 2048);
  gemm_nn_res<<<dim3(32, 32), 256, 0, stream>>>(Smat, X3b, aff, aff, 2048, 2048, 2048);
  float* aff_s = aff;

  // ---- mask_scores -> top-S idx ----
  gemm_nt<EPI_LEAKY><<<dim3(2, 32), 256, 0, stream>>>(
      aff_s, IN(26), IN(27), X1, 2048, 128, 2048, nullptr, nullptr);
  gemm_nt<EPI_TANH><<<dim3(2, 32), 256, 0, stream>>>(
      aff_s, IN(28), IN(29), X2, 2048, 128, 2048, nullptr, nullptr);
  gemm_tn<<<dim3(8, 8), 256, 0, stream>>>(X1, X2, Mm, 2048, 128, 128);
  gemm_nt<EPI_LEAKY><<<dim3(32, 2), 256, 0, stream>>>(
      Mm, IN(30), IN(31), A3, 128, 2048, 128, nullptr, nullptr);
  mask_score<<<8, 256, 0, stream>>>(A3, IN(32), IN(33), svec);
  topk_rank<<<8, 256, 0, stream>>>(svec, idxb, 2048, S);

  // ---- B_bag + concat + fuse ----
  build_cat<<<2048, 256, 0, stream>>>(B_dt, aff_s, idxb, cat);
  gemm_nt<EPI_LEAKY><<<dim3(4, 32), 256, 0, stream>>>(
      cat, IN(34), IN(35), Bfuse, 2048, 256, 460, nullptr, nullptr);

  // ---- attention 1 ----
  gemm_nt<EPI_LEAKY><<<dim3(4, 32), 256, 0, stream>>>(
      Bfuse, IN(36), IN(37), Hbuf, 2048, 256, 256, nullptr, nullptr);
  gemm_nt<EPI_TANH><<<dim3(2, 32), 256, 0, stream>>>(
      Hbuf, IN(38), IN(39), AV, 2048, 128, 256, nullptr, nullptr);
  gemm_nt<EPI_LEAKY><<<dim3(2, 32), 256, 0, stream>>>(
      Hbuf, IN(40), IN(41), AU, 2048, 128, 256, nullptr, nullptr);
  attn_gate<<<8, 256, 0, stream>>>(AV, AU, IN(42), IN(43), avec, 2048);
  softmax_vec<<<1, 256, 0, stream>>>(avec, Awv, nullptr, 2048);
  weighted_colsum<<<1, 1024, 0, stream>>>(Awv, Hbuf, AH, 2048);
  gemv_act<<<1, 256, 0, stream>>>(AH, IN(44), IN(45), M1v, 256, 256, 1);
  build_cat2<<<2048, 512, 0, stream>>>(Bfuse, M1v, cat2);

  // ---- attention 2 (A -> output) ----
  gemm_nt<EPI_LEAKY><<<dim3(4, 32), 256, 0, stream>>>(
      cat2, IN(46), IN(47), Hbuf, 2048, 256, 512, nullptr, nullptr);
  gemm_nt<EPI_TANH><<<dim3(2, 32), 256, 0, stream>>>(
      Hbuf, IN(48), IN(49), AV, 2048, 128, 256, nullptr, nullptr);
  gemm_nt<EPI_LEAKY><<<dim3(2, 32), 256, 0, stream>>>(
      Hbuf, IN(50), IN(51), AU, 2048, 128, 256, nullptr, nullptr);
  attn_gate<<<8, 256, 0, stream>>>(AV, AU, IN(52), IN(53), avec, 2048);
  softmax_vec<<<1, 256, 0, stream>>>(avec, Awv, out_f + 1, 2048);
  weighted_colsum<<<1, 1024, 0, stream>>>(Awv, Hbuf, AH2, 2048);

  // ---- final head -> Y ----
  final_head<<<1, 512, 0, stream>>>(AH2, IN(54), IN(55), IN(56), IN(57),
                                    IN(58), IN(59), out_f);
}

// Round 4
// 4802.012 us; speedup vs baseline: 2.1048x; 2.1048x over previous
//
#include <hip/hip_runtime.h>
#include <math.h>

#define LEAKY(x) ((x) > 0.f ? (x) : 0.01f * (x))
static constexpr float BN_SCALE = 0.9999950000374997f;

// ---- fallback sentinel if workspace is too small (diagnostic, not a pass) --
__global__ void fill_out(float* out, int n) {
  int i = blockIdx.x * 256 + threadIdx.x;
  if (i < n) out[i] = 0.25f;
}

// ---- conv1 + leaky + maxpool2 : [1,28,28] -> [20,12,12] -------------------
// 6x6 register patch per pooled output; 4 pre-pool taps share it.
__global__ void conv1_pool(const float* __restrict__ img, const float* __restrict__ w,
                           const float* __restrict__ b, float* __restrict__ out) {
  int n = blockIdx.x;
  __shared__ float simg[784];
  __shared__ float sw[500];
  __shared__ float sb[20];
  int tid = threadIdx.x;
  for (int i = tid; i < 784; i += 256) simg[i] = img[(size_t)n * 784 + i];
  for (int i = tid; i < 500; i += 256) sw[i] = w[i];
  if (tid < 20) sb[tid] = b[tid];
  __syncthreads();
  for (int o = tid; o < 2880; o += 256) {
    int c = o / 144, rem = o % 144, py = rem / 12, px = rem % 12;
    int y0 = py * 2, x0 = px * 2;
    float p[6][6];
    #pragma unroll
    for (int yy = 0; yy < 6; ++yy)
      #pragma unroll
      for (int xx = 0; xx < 6; ++xx)
        p[yy][xx] = simg[(y0 + yy) * 28 + x0 + xx];
    float t0 = sb[c], t1 = t0, t2 = t0, t3 = t0;
    const float* wc = &sw[c * 25];
    #pragma unroll
    for (int ky = 0; ky < 5; ++ky)
      #pragma unroll
      for (int kx = 0; kx < 5; ++kx) {
        float wv = wc[ky * 5 + kx];
        t0 += p[ky][kx] * wv;
        t1 += p[ky][kx + 1] * wv;
        t2 += p[ky + 1][kx] * wv;
        t3 += p[ky + 1][kx + 1] * wv;
      }
    t0 = LEAKY(t0); t1 = LEAKY(t1); t2 = LEAKY(t2); t3 = LEAKY(t3);
    out[(size_t)n * 2880 + o] = fmaxf(fmaxf(t0, t1), fmaxf(t2, t3));
  }
}

// ---- conv2 + leaky + maxpool2 : [20,12,12] -> [50,4,4]=800 ----------------
// ic chunked 4x5 (25KB weight LDS -> 4 blocks/CU); 6x6 register patch reuse.
__global__ void conv2_pool(const float* __restrict__ h1, const float* __restrict__ w,
                           const float* __restrict__ b, float* __restrict__ out) {
  int n = blockIdx.x;
  __shared__ float sin_[2880];
  __shared__ float sw[6250];   // 50 oc x 5 ic x 25
  __shared__ float sb[50];
  int tid = threadIdx.x;
  for (int i = tid; i < 2880; i += 256) sin_[i] = h1[(size_t)n * 2880 + i];
  if (tid < 50) sb[tid] = b[tid];
  float acc[4][4];
  #pragma unroll
  for (int g = 0; g < 4; ++g) {
    int o = tid + 256 * g;
    float bb = (o < 800) ? b[o / 16] : 0.f;
    #pragma unroll
    for (int p = 0; p < 4; ++p) acc[g][p] = bb;
  }
  for (int chunk = 0; chunk < 4; ++chunk) {
    __syncthreads();
    for (int i = tid; i < 6250; i += 256) {
      int oc = i / 125, rem = i % 125;
      sw[i] = w[(size_t)oc * 500 + chunk * 125 + rem];
    }
    __syncthreads();
    #pragma unroll
    for (int g = 0; g < 4; ++g) {
      int o = tid + 256 * g;
      if (o >= 800) continue;
      int c = o / 16, rem = o % 16, py = rem / 4, px = rem % 4;
      int y0 = py * 2, x0 = px * 2;
      float t0 = 0.f, t1 = 0.f, t2 = 0.f, t3 = 0.f;
      #pragma unroll
      for (int icl = 0; icl < 5; ++icl) {
        int ic = chunk * 5 + icl;
        float p[6][6];
        #pragma unroll
        for (int yy = 0; yy < 6; ++yy)
          #pragma unroll
          for (int xx = 0; xx < 6; ++xx)
            p[yy][xx] = sin_[ic * 144 + (y0 + yy) * 12 + x0 + xx];
        const float* wp = &sw[c * 125 + icl * 25];
        #pragma unroll
        for (int ky = 0; ky < 5; ++ky)
          #pragma unroll
          for (int kx = 0; kx < 5; ++kx) {
            float wv = wp[ky * 5 + kx];
            t0 += p[ky][kx] * wv;
            t1 += p[ky][kx + 1] * wv;
            t2 += p[ky + 1][kx] * wv;
            t3 += p[ky + 1][kx + 1] * wv;
          }
      }
      acc[g][0] += t0; acc[g][1] += t1; acc[g][2] += t2; acc[g][3] += t3;
    }
  }
  #pragma unroll
  for (int g = 0; g < 4; ++g) {
    int o = tid + 256 * g;
    if (o >= 800) continue;
    float m = -1e30f;
    #pragma unroll
    for (int p = 0; p < 4; ++p) {
      float v = LEAKY(acc[g][p]);
      m = fmaxf(m, v);
    }
    out[(size_t)n * 800 + o] = m;
  }
}

// ---------------- epilogue kinds -------------------------------------------
enum { EPI_NONE = 0, EPI_LEAKY = 1, EPI_LEAKY_BN = 2, EPI_TANH = 3, EPI_EUCLID = 4 };

// ---- 128x128-tile fp32 GEMM NT: C = epi(A[M,K] @ B[N,K]^T + bias) ---------
// requires M%128==0 (grid.y=M/128), N%128==0, K%16==0
template <int EPI>
__launch_bounds__(256)
__global__ void gemm128_nt(const float* __restrict__ A, const float* __restrict__ B,
                           const float* __restrict__ bias, float* __restrict__ C,
                           int M, int N, int Kd,
                           const float* __restrict__ e1, const float* __restrict__ e2) {
  __shared__ float As[16][128];
  __shared__ float Bs[16][128];
  int tid = threadIdx.x;
  int tx = tid & 15, ty = tid >> 4;
  int bm = blockIdx.y * 128, bn = blockIdx.x * 128;
  int arow = tid >> 1;
  int akof = (tid & 1) * 8;
  float acc[8][8] = {};
  for (int k0 = 0; k0 < Kd; k0 += 16) {
    const float* ap = &A[(size_t)(bm + arow) * Kd + k0 + akof];
    const float* bp = &B[(size_t)(bn + arow) * Kd + k0 + akof];
    float av8[8], bv8[8];
    #pragma unroll
    for (int i = 0; i < 8; ++i) av8[i] = ap[i];
    #pragma unroll
    for (int i = 0; i < 8; ++i) bv8[i] = bp[i];
    __syncthreads();
    #pragma unroll
    for (int i = 0; i < 8; ++i) As[akof + i][arow] = av8[i];
    #pragma unroll
    for (int i = 0; i < 8; ++i) Bs[akof + i][arow] = bv8[i];
    __syncthreads();
    #pragma unroll
    for (int kk = 0; kk < 16; ++kk) {
      float a[8], b[8];
      #pragma unroll
      for (int i = 0; i < 8; ++i) a[i] = As[kk][ty * 8 + i];
      #pragma unroll
      for (int j = 0; j < 8; ++j) b[j] = Bs[kk][tx * 8 + j];
      #pragma unroll
      for (int i = 0; i < 8; ++i)
        #pragma unroll
        for (int j = 0; j < 8; ++j) acc[i][j] += a[i] * b[j];
    }
  }
  #pragma unroll
  for (int i = 0; i < 8; ++i) {
    int m = bm + ty * 8 + i;
    #pragma unroll
    for (int j = 0; j < 8; ++j) {
      int n = bn + tx * 8 + j;
      float v = acc[i][j];
      if (EPI == EPI_EUCLID) {
        v = e1[m] + e2[n] - 2.f * v;
        v = sqrtf(fmaxf(v, 0.f));
      } else {
        if (bias) v += bias[n];
        if (EPI == EPI_LEAKY) v = LEAKY(v);
        else if (EPI == EPI_LEAKY_BN) { v = LEAKY(v); v *= BN_SCALE; }
        else if (EPI == EPI_TANH) v = tanhf(v);
      }
      C[(size_t)m * N + n] = v;
    }
  }
}

// ---- 128x128-tile fp32 GEMM NN + residual: C = A[M,K]@B[K,N] + R ----------
// (C==R safe: each element read only by its owner thread). Same divisibility.
__launch_bounds__(256)
__global__ void gemm128_nn_res(const float* __restrict__ A, const float* __restrict__ B,
                               const float* __restrict__ R, float* __restrict__ C,
                               int M, int N, int Kd) {
  __shared__ float As[16][128];
  __shared__ float Bs[16][128];
  int tid = threadIdx.x;
  int tx = tid & 15, ty = tid >> 4;
  int bm = blockIdx.y * 128, bn = blockIdx.x * 128;
  int arow = tid >> 1;
  int akof = (tid & 1) * 8;
  int bkrow = tid >> 4;          // 0..15
  int bnof = (tid & 15) * 8;     // 0..120
  float acc[8][8] = {};
  for (int k0 = 0; k0 < Kd; k0 += 16) {
    const float* ap = &A[(size_t)(bm + arow) * Kd + k0 + akof];
    const float* bp = &B[(size_t)(k0 + bkrow) * N + bn + bnof];
    float av8[8], bv8[8];
    #pragma unroll
    for (int i = 0; i < 8; ++i) av8[i] = ap[i];
    #pragma unroll
    for (int i = 0; i < 8; ++i) bv8[i] = bp[i];
    __syncthreads();
    #pragma unroll
    for (int i = 0; i < 8; ++i) As[akof + i][arow] = av8[i];
    #pragma unroll
    for (int i = 0; i < 8; ++i) Bs[bkrow][bnof + i] = bv8[i];
    __syncthreads();
    #pragma unroll
    for (int kk = 0; kk < 16; ++kk) {
      float a[8], b[8];
      #pragma unroll
      for (int i = 0; i < 8; ++i) a[i] = As[kk][ty * 8 + i];
      #pragma unroll
      for (int j = 0; j < 8; ++j) b[j] = Bs[kk][tx * 8 + j];
      #pragma unroll
      for (int i = 0; i < 8; ++i)
        #pragma unroll
        for (int j = 0; j < 8; ++j) acc[i][j] += a[i] * b[j];
    }
  }
  #pragma unroll
  for (int i = 0; i < 8; ++i) {
    int m = bm + ty * 8 + i;
    #pragma unroll
    for (int j = 0; j < 8; ++j) {
      int n = bn + tx * 8 + j;
      C[(size_t)m * N + n] = acc[i][j] + R[(size_t)m * N + n];
    }
  }
}

// ---- generic 64-tile GEMM NT (for K=460 fuse) -----------------------------
template <int EPI>
__global__ void gemm_nt(const float* __restrict__ A, const float* __restrict__ B,
                        const float* __restrict__ bias, float* __restrict__ C,
                        int M, int N, int Kd,
                        const float* __restrict__ e1, const float* __restrict__ e2) {
  __shared__ float As[16][64];
  __shared__ float Bs[16][64];
  int tid = threadIdx.x;
  int tx = tid & 15, ty = tid >> 4;
  int bm = blockIdx.y * 64, bn = blockIdx.x * 64;
  int row_l = tid >> 2;
  int kq = (tid & 3) * 4;
  float acc[4][4] = {};
  for (int k0 = 0; k0 < Kd; k0 += 16) {
    {
      int m = bm + row_l;
      #pragma unroll
      for (int i = 0; i < 4; ++i) {
        int k = k0 + kq + i;
        As[kq + i][row_l] = (m < M && k < Kd) ? A[(size_t)m * Kd + k] : 0.f;
      }
    }
    {
      int n = bn + row_l;
      #pragma unroll
      for (int i = 0; i < 4; ++i) {
        int k = k0 + kq + i;
        Bs[kq + i][row_l] = (n < N && k < Kd) ? B[(size_t)n * Kd + k] : 0.f;
      }
    }
    __syncthreads();
    #pragma unroll
    for (int kk = 0; kk < 16; ++kk) {
      float av[4], bv[4];
      #pragma unroll
      for (int i = 0; i < 4; ++i) av[i] = As[kk][ty * 4 + i];
      #pragma unroll
      for (int j = 0; j < 4; ++j) bv[j] = Bs[kk][tx * 4 + j];
      #pragma unroll
      for (int i = 0; i < 4; ++i)
        #pragma unroll
        for (int j = 0; j < 4; ++j) acc[i][j] += av[i] * bv[j];
    }
    __syncthreads();
  }
  #pragma unroll
  for (int i = 0; i < 4; ++i) {
    int m = bm + ty * 4 + i;
    if (m >= M) continue;
    #pragma unroll
    for (int j = 0; j < 4; ++j) {
      int n = bn + tx * 4 + j;
      if (n >= N) continue;
      float v = acc[i][j];
      if (bias) v += bias[n];
      if (EPI == EPI_LEAKY) v = LEAKY(v);
      else if (EPI == EPI_LEAKY_BN) { v = LEAKY(v); v *= BN_SCALE; }
      else if (EPI == EPI_TANH) v = tanhf(v);
      C[(size_t)m * N + n] = v;
    }
  }
}

// ---- small TN GEMM: C[i,j] = sum_k A[k,i] * B[k,j]  (A,B: [Kd x 128]) ------
__global__ void gemm_tn(const float* __restrict__ A, const float* __restrict__ B,
                        float* __restrict__ C, int Kd, int M, int N) {
  int j = blockIdx.x * 16 + (threadIdx.x & 15);
  int i = blockIdx.y * 16 + (threadIdx.x >> 4);
  if (i >= M || j >= N) return;
  float acc = 0.f;
  for (int k = 0; k < Kd; ++k) acc += A[(size_t)k * M + i] * B[(size_t)k * N + j];
  C[(size_t)i * N + j] = acc;
}

// ---- column softmax (axis 0) in-place; 16 cols x 16 row-groups per block --
__global__ void softmax_col(float* __restrict__ S, int M, int N) {
  int t = threadIdx.x;
  int cl = t & 15, g = t >> 4;
  int c = blockIdx.x * 16 + cl;
  __shared__ float red[16][17];
  float m = -1e30f;
  for (int r = g; r < M; r += 16) m = fmaxf(m, S[(size_t)r * N + c]);
  red[g][cl] = m;
  __syncthreads();
  for (int off = 8; off; off >>= 1) { if (g < off) red[g][cl] = fmaxf(red[g][cl], red[g + off][cl]); __syncthreads(); }
  m = red[0][cl];
  __syncthreads();
  float sum = 0.f;
  for (int r = g; r < M; r += 16) sum += expf(S[(size_t)r * N + c] - m);
  red[g][cl] = sum;
  __syncthreads();
  for (int off = 8; off; off >>= 1) { if (g < off) red[g][cl] += red[g + off][cl]; __syncthreads(); }
  sum = red[0][cl];
  float inv = 1.f / sum;
  for (int r = g; r < M; r += 16) {
    size_t i = (size_t)r * N + c;
    S[i] = expf(S[i] - m) * inv;
  }
}

// ---- row squared-norms ----------------------------------------------------
__global__ void row_norm(const float* __restrict__ X, float* __restrict__ out, int Kd) {
  int r = blockIdx.x;
  int t = threadIdx.x;
  float s = 0.f;
  for (int k = t; k < Kd; k += 64) { float v = X[(size_t)r * Kd + k]; s += v * v; }
  for (int off = 32; off; off >>= 1) s += __shfl_down(s, off);
  if (t == 0) out[r] = s;
}

// ---- mask scores s[k] = sum_h A3[h,k]*w4[h] + b4 --------------------------
__global__ void mask_score(const float* __restrict__ A3, const float* __restrict__ w4,
                           const float* __restrict__ b4, float* __restrict__ s) {
  int k = blockIdx.x * 256 + threadIdx.x;
  float acc = b4[0];
  for (int h = 0; h < 128; ++h) acc += A3[(size_t)h * 2048 + k] * w4[h];
  s[k] = acc;
}

// ---- stable descending-argsort rank -> top-S indices ----------------------
__global__ void topk_rank(const float* __restrict__ s, int* __restrict__ idx, int K, int S) {
  int j = blockIdx.x * 256 + threadIdx.x;
  if (j >= K) return;
  float sj = s[j];
  int rank = 0;
  for (int i = 0; i < K; ++i) {
    float si = s[i];
    rank += (si > sj) || (si == sj && i < j);
  }
  if (rank < S) idx[rank] = j;
}

// ---- build cat = [B_dt | softmax(aff_s[:,idx],axis=1)] --------------------
__global__ void build_cat(const float* __restrict__ Bdt, const float* __restrict__ affs,
                          const int* __restrict__ idx, float* __restrict__ cat) {
  int r = blockIdx.x, t = threadIdx.x;
  __shared__ float vals[256];
  __shared__ float red[256];
  float v = -1e30f;
  if (t < 204) {
    int ix = idx[t];
    ix = ix < 0 ? 0 : (ix > 2047 ? 2047 : ix);  // fault guard
    v = affs[(size_t)r * 2048 + ix];
  }
  vals[t] = v;
  red[t] = v;
  __syncthreads();
  for (int off = 128; off; off >>= 1) { if (t < off) red[t] = fmaxf(red[t], red[t + off]); __syncthreads(); }
  float m = red[0];
  __syncthreads();
  float e = (t < 204) ? expf(vals[t] - m) : 0.f;
  red[t] = e;
  __syncthreads();
  for (int off = 128; off; off >>= 1) { if (t < off) red[t] += red[t + off]; __syncthreads(); }
  float inv = 1.f / red[0];
  cat[(size_t)r * 460 + t] = Bdt[(size_t)r * 256 + t];
  if (t < 204) cat[(size_t)r * 460 + 256 + t] = e * inv;
}

// ---- a = leaky((AV*AU) @ aww.T + awb) -------------------------------------
__global__ void attn_gate(const float* __restrict__ AV, const float* __restrict__ AU,
                          const float* __restrict__ aww, const float* __restrict__ awb,
                          float* __restrict__ a, int n) {
  int r = blockIdx.x * 256 + threadIdx.x;
  if (r >= n) return;
  float acc = awb[0];
  for (int d = 0; d < 128; ++d) acc += AV[(size_t)r * 128 + d] * AU[(size_t)r * 128 + d] * aww[d];
  a[r] = LEAKY(acc);
}

// ---- 1-D softmax (single block); writes y and optionally y2 ---------------
__global__ void softmax_vec(const float* __restrict__ x, float* __restrict__ y,
                            float* __restrict__ y2, int n) {
  __shared__ float red[256];
  int t = threadIdx.x;
  float m = -1e30f;
  for (int i = t; i < n; i += 256) m = fmaxf(m, x[i]);
  red[t] = m;
  __syncthreads();
  for (int off = 128; off; off >>= 1) { if (t < off) red[t] = fmaxf(red[t], red[t + off]); __syncthreads(); }
  m = red[0];
  __syncthreads();
  float s = 0.f;
  for (int i = t; i < n; i += 256) s += expf(x[i] - m);
  red[t] = s;
  __syncthreads();
  for (int off = 128; off; off >>= 1) { if (t < off) red[t] += red[t + off]; __syncthreads(); }
  float inv = 1.f / red[0];
  for (int i = t; i < n; i += 256) {
    float v = expf(x[i] - m) * inv;
    y[i] = v;
    if (y2) y2[i] = v;
  }
}

// ---- weighted column sum, two-stage: part[16][256] then reduce ------------
__global__ void colsum_part(const float* __restrict__ wv, const float* __restrict__ H,
                            float* __restrict__ part, int n) {
  int bk = blockIdx.x, c = threadIdx.x;
  float s = 0.f;
  for (int r = bk; r < n; r += 16) s += wv[r] * H[(size_t)r * 256 + c];
  part[bk * 256 + c] = s;
}
__global__ void colsum_fin(const float* __restrict__ part, float* __restrict__ out) {
  int c = threadIdx.x;
  float s = 0.f;
  #pragma unroll
  for (int k = 0; k < 16; ++k) s += part[k * 256 + c];
  out[c] = s;
}

// ---- small gemv: out[o] = act(sum_k x[k]*W[o,k] + b[o]) -------------------
__global__ void gemv_act(const float* __restrict__ x, const float* __restrict__ W,
                         const float* __restrict__ b, float* __restrict__ out,
                         int O, int Kd, int act) {
  int o = blockIdx.x * blockDim.x + threadIdx.x;
  if (o >= O) return;
  float acc = b ? b[o] : 0.f;
  for (int k = 0; k < Kd; ++k) acc += x[k] * W[(size_t)o * Kd + k];
  if (act == 1) acc = LEAKY(acc);
  out[o] = acc;
}

// ---- cat2 = [B_fuse | tile(M1)] -------------------------------------------
__global__ void build_cat2(const float* __restrict__ Bf, const float* __restrict__ M1,
                           float* __restrict__ cat2) {
  int r = blockIdx.x, t = threadIdx.x; // 512 threads
  cat2[(size_t)r * 512 + t] = (t < 256) ? Bf[(size_t)r * 256 + t] : M1[t - 256];
}

// ---- final head: bvec -> semb -> cls -> Y ---------------------------------
__global__ void final_head(const float* __restrict__ AH2, const float* __restrict__ embw,
                           const float* __restrict__ embb, const float* __restrict__ sembw,
                           const float* __restrict__ sembb, const float* __restrict__ clsw,
                           const float* __restrict__ clsb, float* __restrict__ Yout) {
  __shared__ float bvec[512];
  __shared__ float red[512];
  int t = threadIdx.x; // 512
  float acc = embb[t];
  for (int c = 0; c < 256; ++c) acc += AH2[c] * embw[(size_t)t * 256 + c];
  bvec[t] = LEAKY(acc);
  __syncthreads();
  float p = 0.f;
  if (t < 256) {
    float a2 = sembb[t];
    for (int c = 0; c < 512; ++c) a2 += bvec[c] * sembw[(size_t)t * 512 + c];
    a2 = LEAKY(a2);
    p = a2 * clsw[t];
  }
  red[t] = p;
  __syncthreads();
  for (int off = 256; off; off >>= 1) { if (t < off) red[t] += red[t + off]; __syncthreads(); }
  if (t == 0) {
    float y = red[0] + clsb[0];
    y = 1.f / (1.f + expf(-y));
    y = fminf(fmaxf(y, 1e-5f), 1.f - 1e-5f);
    Yout[0] = y;
  }
}

extern "C" void kernel_launch(void* const* d_in, const int* in_sizes, int n_in,
                              void* d_out, int out_size, void* d_ws, size_t ws_size,
                              hipStream_t stream) {
  auto IN = [&](int i) { return (const float*)d_in[i]; };
  (void)n_in; (void)in_sizes; (void)out_size;

  const int S = 204;
  float* out_f = (float*)d_out;  // out[0]=Y, out[1..2048]=A

  float* W = (float*)d_ws;
  size_t off = 0;
  auto F = [&](size_t n) { float* p = W + off; off += n; return p; };

  float* dt    = F((size_t)4096 * 256);
  float* Xs    = F((size_t)2048 * 256);
  float* Ks    = F((size_t)2048 * 256);
  float* X1    = F((size_t)2048 * 128);
  float* X2    = F((size_t)2048 * 128);
  float* X3s   = F((size_t)2048 * 256);   // skip1/2 X3; later aliased as Bfuse
  float* aff   = F((size_t)2048 * 2048);  // euclid out; skip3 in-place
  float* AV    = F((size_t)2048 * 128);
  float* AU    = F((size_t)2048 * 128);
  float* Mm    = F((size_t)128 * 128);
  float* svec  = F(2048);
  int*   idxb  = (int*)F(256);
  float* avec  = F(2048);
  float* Awv   = F(2048);
  float* AH    = F(256);
  float* M1v   = F(256);
  float* AH2   = F(256);
  float* nx    = F(2048);
  float* ny    = F(2048);
  float* part  = F(4096);                 // colsum partials
  float* pool  = F((size_t)8388608);      // 32 MB phase-shared pool

  const size_t NEED_BYTES = off * 4;
  if (ws_size < NEED_BYTES) {
    fill_out<<<9, 256, 0, stream>>>(out_f, 2049);
    return;
  }

  // pool members (phase-disjoint)
  float* h1   = pool;                 // conv phase: 2048*2880
  float* h2h  = pool + 5898240;       // conv phase: 2048*800
  float* Smat = pool;                 // skip phases: 2048*2048
  float* X3b  = pool + 4194304;       // skip3 only: 2048*2048
  float* A3   = pool;                 // mask phase: 128*2048
  float* cat  = pool;                 // fuse phase: 2048*460
  float* cat2 = pool + 942080;        // 2048*512
  float* Hbuf = pool + 1990656;       // 2048*256

  float* Bfuse = X3s;

  // ---- data_transform for B (g=0) and KB (g=1) ----
  for (int g = 0; g < 2; ++g) {
    conv1_pool<<<2048, 256, 0, stream>>>(IN(g), IN(2), IN(3), h1);
    conv2_pool<<<2048, 256, 0, stream>>>(h1, IN(4), IN(5), h2h);
    gemm128_nt<EPI_LEAKY><<<dim3(2, 16), 256, 0, stream>>>(
        h2h, IN(6), IN(7), dt + (size_t)g * 2048 * 256, 2048, 256, 800, nullptr, nullptr);
  }
  float* B_dt = dt;
  float* KB_dt = dt + (size_t)2048 * 256;

  // ---- skip_block 1 (B_dt -> Xs) and 2 (KB_dt -> Ks) ----
  for (int g = 0; g < 2; ++g) {
    float* Xin = g ? KB_dt : B_dt;
    float* Xout = g ? Ks : Xs;
    int wi = g ? 14 : 8;
    gemm128_nt<EPI_LEAKY_BN><<<dim3(1, 16), 256, 0, stream>>>(
        Xin, IN(wi + 0), IN(wi + 1), X1, 2048, 128, 256, nullptr, nullptr);
    gemm128_nt<EPI_LEAKY_BN><<<dim3(1, 16), 256, 0, stream>>>(
        Xin, IN(wi + 2), IN(wi + 3), X2, 2048, 128, 256, nullptr, nullptr);
    gemm128_nt<EPI_LEAKY_BN><<<dim3(2, 16), 256, 0, stream>>>(
        Xin, IN(wi + 4), IN(wi + 5), X3s, 2048, 256, 256, nullptr, nullptr);
    gemm128_nt<EPI_NONE><<<dim3(16, 16), 256, 0, stream>>>(
        X1, X2, nullptr, Smat, 2048, 2048, 128, nullptr, nullptr);
    softmax_col<<<128, 256, 0, stream>>>(Smat, 2048, 2048);
    gemm128_nn_res<<<dim3(2, 16), 256, 0, stream>>>(Smat, X3s, Xin, Xout, 2048, 256, 2048);
  }

  // ---- euclid -> aff ----
  row_norm<<<2048, 64, 0, stream>>>(Xs, nx, 256);
  row_norm<<<2048, 64, 0, stream>>>(Ks, ny, 256);
  gemm128_nt<EPI_EUCLID><<<dim3(16, 16), 256, 0, stream>>>(
      Xs, Ks, nullptr, aff, 2048, 2048, 256, nx, ny);

  // ---- skip_block 3 (aff -> aff in-place), dd = 2048 ----
  gemm128_nt<EPI_LEAKY_BN><<<dim3(1, 16), 256, 0, stream>>>(
      aff, IN(20), IN(21), X1, 2048, 128, 2048, nullptr, nullptr);
  gemm128_nt<EPI_LEAKY_BN><<<dim3(1, 16), 256, 0, stream>>>(
      aff, IN(22), IN(23), X2, 2048, 128, 2048, nullptr, nullptr);
  gemm128_nt<EPI_LEAKY_BN><<<dim3(16, 16), 256, 0, stream>>>(
      aff, IN(24), IN(25), X3b, 2048, 2048, 2048, nullptr, nullptr);
  gemm128_nt<EPI_NONE><<<dim3(16, 16), 256, 0, stream>>>(
      X1, X2, nullptr, Smat, 2048, 2048, 128, nullptr, nullptr);
  softmax_col<<<128, 256, 0, stream>>>(Smat, 2048, 2048);
  gemm128_nn_res<<<dim3(16, 16), 256, 0, stream>>>(Smat, X3b, aff, aff, 2048, 2048, 2048);
  float* aff_s = aff;

  // ---- mask_scores -> top-S idx ----
  gemm128_nt<EPI_LEAKY><<<dim3(1, 16), 256, 0, stream>>>(
      aff_s, IN(26), IN(27), X1, 2048, 128, 2048, nullptr, nullptr);
  gemm128_nt<EPI_TANH><<<dim3(1, 16), 256, 0, stream>>>(
      aff_s, IN(28), IN(29), X2, 2048, 128, 2048, nullptr, nullptr);
  gemm_tn<<<dim3(8, 8), 256, 0, stream>>>(X1, X2, Mm, 2048, 128, 128);
  gemm128_nt<EPI_LEAKY><<<dim3(16, 1), 256, 0, stream>>>(
      Mm, IN(30), IN(31), A3, 128, 2048, 128, nullptr, nullptr);
  mask_score<<<8, 256, 0, stream>>>(A3, IN(32), IN(33), svec);
  topk_rank<<<8, 256, 0, stream>>>(svec, idxb, 2048, S);

  // ---- B_bag + concat + fuse (K=460 not /16 -> 64-tile gemm) ----
  build_cat<<<2048, 256, 0, stream>>>(B_dt, aff_s, idxb, cat);
  gemm_nt<EPI_LEAKY><<<dim3(4, 32), 256, 0, stream>>>(
      cat, IN(34), IN(35), Bfuse, 2048, 256, 460, nullptr, nullptr);

  // ---- attention 1 ----
  gemm128_nt<EPI_LEAKY><<<dim3(2, 16), 256, 0, stream>>>(
      Bfuse, IN(36), IN(37), Hbuf, 2048, 256, 256, nullptr, nullptr);
  gemm128_nt<EPI_TANH><<<dim3(1, 16), 256, 0, stream>>>(
      Hbuf, IN(38), IN(39), AV, 2048, 128, 256, nullptr, nullptr);
  gemm128_nt<EPI_LEAKY><<<dim3(1, 16), 256, 0, stream>>>(
      Hbuf, IN(40), IN(41), AU, 2048, 128, 256, nullptr, nullptr);
  attn_gate<<<8, 256, 0, stream>>>(AV, AU, IN(42), IN(43), avec, 2048);
  softmax_vec<<<1, 256, 0, stream>>>(avec, Awv, nullptr, 2048);
  colsum_part<<<16, 256, 0, stream>>>(Awv, Hbuf, part, 2048);
  colsum_fin<<<1, 256, 0, stream>>>(part, AH);
  gemv_act<<<1, 256, 0, stream>>>(AH, IN(44), IN(45), M1v, 256, 256, 1);
  build_cat2<<<2048, 512, 0, stream>>>(Bfuse, M1v, cat2);

  // ---- attention 2 (A -> output) ----
  gemm128_nt<EPI_LEAKY><<<dim3(2, 16), 256, 0, stream>>>(
      cat2, IN(46), IN(47), Hbuf, 2048, 256, 512, nullptr, nullptr);
  gemm128_nt<EPI_TANH><<<dim3(1, 16), 256, 0, stream>>>(
      Hbuf, IN(48), IN(49), AV, 2048, 128, 256, nullptr, nullptr);
  gemm128_nt<EPI_LEAKY><<<dim3(1, 16), 256, 0, stream>>>(
      Hbuf, IN(50), IN(51), AU, 2048, 128, 256, nullptr, nullptr);
  attn_gate<<<8, 256, 0, stream>>>(AV, AU, IN(52), IN(53), avec, 2048);
  softmax_vec<<<1, 256, 0, stream>>>(avec, Awv, out_f + 1, 2048);
  colsum_part<<<16, 256, 0, stream>>>(Awv, Hbuf, part, 2048);
  colsum_fin<<<1, 256, 0, stream>>>(part, AH2);

  // ---- final head -> Y ----
  final_head<<<1, 512, 0, stream>>>(AH2, IN(54), IN(55), IN(56), IN(57),
                                    IN(58), IN(59), out_f);
}

// Round 5
// 2471.045 us; speedup vs baseline: 4.0902x; 1.9433x over previous
//
#include <hip/hip_runtime.h>
#include <math.h>

#define LEAKY(x) ((x) > 0.f ? (x) : 0.01f * (x))
static constexpr float BN_SCALE = 0.9999950000374997f;

typedef unsigned short ushort_t;
typedef float f32x4 __attribute__((ext_vector_type(4)));
typedef short bf16x8 __attribute__((ext_vector_type(8)));

__device__ __forceinline__ ushort_t f2bfu(float f) {
  union { float f; unsigned u; } v; v.f = f;
  unsigned r = v.u + 0x7fffu + ((v.u >> 16) & 1u);
  return (ushort_t)(r >> 16);
}

// ---- fallback sentinel if workspace is too small ---------------------------
__global__ void fill_out(float* out, int n) {
  int i = blockIdx.x * 256 + threadIdx.x;
  if (i < n) out[i] = 0.25f;
}

// ---- conv1 + leaky + maxpool2 : [1,28,28] -> [20,12,12] -------------------
__global__ void conv1_pool(const float* __restrict__ img, const float* __restrict__ w,
                           const float* __restrict__ b, float* __restrict__ out) {
  int n = blockIdx.x;
  __shared__ float simg[784];
  __shared__ float sw[500];
  __shared__ float sb[20];
  int tid = threadIdx.x;
  for (int i = tid; i < 784; i += 256) simg[i] = img[(size_t)n * 784 + i];
  for (int i = tid; i < 500; i += 256) sw[i] = w[i];
  if (tid < 20) sb[tid] = b[tid];
  __syncthreads();
  for (int o = tid; o < 2880; o += 256) {
    int c = o / 144, rem = o % 144, py = rem / 12, px = rem % 12;
    int y0 = py * 2, x0 = px * 2;
    float p[6][6];
    #pragma unroll
    for (int yy = 0; yy < 6; ++yy)
      #pragma unroll
      for (int xx = 0; xx < 6; ++xx)
        p[yy][xx] = simg[(y0 + yy) * 28 + x0 + xx];
    float t0 = sb[c], t1 = t0, t2 = t0, t3 = t0;
    const float* wc = &sw[c * 25];
    #pragma unroll
    for (int ky = 0; ky < 5; ++ky)
      #pragma unroll
      for (int kx = 0; kx < 5; ++kx) {
        float wv = wc[ky * 5 + kx];
        t0 += p[ky][kx] * wv;
        t1 += p[ky][kx + 1] * wv;
        t2 += p[ky + 1][kx] * wv;
        t3 += p[ky + 1][kx + 1] * wv;
      }
    t0 = LEAKY(t0); t1 = LEAKY(t1); t2 = LEAKY(t2); t3 = LEAKY(t3);
    out[(size_t)n * 2880 + o] = fmaxf(fmaxf(t0, t1), fmaxf(t2, t3));
  }
}

// ---- conv2 + leaky + maxpool2 : [20,12,12] -> [50,4,4]=800 ----------------
__global__ void conv2_pool(const float* __restrict__ h1, const float* __restrict__ w,
                           const float* __restrict__ b, float* __restrict__ out) {
  int n = blockIdx.x;
  __shared__ float sin_[2880];
  __shared__ float sw[6250];
  __shared__ float sb[50];
  int tid = threadIdx.x;
  for (int i = tid; i < 2880; i += 256) sin_[i] = h1[(size_t)n * 2880 + i];
  if (tid < 50) sb[tid] = b[tid];
  float acc[4][4];
  #pragma unroll
  for (int g = 0; g < 4; ++g) {
    int o = tid + 256 * g;
    float bb = (o < 800) ? b[o / 16] : 0.f;
    #pragma unroll
    for (int p = 0; p < 4; ++p) acc[g][p] = bb;
  }
  for (int chunk = 0; chunk < 4; ++chunk) {
    __syncthreads();
    for (int i = tid; i < 6250; i += 256) {
      int oc = i / 125, rem = i % 125;
      sw[i] = w[(size_t)oc * 500 + chunk * 125 + rem];
    }
    __syncthreads();
    #pragma unroll
    for (int g = 0; g < 4; ++g) {
      int o = tid + 256 * g;
      if (o >= 800) continue;
      int c = o / 16, rem = o % 16, py = rem / 4, px = rem % 4;
      int y0 = py * 2, x0 = px * 2;
      float t0 = 0.f, t1 = 0.f, t2 = 0.f, t3 = 0.f;
      #pragma unroll
      for (int icl = 0; icl < 5; ++icl) {
        int ic = chunk * 5 + icl;
        float p[6][6];
        #pragma unroll
        for (int yy = 0; yy < 6; ++yy)
          #pragma unroll
          for (int xx = 0; xx < 6; ++xx)
            p[yy][xx] = sin_[ic * 144 + (y0 + yy) * 12 + x0 + xx];
        const float* wp = &sw[c * 125 + icl * 25];
        #pragma unroll
        for (int ky = 0; ky < 5; ++ky)
          #pragma unroll
          for (int kx = 0; kx < 5; ++kx) {
            float wv = wp[ky * 5 + kx];
            t0 += p[ky][kx] * wv;
            t1 += p[ky][kx + 1] * wv;
            t2 += p[ky + 1][kx] * wv;
            t3 += p[ky + 1][kx + 1] * wv;
          }
      }
      acc[g][0] += t0; acc[g][1] += t1; acc[g][2] += t2; acc[g][3] += t3;
    }
  }
  #pragma unroll
  for (int g = 0; g < 4; ++g) {
    int o = tid + 256 * g;
    if (o >= 800) continue;
    float m = -1e30f;
    #pragma unroll
    for (int p = 0; p < 4; ++p) {
      float v = LEAKY(acc[g][p]);
      m = fmaxf(m, v);
    }
    out[(size_t)n * 800 + o] = m;
  }
}

// ---------------- epilogue kinds -------------------------------------------
enum { EPI_NONE = 0, EPI_LEAKY = 1, EPI_LEAKY_BN = 2, EPI_TANH = 3, EPI_EUCLID = 4 };

// LDS row stride 40 ushorts (80B = 5 bank-quads): 16-lane b128 frag reads hit
// each quad exactly twice -> 2-way (free, m136). 16B aligned for ds_read_b128.
#define LROW 40

// ---- MFMA NT GEMM: C[M,N] = epi(A[M,K] @ B[N,K]^T + bias) -----------------
// fp32 inputs, bf16 LDS staging, mfma_f32_16x16x32_bf16, fp32 out.
// Requires M%128==0, N%128==0, K%32==0. Grid (N/128, M/128), block 256.
template <int EPI>
__launch_bounds__(256)
__global__ void gemm_mfma_nt(const float* __restrict__ A, const float* __restrict__ B,
                             const float* __restrict__ bias, float* __restrict__ C,
                             int M, int N, int Kd,
                             const float* __restrict__ e1, const float* __restrict__ e2) {
  __shared__ ushort_t As[128 * LROW];
  __shared__ ushort_t Bs[128 * LROW];
  int tid = threadIdx.x;
  int bm = blockIdx.y * 128, bn = blockIdx.x * 128;
  int wave = tid >> 6, lane = tid & 63;
  int wm = (wave >> 1) * 64, wn = (wave & 1) * 64;
  int mrow = lane & 15, kq = lane >> 4;        // frag indices
  int srow = tid >> 1, skof = (tid & 1) * 16;  // staging indices

  f32x4 acc[4][4];
  #pragma unroll
  for (int i = 0; i < 4; ++i)
    #pragma unroll
    for (int j = 0; j < 4; ++j)
      #pragma unroll
      for (int r = 0; r < 4; ++r) acc[i][j][r] = 0.f;

  for (int k0 = 0; k0 < Kd; k0 += 32) {
    // stage A,B tiles (fp32 -> bf16)
    const float4* ap = (const float4*)(A + (size_t)(bm + srow) * Kd + k0 + skof);
    const float4* bp = (const float4*)(B + (size_t)(bn + srow) * Kd + k0 + skof);
    float4 av[4], bv[4];
    #pragma unroll
    for (int i = 0; i < 4; ++i) av[i] = ap[i];
    #pragma unroll
    for (int i = 0; i < 4; ++i) bv[i] = bp[i];
    __syncthreads();
    ushort_t* wa = &As[srow * LROW + skof];
    ushort_t* wb = &Bs[srow * LROW + skof];
    #pragma unroll
    for (int i = 0; i < 4; ++i) {
      wa[i * 4 + 0] = f2bfu(av[i].x); wa[i * 4 + 1] = f2bfu(av[i].y);
      wa[i * 4 + 2] = f2bfu(av[i].z); wa[i * 4 + 3] = f2bfu(av[i].w);
      wb[i * 4 + 0] = f2bfu(bv[i].x); wb[i * 4 + 1] = f2bfu(bv[i].y);
      wb[i * 4 + 2] = f2bfu(bv[i].z); wb[i * 4 + 3] = f2bfu(bv[i].w);
    }
    __syncthreads();
    bf16x8 af[4], bf[4];
    #pragma unroll
    for (int mt = 0; mt < 4; ++mt)
      af[mt] = *(const bf16x8*)&As[(wm + mt * 16 + mrow) * LROW + kq * 8];
    #pragma unroll
    for (int nt = 0; nt < 4; ++nt)
      bf[nt] = *(const bf16x8*)&Bs[(wn + nt * 16 + mrow) * LROW + kq * 8];
    #pragma unroll
    for (int mt = 0; mt < 4; ++mt)
      #pragma unroll
      for (int nt = 0; nt < 4; ++nt)
        acc[mt][nt] = __builtin_amdgcn_mfma_f32_16x16x32_bf16(af[mt], bf[nt], acc[mt][nt], 0, 0, 0);
  }
  // epilogue: D[m][n]: n = lane&15, m = kq*4 + r
  #pragma unroll
  for (int mt = 0; mt < 4; ++mt) {
    #pragma unroll
    for (int nt = 0; nt < 4; ++nt) {
      int n_g = bn + wn + nt * 16 + (lane & 15);
      #pragma unroll
      for (int r = 0; r < 4; ++r) {
        int m_g = bm + wm + mt * 16 + kq * 4 + r;
        float v = acc[mt][nt][r];
        if (EPI == EPI_EUCLID) {
          v = e1[m_g] + e2[n_g] - 2.f * v;
          v = sqrtf(fmaxf(v, 0.f));
        } else {
          if (bias) v += bias[n_g];
          if (EPI == EPI_LEAKY) v = LEAKY(v);
          else if (EPI == EPI_LEAKY_BN) { v = LEAKY(v); v *= BN_SCALE; }
          else if (EPI == EPI_TANH) v = tanhf(v);
        }
        C[(size_t)m_g * N + n_g] = v;
      }
    }
  }
}

// ---- MFMA NN GEMM + residual: C = A[M,K] @ B[K,N] + R  (C==R safe) --------
__launch_bounds__(256)
__global__ void gemm_mfma_nn_res(const float* __restrict__ A, const float* __restrict__ B,
                                 const float* __restrict__ R, float* __restrict__ C,
                                 int M, int N, int Kd) {
  __shared__ ushort_t As[128 * LROW];
  __shared__ ushort_t Bs[128 * LROW];
  int tid = threadIdx.x;
  int bm = blockIdx.y * 128, bn = blockIdx.x * 128;
  int wave = tid >> 6, lane = tid & 63;
  int wm = (wave >> 1) * 64, wn = (wave & 1) * 64;
  int mrow = lane & 15, kq = lane >> 4;
  int srow = tid >> 1, skof = (tid & 1) * 16;
  int krow = tid >> 3, nof = (tid & 7) * 16;   // B staging (transpose)

  f32x4 acc[4][4];
  #pragma unroll
  for (int i = 0; i < 4; ++i)
    #pragma unroll
    for (int j = 0; j < 4; ++j)
      #pragma unroll
      for (int r = 0; r < 4; ++r) acc[i][j][r] = 0.f;

  for (int k0 = 0; k0 < Kd; k0 += 32) {
    const float4* ap = (const float4*)(A + (size_t)(bm + srow) * Kd + k0 + skof);
    const float4* bp = (const float4*)(B + (size_t)(k0 + krow) * N + bn + nof);
    float4 av[4], bv[4];
    #pragma unroll
    for (int i = 0; i < 4; ++i) av[i] = ap[i];
    #pragma unroll
    for (int i = 0; i < 4; ++i) bv[i] = bp[i];
    __syncthreads();
    ushort_t* wa = &As[srow * LROW + skof];
    #pragma unroll
    for (int i = 0; i < 4; ++i) {
      wa[i * 4 + 0] = f2bfu(av[i].x); wa[i * 4 + 1] = f2bfu(av[i].y);
      wa[i * 4 + 2] = f2bfu(av[i].z); wa[i * 4 + 3] = f2bfu(av[i].w);
      // transpose B into [n][k] layout
      Bs[(nof + i * 4 + 0) * LROW + krow] = f2bfu(bv[i].x);
      Bs[(nof + i * 4 + 1) * LROW + krow] = f2bfu(bv[i].y);
      Bs[(nof + i * 4 + 2) * LROW + krow] = f2bfu(bv[i].z);
      Bs[(nof + i * 4 + 3) * LROW + krow] = f2bfu(bv[i].w);
    }
    __syncthreads();
    bf16x8 af[4], bf[4];
    #pragma unroll
    for (int mt = 0; mt < 4; ++mt)
      af[mt] = *(const bf16x8*)&As[(wm + mt * 16 + mrow) * LROW + kq * 8];
    #pragma unroll
    for (int nt = 0; nt < 4; ++nt)
      bf[nt] = *(const bf16x8*)&Bs[(wn + nt * 16 + mrow) * LROW + kq * 8];
    #pragma unroll
    for (int mt = 0; mt < 4; ++mt)
      #pragma unroll
      for (int nt = 0; nt < 4; ++nt)
        acc[mt][nt] = __builtin_amdgcn_mfma_f32_16x16x32_bf16(af[mt], bf[nt], acc[mt][nt], 0, 0, 0);
  }
  #pragma unroll
  for (int mt = 0; mt < 4; ++mt)
    #pragma unroll
    for (int nt = 0; nt < 4; ++nt) {
      int n_g = bn + wn + nt * 16 + (lane & 15);
      #pragma unroll
      for (int r = 0; r < 4; ++r) {
        int m_g = bm + wm + mt * 16 + kq * 4 + r;
        C[(size_t)m_g * N + n_g] = acc[mt][nt][r] + R[(size_t)m_g * N + n_g];
      }
    }
}

// ---- split-K TN GEMM stage 1: part[ks][i][j] over 128-k chunk -------------
__global__ void gemm_tn_part(const float* __restrict__ A, const float* __restrict__ B,
                             float* __restrict__ part) {
  int tx = threadIdx.x & 15, ty = threadIdx.x >> 4;
  int i = blockIdx.y * 16 + ty, j = blockIdx.x * 16 + tx;
  int ks = blockIdx.z;
  float acc = 0.f;
  for (int k = ks * 128; k < ks * 128 + 128; ++k)
    acc += A[(size_t)k * 128 + i] * B[(size_t)k * 128 + j];
  part[(size_t)ks * 16384 + i * 128 + j] = acc;
}
__global__ void gemm_tn_reduce(const float* __restrict__ part, float* __restrict__ Mm) {
  int idx = blockIdx.x * 256 + threadIdx.x;
  float s = 0.f;
  #pragma unroll
  for (int ks = 0; ks < 16; ++ks) s += part[(size_t)ks * 16384 + idx];
  Mm[idx] = s;
}

// ---- column softmax (axis 0) in-place -------------------------------------
__global__ void softmax_col(float* __restrict__ S, int M, int N) {
  int t = threadIdx.x;
  int cl = t & 15, g = t >> 4;
  int c = blockIdx.x * 16 + cl;
  __shared__ float red[16][17];
  float m = -1e30f;
  for (int r = g; r < M; r += 16) m = fmaxf(m, S[(size_t)r * N + c]);
  red[g][cl] = m;
  __syncthreads();
  for (int off = 8; off; off >>= 1) { if (g < off) red[g][cl] = fmaxf(red[g][cl], red[g + off][cl]); __syncthreads(); }
  m = red[0][cl];
  __syncthreads();
  float sum = 0.f;
  for (int r = g; r < M; r += 16) sum += expf(S[(size_t)r * N + c] - m);
  red[g][cl] = sum;
  __syncthreads();
  for (int off = 8; off; off >>= 1) { if (g < off) red[g][cl] += red[g + off][cl]; __syncthreads(); }
  sum = red[0][cl];
  float inv = 1.f / sum;
  for (int r = g; r < M; r += 16) {
    size_t i = (size_t)r * N + c;
    S[i] = expf(S[i] - m) * inv;
  }
}

// ---- row squared-norms ----------------------------------------------------
__global__ void row_norm(const float* __restrict__ X, float* __restrict__ out, int Kd) {
  int r = blockIdx.x;
  int t = threadIdx.x;
  float s = 0.f;
  for (int k = t; k < Kd; k += 64) { float v = X[(size_t)r * Kd + k]; s += v * v; }
  for (int off = 32; off; off >>= 1) s += __shfl_down(s, off);
  if (t == 0) out[r] = s;
}

// ---- mask scores ----------------------------------------------------------
__global__ void mask_score(const float* __restrict__ A3, const float* __restrict__ w4,
                           const float* __restrict__ b4, float* __restrict__ s) {
  int k = blockIdx.x * 256 + threadIdx.x;
  float acc = b4[0];
  for (int h = 0; h < 128; ++h) acc += A3[(size_t)h * 2048 + k] * w4[h];
  s[k] = acc;
}

// ---- stable descending-argsort rank -> top-S indices ----------------------
__global__ void topk_rank(const float* __restrict__ s, int* __restrict__ idx, int K, int S) {
  int j = blockIdx.x * 256 + threadIdx.x;
  if (j >= K) return;
  float sj = s[j];
  int rank = 0;
  for (int i = 0; i < K; ++i) {
    float si = s[i];
    rank += (si > sj) || (si == sj && i < j);
  }
  if (rank < S) idx[rank] = j;
}

// ---- build cat = [B_dt | softmax(aff_s[:,idx],axis=1) | 0pad] stride 512 --
__global__ void build_cat(const float* __restrict__ Bdt, const float* __restrict__ affs,
                          const int* __restrict__ idx, float* __restrict__ cat) {
  int r = blockIdx.x, t = threadIdx.x;
  __shared__ float vals[256];
  __shared__ float red[256];
  float v = -1e30f;
  if (t < 204) {
    int ix = idx[t];
    ix = ix < 0 ? 0 : (ix > 2047 ? 2047 : ix);
    v = affs[(size_t)r * 2048 + ix];
  }
  vals[t] = v;
  red[t] = v;
  __syncthreads();
  for (int off = 128; off; off >>= 1) { if (t < off) red[t] = fmaxf(red[t], red[t + off]); __syncthreads(); }
  float m = red[0];
  __syncthreads();
  float e = (t < 204) ? expf(vals[t] - m) : 0.f;
  red[t] = e;
  __syncthreads();
  for (int off = 128; off; off >>= 1) { if (t < off) red[t] += red[t + off]; __syncthreads(); }
  float inv = 1.f / red[0];
  cat[(size_t)r * 512 + t] = Bdt[(size_t)r * 256 + t];
  if (t < 204) cat[(size_t)r * 512 + 256 + t] = e * inv;
  else cat[(size_t)r * 512 + 256 + t] = 0.f;  // zero pad 460..511
}

// ---- pad fuse_w [256,460] -> [256,512] ------------------------------------
__global__ void pad_fuse(const float* __restrict__ w, float* __restrict__ wp) {
  int idx = blockIdx.x * 256 + threadIdx.x;
  if (idx >= 256 * 512) return;
  int o = idx >> 9, k = idx & 511;
  wp[idx] = (k < 460) ? w[(size_t)o * 460 + k] : 0.f;
}

// ---- a = leaky((AV*AU) @ aww.T + awb) -------------------------------------
__global__ void attn_gate(const float* __restrict__ AV, const float* __restrict__ AU,
                          const float* __restrict__ aww, const float* __restrict__ awb,
                          float* __restrict__ a, int n) {
  int r = blockIdx.x * 256 + threadIdx.x;
  if (r >= n) return;
  float acc = awb[0];
  for (int d = 0; d < 128; ++d) acc += AV[(size_t)r * 128 + d] * AU[(size_t)r * 128 + d] * aww[d];
  a[r] = LEAKY(acc);
}

// ---- 1-D softmax (single block) -------------------------------------------
__global__ void softmax_vec(const float* __restrict__ x, float* __restrict__ y,
                            float* __restrict__ y2, int n) {
  __shared__ float red[256];
  int t = threadIdx.x;
  float m = -1e30f;
  for (int i = t; i < n; i += 256) m = fmaxf(m, x[i]);
  red[t] = m;
  __syncthreads();
  for (int off = 128; off; off >>= 1) { if (t < off) red[t] = fmaxf(red[t], red[t + off]); __syncthreads(); }
  m = red[0];
  __syncthreads();
  float s = 0.f;
  for (int i = t; i < n; i += 256) s += expf(x[i] - m);
  red[t] = s;
  __syncthreads();
  for (int off = 128; off; off >>= 1) { if (t < off) red[t] += red[t + off]; __syncthreads(); }
  float inv = 1.f / red[0];
  for (int i = t; i < n; i += 256) {
    float v = expf(x[i] - m) * inv;
    y[i] = v;
    if (y2) y2[i] = v;
  }
}

// ---- weighted column sum, two-stage ---------------------------------------
__global__ void colsum_part(const float* __restrict__ wv, const float* __restrict__ H,
                            float* __restrict__ part, int n) {
  int bk = blockIdx.x, c = threadIdx.x;
  float s = 0.f;
  for (int r = bk; r < n; r += 16) s += wv[r] * H[(size_t)r * 256 + c];
  part[bk * 256 + c] = s;
}
__global__ void colsum_fin(const float* __restrict__ part, float* __restrict__ out) {
  int c = threadIdx.x;
  float s = 0.f;
  #pragma unroll
  for (int k = 0; k < 16; ++k) s += part[k * 256 + c];
  out[c] = s;
}

// ---- small gemv -----------------------------------------------------------
__global__ void gemv_act(const float* __restrict__ x, const float* __restrict__ W,
                         const float* __restrict__ b, float* __restrict__ out,
                         int O, int Kd, int act) {
  int o = blockIdx.x * blockDim.x + threadIdx.x;
  if (o >= O) return;
  float acc = b ? b[o] : 0.f;
  for (int k = 0; k < Kd; ++k) acc += x[k] * W[(size_t)o * Kd + k];
  if (act == 1) acc = LEAKY(acc);
  out[o] = acc;
}

// ---- cat2 = [B_fuse | tile(M1)] -------------------------------------------
__global__ void build_cat2(const float* __restrict__ Bf, const float* __restrict__ M1,
                           float* __restrict__ cat2) {
  int r = blockIdx.x, t = threadIdx.x; // 512 threads
  cat2[(size_t)r * 512 + t] = (t < 256) ? Bf[(size_t)r * 256 + t] : M1[t - 256];
}

// ---- final head -----------------------------------------------------------
__global__ void final_head(const float* __restrict__ AH2, const float* __restrict__ embw,
                           const float* __restrict__ embb, const float* __restrict__ sembw,
                           const float* __restrict__ sembb, const float* __restrict__ clsw,
                           const float* __restrict__ clsb, float* __restrict__ Yout) {
  __shared__ float bvec[512];
  __shared__ float red[512];
  int t = threadIdx.x; // 512
  float acc = embb[t];
  for (int c = 0; c < 256; ++c) acc += AH2[c] * embw[(size_t)t * 256 + c];
  bvec[t] = LEAKY(acc);
  __syncthreads();
  float p = 0.f;
  if (t < 256) {
    float a2 = sembb[t];
    for (int c = 0; c < 512; ++c) a2 += bvec[c] * sembw[(size_t)t * 512 + c];
    a2 = LEAKY(a2);
    p = a2 * clsw[t];
  }
  red[t] = p;
  __syncthreads();
  for (int off = 256; off; off >>= 1) { if (t < off) red[t] += red[t + off]; __syncthreads(); }
  if (t == 0) {
    float y = red[0] + clsb[0];
    y = 1.f / (1.f + expf(-y));
    y = fminf(fmaxf(y, 1e-5f), 1.f - 1e-5f);
    Yout[0] = y;
  }
}

extern "C" void kernel_launch(void* const* d_in, const int* in_sizes, int n_in,
                              void* d_out, int out_size, void* d_ws, size_t ws_size,
                              hipStream_t stream) {
  auto IN = [&](int i) { return (const float*)d_in[i]; };
  (void)n_in; (void)in_sizes; (void)out_size;

  const int S = 204;
  float* out_f = (float*)d_out;  // out[0]=Y, out[1..2048]=A

  float* W = (float*)d_ws;
  size_t off = 0;
  auto F = [&](size_t n) { float* p = W + off; off += n; return p; };

  float* dt    = F((size_t)4096 * 256);
  float* Xs    = F((size_t)2048 * 256);
  float* Ks    = F((size_t)2048 * 256);
  float* X1    = F((size_t)2048 * 128);
  float* X2    = F((size_t)2048 * 128);
  float* X3s   = F((size_t)2048 * 256);   // skip1/2 X3; later Bfuse
  float* aff   = F((size_t)2048 * 2048);  // euclid out; skip3 in-place
  float* AV    = F((size_t)2048 * 128);
  float* AU    = F((size_t)2048 * 128);
  float* Mm    = F((size_t)128 * 128);
  float* svec  = F(2048);
  int*   idxb  = (int*)F(256);
  float* avec  = F(2048);
  float* Awv   = F(2048);
  float* AH    = F(256);
  float* M1v   = F(256);
  float* AH2   = F(256);
  float* nx    = F(2048);
  float* ny    = F(2048);
  float* part  = F(4096);
  float* pool  = F((size_t)8388608);      // 32 MB phase-shared pool

  const size_t NEED_BYTES = off * 4;
  if (ws_size < NEED_BYTES) {
    fill_out<<<9, 256, 0, stream>>>(out_f, 2049);
    return;
  }

  // pool members (phase-disjoint)
  float* h1    = pool;                 // conv: 2048*2880
  float* h2h   = pool + 5898240;       // conv: 2048*800
  float* Smat  = pool;                 // skip: 2048*2048
  float* X3b   = pool + 4194304;       // skip3: 2048*2048
  float* A3    = pool;                 // mask: 128*2048
  float* tnpt  = pool + 4194304;       // mask: 16*16384 split-K partials
  float* cat   = pool;                 // fuse: 2048*512
  float* cat2  = pool + 1048576;       // 2048*512
  float* Hbuf  = pool + 2097152;       // 2048*256
  float* fwpad = pool + 2621440;       // 256*512

  float* Bfuse = X3s;

  // ---- data_transform for B (g=0) and KB (g=1) ----
  for (int g = 0; g < 2; ++g) {
    conv1_pool<<<2048, 256, 0, stream>>>(IN(g), IN(2), IN(3), h1);
    conv2_pool<<<2048, 256, 0, stream>>>(h1, IN(4), IN(5), h2h);
    gemm_mfma_nt<EPI_LEAKY><<<dim3(2, 16), 256, 0, stream>>>(
        h2h, IN(6), IN(7), dt + (size_t)g * 2048 * 256, 2048, 256, 800, nullptr, nullptr);
  }
  float* B_dt = dt;
  float* KB_dt = dt + (size_t)2048 * 256;

  // ---- skip_block 1 (B_dt -> Xs) and 2 (KB_dt -> Ks) ----
  for (int g = 0; g < 2; ++g) {
    float* Xin = g ? KB_dt : B_dt;
    float* Xout = g ? Ks : Xs;
    int wi = g ? 14 : 8;
    gemm_mfma_nt<EPI_LEAKY_BN><<<dim3(1, 16), 256, 0, stream>>>(
        Xin, IN(wi + 0), IN(wi + 1), X1, 2048, 128, 256, nullptr, nullptr);
    gemm_mfma_nt<EPI_LEAKY_BN><<<dim3(1, 16), 256, 0, stream>>>(
        Xin, IN(wi + 2), IN(wi + 3), X2, 2048, 128, 256, nullptr, nullptr);
    gemm_mfma_nt<EPI_LEAKY_BN><<<dim3(2, 16), 256, 0, stream>>>(
        Xin, IN(wi + 4), IN(wi + 5), X3s, 2048, 256, 256, nullptr, nullptr);
    gemm_mfma_nt<EPI_NONE><<<dim3(16, 16), 256, 0, stream>>>(
        X1, X2, nullptr, Smat, 2048, 2048, 128, nullptr, nullptr);
    softmax_col<<<128, 256, 0, stream>>>(Smat, 2048, 2048);
    gemm_mfma_nn_res<<<dim3(2, 16), 256, 0, stream>>>(Smat, X3s, Xin, Xout, 2048, 256, 2048);
  }

  // ---- euclid -> aff ----
  row_norm<<<2048, 64, 0, stream>>>(Xs, nx, 256);
  row_norm<<<2048, 64, 0, stream>>>(Ks, ny, 256);
  gemm_mfma_nt<EPI_EUCLID><<<dim3(16, 16), 256, 0, stream>>>(
      Xs, Ks, nullptr, aff, 2048, 2048, 256, nx, ny);

  // ---- skip_block 3 (aff -> aff in-place) ----
  gemm_mfma_nt<EPI_LEAKY_BN><<<dim3(1, 16), 256, 0, stream>>>(
      aff, IN(20), IN(21), X1, 2048, 128, 2048, nullptr, nullptr);
  gemm_mfma_nt<EPI_LEAKY_BN><<<dim3(1, 16), 256, 0, stream>>>(
      aff, IN(22), IN(23), X2, 2048, 128, 2048, nullptr, nullptr);
  gemm_mfma_nt<EPI_LEAKY_BN><<<dim3(16, 16), 256, 0, stream>>>(
      aff, IN(24), IN(25), X3b, 2048, 2048, 2048, nullptr, nullptr);
  gemm_mfma_nt<EPI_NONE><<<dim3(16, 16), 256, 0, stream>>>(
      X1, X2, nullptr, Smat, 2048, 2048, 128, nullptr, nullptr);
  softmax_col<<<128, 256, 0, stream>>>(Smat, 2048, 2048);
  gemm_mfma_nn_res<<<dim3(16, 16), 256, 0, stream>>>(Smat, X3b, aff, aff, 2048, 2048, 2048);
  float* aff_s = aff;

  // ---- mask_scores -> top-S idx ----
  gemm_mfma_nt<EPI_LEAKY><<<dim3(1, 16), 256, 0, stream>>>(
      aff_s, IN(26), IN(27), X1, 2048, 128, 2048, nullptr, nullptr);
  gemm_mfma_nt<EPI_TANH><<<dim3(1, 16), 256, 0, stream>>>(
      aff_s, IN(28), IN(29), X2, 2048, 128, 2048, nullptr, nullptr);
  gemm_tn_part<<<dim3(8, 8, 16), 256, 0, stream>>>(X1, X2, tnpt);
  gemm_tn_reduce<<<64, 256, 0, stream>>>(tnpt, Mm);
  gemm_mfma_nt<EPI_LEAKY><<<dim3(16, 1), 256, 0, stream>>>(
      Mm, IN(30), IN(31), A3, 128, 2048, 128, nullptr, nullptr);
  mask_score<<<8, 256, 0, stream>>>(A3, IN(32), IN(33), svec);
  topk_rank<<<8, 256, 0, stream>>>(svec, idxb, 2048, S);

  // ---- B_bag + concat (pad to 512) + fuse ----
  build_cat<<<2048, 256, 0, stream>>>(B_dt, aff_s, idxb, cat);
  pad_fuse<<<512, 256, 0, stream>>>(IN(34), fwpad);
  gemm_mfma_nt<EPI_LEAKY><<<dim3(2, 16), 256, 0, stream>>>(
      cat, fwpad, IN(35), Bfuse, 2048, 256, 512, nullptr, nullptr);

  // ---- attention 1 ----
  gemm_mfma_nt<EPI_LEAKY><<<dim3(2, 16), 256, 0, stream>>>(
      Bfuse, IN(36), IN(37), Hbuf, 2048, 256, 256, nullptr, nullptr);
  gemm_mfma_nt<EPI_TANH><<<dim3(1, 16), 256, 0, stream>>>(
      Hbuf, IN(38), IN(39), AV, 2048, 128, 256, nullptr, nullptr);
  gemm_mfma_nt<EPI_LEAKY><<<dim3(1, 16), 256, 0, stream>>>(
      Hbuf, IN(40), IN(41), AU, 2048, 128, 256, nullptr, nullptr);
  attn_gate<<<8, 256, 0, stream>>>(AV, AU, IN(42), IN(43), avec, 2048);
  softmax_vec<<<1, 256, 0, stream>>>(avec, Awv, nullptr, 2048);
  colsum_part<<<16, 256, 0, stream>>>(Awv, Hbuf, part, 2048);
  colsum_fin<<<1, 256, 0, stream>>>(part, AH);
  gemv_act<<<1, 256, 0, stream>>>(AH, IN(44), IN(45), M1v, 256, 256, 1);
  build_cat2<<<2048, 512, 0, stream>>>(Bfuse, M1v, cat2);

  // ---- attention 2 (A -> output) ----
  gemm_mfma_nt<EPI_LEAKY><<<dim3(2, 16), 256, 0, stream>>>(
      cat2, IN(46), IN(47), Hbuf, 2048, 256, 512, nullptr, nullptr);
  gemm_mfma_nt<EPI_TANH><<<dim3(1, 16), 256, 0, stream>>>(
      Hbuf, IN(48), IN(49), AV, 2048, 128, 256, nullptr, nullptr);
  gemm_mfma_nt<EPI_LEAKY><<<dim3(1, 16), 256, 0, stream>>>(
      Hbuf, IN(50), IN(51), AU, 2048, 128, 256, nullptr, nullptr);
  attn_gate<<<8, 256, 0, stream>>>(AV, AU, IN(52), IN(53), avec, 2048);
  softmax_vec<<<1, 256, 0, stream>>>(avec, Awv, out_f + 1, 2048);
  colsum_part<<<16, 256, 0, stream>>>(Awv, Hbuf, part, 2048);
  colsum_fin<<<1, 256, 0, stream>>>(part, AH2);

  // ---- final head -> Y ----
  final_head<<<1, 512, 0, stream>>>(AH2, IN(54), IN(55), IN(56), IN(57),
                                    IN(58), IN(59), out_f);
}

// Round 6
// 1774.373 us; speedup vs baseline: 5.6962x; 1.3926x over previous
//
#include <hip/hip_runtime.h>
#include <math.h>

#define LEAKY(x) ((x) > 0.f ? (x) : 0.01f * (x))
static constexpr float BN_SCALE = 0.9999950000374997f;

typedef unsigned short ushort_t;
typedef float f32x4 __attribute__((ext_vector_type(4)));
typedef short bf16x8 __attribute__((ext_vector_type(8)));

__device__ __forceinline__ ushort_t f2bfu(float f) {
  union { float f; unsigned u; } v; v.f = f;
  unsigned r = v.u + 0x7fffu + ((v.u >> 16) & 1u);
  return (ushort_t)(r >> 16);
}

// ---- fallback sentinel if workspace is too small ---------------------------
__global__ void fill_out(float* out, int n) {
  int i = blockIdx.x * 256 + threadIdx.x;
  if (i < n) out[i] = 0.25f;
}

// ============================================================================
// Fused conv1+pool+conv2+pool via MFMA implicit GEMM.
// 2 images/block. Phase 1: conv1 (fp32) -> leaky -> pool -> sh1 (bf16, LDS).
// Phase 2: im2col K-loop (K=500 pad 512, chunk 64), M=128 (2img x 64 pos),
// N=64 (50 oc pad), mfma 16x16x32 bf16. Epilogue: C->LDS fp32, bias+leaky+
// 2x2 maxpool -> out800[img][oc*16+p].
// LDS union: sh1 11520B | As 18432B (128x72 us) | Bs 9216B (64x72 us);
// phase1 simg/sw1 and epilogue C alias these regions. Total 39168B.
// ============================================================================
__launch_bounds__(256)
__global__ void conv12_mfma(const float* __restrict__ img, const float* __restrict__ w1,
                            const float* __restrict__ b1, const float* __restrict__ w2,
                            const float* __restrict__ b2, float* __restrict__ out800) {
  __shared__ __align__(16) char smem[39168];
  ushort_t* sh1u = (ushort_t*)smem;                 // [2*2880]
  float* simg = (float*)(smem + 11520);             // [2*784] (phase 1)
  float* sw1  = (float*)(smem + 11520 + 6272);      // [500]   (phase 1)
  ushort_t* As = (ushort_t*)(smem + 11520);         // [128*72] (phase 2)
  ushort_t* Bs = (ushort_t*)(smem + 29952);         // [64*72]  (phase 2)
  float* Cf = (float*)smem;                         // [128*68] (epilogue)

  int tid = threadIdx.x;
  const float* imgb = img + (size_t)blockIdx.x * 2 * 784;

  // ---- phase 1: conv1 ----
  for (int i = tid; i < 1568; i += 256) simg[i] = imgb[i];
  for (int i = tid; i < 500; i += 256) sw1[i] = w1[i];
  __syncthreads();
  for (int o = tid; o < 5760; o += 256) {
    int im = o / 2880, oi = o % 2880;
    int c = oi / 144, rem = oi % 144, py = rem / 12, px = rem % 12;
    int y0 = py * 2, x0 = px * 2;
    const float* sb = &simg[im * 784];
    float p[6][6];
    #pragma unroll
    for (int yy = 0; yy < 6; ++yy)
      #pragma unroll
      for (int xx = 0; xx < 6; ++xx)
        p[yy][xx] = sb[(y0 + yy) * 28 + x0 + xx];
    float bb = b1[c];
    float t0 = bb, t1 = bb, t2 = bb, t3 = bb;
    const float* wc = &sw1[c * 25];
    #pragma unroll
    for (int ky = 0; ky < 5; ++ky)
      #pragma unroll
      for (int kx = 0; kx < 5; ++kx) {
        float wv = wc[ky * 5 + kx];
        t0 += p[ky][kx] * wv;
        t1 += p[ky][kx + 1] * wv;
        t2 += p[ky + 1][kx] * wv;
        t3 += p[ky + 1][kx + 1] * wv;
      }
    t0 = LEAKY(t0); t1 = LEAKY(t1); t2 = LEAKY(t2); t3 = LEAKY(t3);
    sh1u[o] = f2bfu(fmaxf(fmaxf(t0, t1), fmaxf(t2, t3)));
  }

  // ---- phase 2: implicit GEMM ----
  int wave = tid >> 6, lane = tid & 63;
  int wm = (wave >> 1) * 64, wn = (wave & 1) * 32;
  int mrow = lane & 15, kq = lane >> 4;
  int kl = tid & 63, rbase = tid >> 6;

  f32x4 acc[4][2];
  #pragma unroll
  for (int i = 0; i < 4; ++i)
    #pragma unroll
    for (int j = 0; j < 2; ++j)
      #pragma unroll
      for (int r = 0; r < 4; ++r) acc[i][j][r] = 0.f;

  for (int k0 = 0; k0 < 512; k0 += 64) {
    __syncthreads();  // guards sh1 ready (1st) / frag reads of prev iter
    int k = k0 + kl;
    bool valid = k < 500;
    int ic = k / 25, tap = k - ic * 25;
    int ky = tap / 5, kx = tap - ky * 5;
    int kof = ic * 144 + ky * 12 + kx;
    for (int i = 0; i < 32; ++i) {
      int r = rbase + 4 * i;
      int im = r >> 6, pos = r & 63, oy = pos >> 3, ox = pos & 7;
      ushort_t v = valid ? sh1u[im * 2880 + kof + oy * 12 + ox] : (ushort_t)0;
      As[r * 72 + kl] = v;
    }
    for (int i = 0; i < 16; ++i) {
      int oc = rbase + 4 * i;
      ushort_t v = (valid && oc < 50) ? f2bfu(w2[(size_t)oc * 500 + k]) : (ushort_t)0;
      Bs[oc * 72 + kl] = v;
    }
    __syncthreads();
    #pragma unroll
    for (int ks = 0; ks < 2; ++ks) {
      bf16x8 af[4], bf[2];
      #pragma unroll
      for (int mt = 0; mt < 4; ++mt)
        af[mt] = *(const bf16x8*)&As[(wm + mt * 16 + mrow) * 72 + ks * 32 + kq * 8];
      #pragma unroll
      for (int nt = 0; nt < 2; ++nt)
        bf[nt] = *(const bf16x8*)&Bs[(wn + nt * 16 + mrow) * 72 + ks * 32 + kq * 8];
      #pragma unroll
      for (int mt = 0; mt < 4; ++mt)
        #pragma unroll
        for (int nt = 0; nt < 2; ++nt)
          acc[mt][nt] = __builtin_amdgcn_mfma_f32_16x16x32_bf16(af[mt], bf[nt], acc[mt][nt], 0, 0, 0);
    }
  }
  __syncthreads();  // all frag reads done before C overwrites LDS
  #pragma unroll
  for (int mt = 0; mt < 4; ++mt)
    #pragma unroll
    for (int nt = 0; nt < 2; ++nt) {
      int n0 = wn + nt * 16 + (lane & 15);
      #pragma unroll
      for (int r = 0; r < 4; ++r)
        Cf[(wm + mt * 16 + kq * 4 + r) * 68 + n0] = acc[mt][nt][r];
    }
  __syncthreads();
  // pooled epilogue
  for (int o = tid; o < 1600; o += 256) {
    int im = o / 800, oi = o - im * 800;
    int oc = oi >> 4, p = oi & 15, py = p >> 2, px = p & 3;
    int r0 = im * 64 + py * 16 + px * 2;
    float bb = b2[oc];
    float t0 = LEAKY(Cf[r0 * 68 + oc] + bb);
    float t1 = LEAKY(Cf[(r0 + 1) * 68 + oc] + bb);
    float t2 = LEAKY(Cf[(r0 + 8) * 68 + oc] + bb);
    float t3 = LEAKY(Cf[(r0 + 9) * 68 + oc] + bb);
    out800[(size_t)(blockIdx.x * 2 + im) * 800 + oi] = fmaxf(fmaxf(t0, t1), fmaxf(t2, t3));
  }
}

// ---------------- epilogue kinds -------------------------------------------
enum { EPI_NONE = 0, EPI_LEAKY = 1, EPI_LEAKY_BN = 2, EPI_TANH = 3, EPI_EUCLID = 4 };

#define LROW 40

// ---- 128x128 MFMA NT GEMM (M%128, N%128, K%32) ----------------------------
template <int EPI>
__launch_bounds__(256)
__global__ void gemm_mfma_nt(const float* __restrict__ A, const float* __restrict__ B,
                             const float* __restrict__ bias, float* __restrict__ C,
                             int M, int N, int Kd,
                             const float* __restrict__ e1, const float* __restrict__ e2) {
  __shared__ ushort_t As[128 * LROW];
  __shared__ ushort_t Bs[128 * LROW];
  int tid = threadIdx.x;
  int bm = blockIdx.y * 128, bn = blockIdx.x * 128;
  int wave = tid >> 6, lane = tid & 63;
  int wm = (wave >> 1) * 64, wn = (wave & 1) * 64;
  int mrow = lane & 15, kq = lane >> 4;
  int srow = tid >> 1, skof = (tid & 1) * 16;

  f32x4 acc[4][4];
  #pragma unroll
  for (int i = 0; i < 4; ++i)
    #pragma unroll
    for (int j = 0; j < 4; ++j)
      #pragma unroll
      for (int r = 0; r < 4; ++r) acc[i][j][r] = 0.f;

  for (int k0 = 0; k0 < Kd; k0 += 32) {
    const float4* ap = (const float4*)(A + (size_t)(bm + srow) * Kd + k0 + skof);
    const float4* bp = (const float4*)(B + (size_t)(bn + srow) * Kd + k0 + skof);
    float4 av[4], bv[4];
    #pragma unroll
    for (int i = 0; i < 4; ++i) av[i] = ap[i];
    #pragma unroll
    for (int i = 0; i < 4; ++i) bv[i] = bp[i];
    __syncthreads();
    ushort_t* wa = &As[srow * LROW + skof];
    ushort_t* wb = &Bs[srow * LROW + skof];
    #pragma unroll
    for (int i = 0; i < 4; ++i) {
      wa[i * 4 + 0] = f2bfu(av[i].x); wa[i * 4 + 1] = f2bfu(av[i].y);
      wa[i * 4 + 2] = f2bfu(av[i].z); wa[i * 4 + 3] = f2bfu(av[i].w);
      wb[i * 4 + 0] = f2bfu(bv[i].x); wb[i * 4 + 1] = f2bfu(bv[i].y);
      wb[i * 4 + 2] = f2bfu(bv[i].z); wb[i * 4 + 3] = f2bfu(bv[i].w);
    }
    __syncthreads();
    bf16x8 af[4], bf[4];
    #pragma unroll
    for (int mt = 0; mt < 4; ++mt)
      af[mt] = *(const bf16x8*)&As[(wm + mt * 16 + mrow) * LROW + kq * 8];
    #pragma unroll
    for (int nt = 0; nt < 4; ++nt)
      bf[nt] = *(const bf16x8*)&Bs[(wn + nt * 16 + mrow) * LROW + kq * 8];
    #pragma unroll
    for (int mt = 0; mt < 4; ++mt)
      #pragma unroll
      for (int nt = 0; nt < 4; ++nt)
        acc[mt][nt] = __builtin_amdgcn_mfma_f32_16x16x32_bf16(af[mt], bf[nt], acc[mt][nt], 0, 0, 0);
  }
  #pragma unroll
  for (int mt = 0; mt < 4; ++mt) {
    #pragma unroll
    for (int nt = 0; nt < 4; ++nt) {
      int n_g = bn + wn + nt * 16 + (lane & 15);
      #pragma unroll
      for (int r = 0; r < 4; ++r) {
        int m_g = bm + wm + mt * 16 + kq * 4 + r;
        float v = acc[mt][nt][r];
        if (EPI == EPI_EUCLID) {
          v = e1[m_g] + e2[n_g] - 2.f * v;
          v = sqrtf(fmaxf(v, 0.f));
        } else {
          if (bias) v += bias[n_g];
          if (EPI == EPI_LEAKY) v = LEAKY(v);
          else if (EPI == EPI_LEAKY_BN) { v = LEAKY(v); v *= BN_SCALE; }
          else if (EPI == EPI_TANH) v = tanhf(v);
        }
        C[(size_t)m_g * N + n_g] = v;
      }
    }
  }
}

// ---- 64x64 MFMA NT GEMM (M%64, N%64, K%32) — for skinny shapes ------------
template <int EPI>
__launch_bounds__(256)
__global__ void gemm_mfma_nt64(const float* __restrict__ A, const float* __restrict__ B,
                               const float* __restrict__ bias, float* __restrict__ C,
                               int M, int N, int Kd) {
  __shared__ ushort_t As[64 * LROW];
  __shared__ ushort_t Bs[64 * LROW];
  int tid = threadIdx.x;
  int bm = blockIdx.y * 64, bn = blockIdx.x * 64;
  int wave = tid >> 6, lane = tid & 63;
  int wm = (wave >> 1) * 32, wn = (wave & 1) * 32;
  int mrow = lane & 15, kq = lane >> 4;
  int srow = tid >> 2, skof = (tid & 3) * 8;

  f32x4 acc[2][2];
  #pragma unroll
  for (int i = 0; i < 2; ++i)
    #pragma unroll
    for (int j = 0; j < 2; ++j)
      #pragma unroll
      for (int r = 0; r < 4; ++r) acc[i][j][r] = 0.f;

  for (int k0 = 0; k0 < Kd; k0 += 32) {
    const float4* ap = (const float4*)(A + (size_t)(bm + srow) * Kd + k0 + skof);
    const float4* bp = (const float4*)(B + (size_t)(bn + srow) * Kd + k0 + skof);
    float4 av0 = ap[0], av1 = ap[1];
    float4 bv0 = bp[0], bv1 = bp[1];
    __syncthreads();
    ushort_t* wa = &As[srow * LROW + skof];
    ushort_t* wb = &Bs[srow * LROW + skof];
    wa[0] = f2bfu(av0.x); wa[1] = f2bfu(av0.y); wa[2] = f2bfu(av0.z); wa[3] = f2bfu(av0.w);
    wa[4] = f2bfu(av1.x); wa[5] = f2bfu(av1.y); wa[6] = f2bfu(av1.z); wa[7] = f2bfu(av1.w);
    wb[0] = f2bfu(bv0.x); wb[1] = f2bfu(bv0.y); wb[2] = f2bfu(bv0.z); wb[3] = f2bfu(bv0.w);
    wb[4] = f2bfu(bv1.x); wb[5] = f2bfu(bv1.y); wb[6] = f2bfu(bv1.z); wb[7] = f2bfu(bv1.w);
    __syncthreads();
    bf16x8 af[2], bf[2];
    #pragma unroll
    for (int mt = 0; mt < 2; ++mt)
      af[mt] = *(const bf16x8*)&As[(wm + mt * 16 + mrow) * LROW + kq * 8];
    #pragma unroll
    for (int nt = 0; nt < 2; ++nt)
      bf[nt] = *(const bf16x8*)&Bs[(wn + nt * 16 + mrow) * LROW + kq * 8];
    #pragma unroll
    for (int mt = 0; mt < 2; ++mt)
      #pragma unroll
      for (int nt = 0; nt < 2; ++nt)
        acc[mt][nt] = __builtin_amdgcn_mfma_f32_16x16x32_bf16(af[mt], bf[nt], acc[mt][nt], 0, 0, 0);
  }
  #pragma unroll
  for (int mt = 0; mt < 2; ++mt) {
    #pragma unroll
    for (int nt = 0; nt < 2; ++nt) {
      int n_g = bn + wn + nt * 16 + (lane & 15);
      #pragma unroll
      for (int r = 0; r < 4; ++r) {
        int m_g = bm + wm + mt * 16 + kq * 4 + r;
        float v = acc[mt][nt][r];
        if (bias) v += bias[n_g];
        if (EPI == EPI_LEAKY) v = LEAKY(v);
        else if (EPI == EPI_LEAKY_BN) { v = LEAKY(v); v *= BN_SCALE; }
        else if (EPI == EPI_TANH) v = tanhf(v);
        C[(size_t)m_g * N + n_g] = v;
      }
    }
  }
}

// ---- 128x128 MFMA NN GEMM + residual (C==R safe) --------------------------
__launch_bounds__(256)
__global__ void gemm_mfma_nn_res(const float* __restrict__ A, const float* __restrict__ B,
                                 const float* __restrict__ R, float* __restrict__ C,
                                 int M, int N, int Kd) {
  __shared__ ushort_t As[128 * LROW];
  __shared__ ushort_t Bs[128 * LROW];
  int tid = threadIdx.x;
  int bm = blockIdx.y * 128, bn = blockIdx.x * 128;
  int wave = tid >> 6, lane = tid & 63;
  int wm = (wave >> 1) * 64, wn = (wave & 1) * 64;
  int mrow = lane & 15, kq = lane >> 4;
  int srow = tid >> 1, skof = (tid & 1) * 16;
  int krow = tid >> 3, nof = (tid & 7) * 16;

  f32x4 acc[4][4];
  #pragma unroll
  for (int i = 0; i < 4; ++i)
    #pragma unroll
    for (int j = 0; j < 4; ++j)
      #pragma unroll
      for (int r = 0; r < 4; ++r) acc[i][j][r] = 0.f;

  for (int k0 = 0; k0 < Kd; k0 += 32) {
    const float4* ap = (const float4*)(A + (size_t)(bm + srow) * Kd + k0 + skof);
    const float4* bp = (const float4*)(B + (size_t)(k0 + krow) * N + bn + nof);
    float4 av[4], bv[4];
    #pragma unroll
    for (int i = 0; i < 4; ++i) av[i] = ap[i];
    #pragma unroll
    for (int i = 0; i < 4; ++i) bv[i] = bp[i];
    __syncthreads();
    ushort_t* wa = &As[srow * LROW + skof];
    #pragma unroll
    for (int i = 0; i < 4; ++i) {
      wa[i * 4 + 0] = f2bfu(av[i].x); wa[i * 4 + 1] = f2bfu(av[i].y);
      wa[i * 4 + 2] = f2bfu(av[i].z); wa[i * 4 + 3] = f2bfu(av[i].w);
      Bs[(nof + i * 4 + 0) * LROW + krow] = f2bfu(bv[i].x);
      Bs[(nof + i * 4 + 1) * LROW + krow] = f2bfu(bv[i].y);
      Bs[(nof + i * 4 + 2) * LROW + krow] = f2bfu(bv[i].z);
      Bs[(nof + i * 4 + 3) * LROW + krow] = f2bfu(bv[i].w);
    }
    __syncthreads();
    bf16x8 af[4], bf[4];
    #pragma unroll
    for (int mt = 0; mt < 4; ++mt)
      af[mt] = *(const bf16x8*)&As[(wm + mt * 16 + mrow) * LROW + kq * 8];
    #pragma unroll
    for (int nt = 0; nt < 4; ++nt)
      bf[nt] = *(const bf16x8*)&Bs[(wn + nt * 16 + mrow) * LROW + kq * 8];
    #pragma unroll
    for (int mt = 0; mt < 4; ++mt)
      #pragma unroll
      for (int nt = 0; nt < 4; ++nt)
        acc[mt][nt] = __builtin_amdgcn_mfma_f32_16x16x32_bf16(af[mt], bf[nt], acc[mt][nt], 0, 0, 0);
  }
  #pragma unroll
  for (int mt = 0; mt < 4; ++mt)
    #pragma unroll
    for (int nt = 0; nt < 4; ++nt) {
      int n_g = bn + wn + nt * 16 + (lane & 15);
      #pragma unroll
      for (int r = 0; r < 4; ++r) {
        int m_g = bm + wm + mt * 16 + kq * 4 + r;
        C[(size_t)m_g * N + n_g] = acc[mt][nt][r] + R[(size_t)m_g * N + n_g];
      }
    }
}

// ---- 64x64 MFMA NN GEMM + residual (C==R safe) ----------------------------
__launch_bounds__(256)
__global__ void gemm_mfma_nn_res64(const float* __restrict__ A, const float* __restrict__ B,
                                   const float* __restrict__ R, float* __restrict__ C,
                                   int M, int N, int Kd) {
  __shared__ ushort_t As[64 * LROW];
  __shared__ ushort_t Bs[64 * LROW];
  int tid = threadIdx.x;
  int bm = blockIdx.y * 64, bn = blockIdx.x * 64;
  int wave = tid >> 6, lane = tid & 63;
  int wm = (wave >> 1) * 32, wn = (wave & 1) * 32;
  int mrow = lane & 15, kq = lane >> 4;
  int srow = tid >> 2, skof = (tid & 3) * 8;
  int krow = tid >> 3, nof = (tid & 7) * 8;

  f32x4 acc[2][2];
  #pragma unroll
  for (int i = 0; i < 2; ++i)
    #pragma unroll
    for (int j = 0; j < 2; ++j)
      #pragma unroll
      for (int r = 0; r < 4; ++r) acc[i][j][r] = 0.f;

  for (int k0 = 0; k0 < Kd; k0 += 32) {
    const float4* ap = (const float4*)(A + (size_t)(bm + srow) * Kd + k0 + skof);
    const float4* bp = (const float4*)(B + (size_t)(k0 + krow) * N + bn + nof);
    float4 av0 = ap[0], av1 = ap[1];
    float4 bv0 = bp[0], bv1 = bp[1];
    __syncthreads();
    ushort_t* wa = &As[srow * LROW + skof];
    wa[0] = f2bfu(av0.x); wa[1] = f2bfu(av0.y); wa[2] = f2bfu(av0.z); wa[3] = f2bfu(av0.w);
    wa[4] = f2bfu(av1.x); wa[5] = f2bfu(av1.y); wa[6] = f2bfu(av1.z); wa[7] = f2bfu(av1.w);
    Bs[(nof + 0) * LROW + krow] = f2bfu(bv0.x);
    Bs[(nof + 1) * LROW + krow] = f2bfu(bv0.y);
    Bs[(nof + 2) * LROW + krow] = f2bfu(bv0.z);
    Bs[(nof + 3) * LROW + krow] = f2bfu(bv0.w);
    Bs[(nof + 4) * LROW + krow] = f2bfu(bv1.x);
    Bs[(nof + 5) * LROW + krow] = f2bfu(bv1.y);
    Bs[(nof + 6) * LROW + krow] = f2bfu(bv1.z);
    Bs[(nof + 7) * LROW + krow] = f2bfu(bv1.w);
    __syncthreads();
    bf16x8 af[2], bf[2];
    #pragma unroll
    for (int mt = 0; mt < 2; ++mt)
      af[mt] = *(const bf16x8*)&As[(wm + mt * 16 + mrow) * LROW + kq * 8];
    #pragma unroll
    for (int nt = 0; nt < 2; ++nt)
      bf[nt] = *(const bf16x8*)&Bs[(wn + nt * 16 + mrow) * LROW + kq * 8];
    #pragma unroll
    for (int mt = 0; mt < 2; ++mt)
      #pragma unroll
      for (int nt = 0; nt < 2; ++nt)
        acc[mt][nt] = __builtin_amdgcn_mfma_f32_16x16x32_bf16(af[mt], bf[nt], acc[mt][nt], 0, 0, 0);
  }
  #pragma unroll
  for (int mt = 0; mt < 2; ++mt)
    #pragma unroll
    for (int nt = 0; nt < 2; ++nt) {
      int n_g = bn + wn + nt * 16 + (lane & 15);
      #pragma unroll
      for (int r = 0; r < 4; ++r) {
        int m_g = bm + wm + mt * 16 + kq * 4 + r;
        C[(size_t)m_g * N + n_g] = acc[mt][nt][r] + R[(size_t)m_g * N + n_g];
      }
    }
}

// ---- split-K TN GEMM (Mm = X1^T @ X2, 128x128, K=2048) --------------------
__global__ void gemm_tn_part(const float* __restrict__ A, const float* __restrict__ B,
                             float* __restrict__ part) {
  int tx = threadIdx.x & 15, ty = threadIdx.x >> 4;
  int i = blockIdx.y * 16 + ty, j = blockIdx.x * 16 + tx;
  int ks = blockIdx.z;
  float acc = 0.f;
  for (int k = ks * 128; k < ks * 128 + 128; ++k)
    acc += A[(size_t)k * 128 + i] * B[(size_t)k * 128 + j];
  part[(size_t)ks * 16384 + i * 128 + j] = acc;
}
__global__ void gemm_tn_reduce(const float* __restrict__ part, float* __restrict__ Mm) {
  int idx = blockIdx.x * 256 + threadIdx.x;
  float s = 0.f;
  #pragma unroll
  for (int ks = 0; ks < 16; ++ks) s += part[(size_t)ks * 16384 + idx];
  Mm[idx] = s;
}

// ---- column softmax (axis 0) in-place -------------------------------------
__global__ void softmax_col(float* __restrict__ S, int M, int N) {
  int t = threadIdx.x;
  int cl = t & 15, g = t >> 4;
  int c = blockIdx.x * 16 + cl;
  __shared__ float red[16][17];
  float m = -1e30f;
  for (int r = g; r < M; r += 16) m = fmaxf(m, S[(size_t)r * N + c]);
  red[g][cl] = m;
  __syncthreads();
  for (int off = 8; off; off >>= 1) { if (g < off) red[g][cl] = fmaxf(red[g][cl], red[g + off][cl]); __syncthreads(); }
  m = red[0][cl];
  __syncthreads();
  float sum = 0.f;
  for (int r = g; r < M; r += 16) sum += expf(S[(size_t)r * N + c] - m);
  red[g][cl] = sum;
  __syncthreads();
  for (int off = 8; off; off >>= 1) { if (g < off) red[g][cl] += red[g + off][cl]; __syncthreads(); }
  sum = red[0][cl];
  float inv = 1.f / sum;
  for (int r = g; r < M; r += 16) {
    size_t i = (size_t)r * N + c;
    S[i] = expf(S[i] - m) * inv;
  }
}

// ---- row squared-norms ----------------------------------------------------
__global__ void row_norm(const float* __restrict__ X, float* __restrict__ out, int Kd) {
  int r = blockIdx.x;
  int t = threadIdx.x;
  float s = 0.f;
  for (int k = t; k < Kd; k += 64) { float v = X[(size_t)r * Kd + k]; s += v * v; }
  for (int off = 32; off; off >>= 1) s += __shfl_down(s, off);
  if (t == 0) out[r] = s;
}

// ---- mask scores ----------------------------------------------------------
__global__ void mask_score(const float* __restrict__ A3, const float* __restrict__ w4,
                           const float* __restrict__ b4, float* __restrict__ s) {
  int k = blockIdx.x * 256 + threadIdx.x;
  float acc = b4[0];
  for (int h = 0; h < 128; ++h) acc += A3[(size_t)h * 2048 + k] * w4[h];
  s[k] = acc;
}

// ---- stable descending-argsort rank -> top-S indices ----------------------
__global__ void topk_rank(const float* __restrict__ s, int* __restrict__ idx, int K, int S) {
  int j = blockIdx.x * 256 + threadIdx.x;
  if (j >= K) return;
  float sj = s[j];
  int rank = 0;
  for (int i = 0; i < K; ++i) {
    float si = s[i];
    rank += (si > sj) || (si == sj && i < j);
  }
  if (rank < S) idx[rank] = j;
}

// ---- build cat = [B_dt | softmax(aff_s[:,idx],axis=1) | 0pad] stride 512 --
__global__ void build_cat(const float* __restrict__ Bdt, const float* __restrict__ affs,
                          const int* __restrict__ idx, float* __restrict__ cat) {
  int r = blockIdx.x, t = threadIdx.x;
  __shared__ float vals[256];
  __shared__ float red[256];
  float v = -1e30f;
  if (t < 204) {
    int ix = idx[t];
    ix = ix < 0 ? 0 : (ix > 2047 ? 2047 : ix);
    v = affs[(size_t)r * 2048 + ix];
  }
  vals[t] = v;
  red[t] = v;
  __syncthreads();
  for (int off = 128; off; off >>= 1) { if (t < off) red[t] = fmaxf(red[t], red[t + off]); __syncthreads(); }
  float m = red[0];
  __syncthreads();
  float e = (t < 204) ? expf(vals[t] - m) : 0.f;
  red[t] = e;
  __syncthreads();
  for (int off = 128; off; off >>= 1) { if (t < off) red[t] += red[t + off]; __syncthreads(); }
  float inv = 1.f / red[0];
  cat[(size_t)r * 512 + t] = Bdt[(size_t)r * 256 + t];
  if (t < 204) cat[(size_t)r * 512 + 256 + t] = e * inv;
  else cat[(size_t)r * 512 + 256 + t] = 0.f;
}

// ---- pad fuse_w [256,460] -> [256,512] ------------------------------------
__global__ void pad_fuse(const float* __restrict__ w, float* __restrict__ wp) {
  int idx = blockIdx.x * 256 + threadIdx.x;
  if (idx >= 256 * 512) return;
  int o = idx >> 9, k = idx & 511;
  wp[idx] = (k < 460) ? w[(size_t)o * 460 + k] : 0.f;
}

// ---- a = leaky((AV*AU) @ aww.T + awb) -------------------------------------
__global__ void attn_gate(const float* __restrict__ AV, const float* __restrict__ AU,
                          const float* __restrict__ aww, const float* __restrict__ awb,
                          float* __restrict__ a, int n) {
  int r = blockIdx.x * 256 + threadIdx.x;
  if (r >= n) return;
  float acc = awb[0];
  for (int d = 0; d < 128; ++d) acc += AV[(size_t)r * 128 + d] * AU[(size_t)r * 128 + d] * aww[d];
  a[r] = LEAKY(acc);
}

// ---- 1-D softmax (single block) -------------------------------------------
__global__ void softmax_vec(const float* __restrict__ x, float* __restrict__ y,
                            float* __restrict__ y2, int n) {
  __shared__ float red[256];
  int t = threadIdx.x;
  float m = -1e30f;
  for (int i = t; i < n; i += 256) m = fmaxf(m, x[i]);
  red[t] = m;
  __syncthreads();
  for (int off = 128; off; off >>= 1) { if (t < off) red[t] = fmaxf(red[t], red[t + off]); __syncthreads(); }
  m = red[0];
  __syncthreads();
  float s = 0.f;
  for (int i = t; i < n; i += 256) s += expf(x[i] - m);
  red[t] = s;
  __syncthreads();
  for (int off = 128; off; off >>= 1) { if (t < off) red[t] += red[t + off]; __syncthreads(); }
  float inv = 1.f / red[0];
  for (int i = t; i < n; i += 256) {
    float v = expf(x[i] - m) * inv;
    y[i] = v;
    if (y2) y2[i] = v;
  }
}

// ---- weighted column sum, two-stage ---------------------------------------
__global__ void colsum_part(const float* __restrict__ wv, const float* __restrict__ H,
                            float* __restrict__ part, int n) {
  int bk = blockIdx.x, c = threadIdx.x;
  float s = 0.f;
  for (int r = bk; r < n; r += 16) s += wv[r] * H[(size_t)r * 256 + c];
  part[bk * 256 + c] = s;
}
__global__ void colsum_fin(const float* __restrict__ part, float* __restrict__ out) {
  int c = threadIdx.x;
  float s = 0.f;
  #pragma unroll
  for (int k = 0; k < 16; ++k) s += part[k * 256 + c];
  out[c] = s;
}

// ---- small gemv -----------------------------------------------------------
__global__ void gemv_act(const float* __restrict__ x, const float* __restrict__ W,
                         const float* __restrict__ b, float* __restrict__ out,
                         int O, int Kd, int act) {
  int o = blockIdx.x * blockDim.x + threadIdx.x;
  if (o >= O) return;
  float acc = b ? b[o] : 0.f;
  for (int k = 0; k < Kd; ++k) acc += x[k] * W[(size_t)o * Kd + k];
  if (act == 1) acc = LEAKY(acc);
  out[o] = acc;
}

// ---- cat2 = [B_fuse | tile(M1)] -------------------------------------------
__global__ void build_cat2(const float* __restrict__ Bf, const float* __restrict__ M1,
                           float* __restrict__ cat2) {
  int r = blockIdx.x, t = threadIdx.x;
  cat2[(size_t)r * 512 + t] = (t < 256) ? Bf[(size_t)r * 256 + t] : M1[t - 256];
}

// ---- final head -----------------------------------------------------------
__global__ void final_head(const float* __restrict__ AH2, const float* __restrict__ embw,
                           const float* __restrict__ embb, const float* __restrict__ sembw,
                           const float* __restrict__ sembb, const float* __restrict__ clsw,
                           const float* __restrict__ clsb, float* __restrict__ Yout) {
  __shared__ float bvec[512];
  __shared__ float red[512];
  int t = threadIdx.x;
  float acc = embb[t];
  for (int c = 0; c < 256; ++c) acc += AH2[c] * embw[(size_t)t * 256 + c];
  bvec[t] = LEAKY(acc);
  __syncthreads();
  float p = 0.f;
  if (t < 256) {
    float a2 = sembb[t];
    for (int c = 0; c < 512; ++c) a2 += bvec[c] * sembw[(size_t)t * 512 + c];
    a2 = LEAKY(a2);
    p = a2 * clsw[t];
  }
  red[t] = p;
  __syncthreads();
  for (int off = 256; off; off >>= 1) { if (t < off) red[t] += red[t + off]; __syncthreads(); }
  if (t == 0) {
    float y = red[0] + clsb[0];
    y = 1.f / (1.f + expf(-y));
    y = fminf(fmaxf(y, 1e-5f), 1.f - 1e-5f);
    Yout[0] = y;
  }
}

extern "C" void kernel_launch(void* const* d_in, const int* in_sizes, int n_in,
                              void* d_out, int out_size, void* d_ws, size_t ws_size,
                              hipStream_t stream) {
  auto IN = [&](int i) { return (const float*)d_in[i]; };
  (void)n_in; (void)in_sizes; (void)out_size;

  const int S = 204;
  float* out_f = (float*)d_out;  // out[0]=Y, out[1..2048]=A

  float* W = (float*)d_ws;
  size_t off = 0;
  auto F = [&](size_t n) { float* p = W + off; off += n; return p; };

  float* dt    = F((size_t)4096 * 256);
  float* Xs    = F((size_t)2048 * 256);
  float* Ks    = F((size_t)2048 * 256);
  float* X1    = F((size_t)2048 * 128);
  float* X2    = F((size_t)2048 * 128);
  float* X3s   = F((size_t)2048 * 256);   // skip1/2 X3; later Bfuse
  float* aff   = F((size_t)2048 * 2048);  // euclid out; skip3 in-place
  float* AV    = F((size_t)2048 * 128);
  float* AU    = F((size_t)2048 * 128);
  float* Mm    = F((size_t)128 * 128);
  float* svec  = F(2048);
  int*   idxb  = (int*)F(256);
  float* avec  = F(2048);
  float* Awv   = F(2048);
  float* AH    = F(256);
  float* M1v   = F(256);
  float* AH2   = F(256);
  float* nx    = F(2048);
  float* ny    = F(2048);
  float* part  = F(4096);
  float* pool  = F((size_t)8388608);      // 32 MB phase-shared pool

  const size_t NEED_BYTES = off * 4;
  if (ws_size < NEED_BYTES) {
    fill_out<<<9, 256, 0, stream>>>(out_f, 2049);
    return;
  }

  // pool members (phase-disjoint)
  float* h2h   = pool;                 // conv: 2048*800
  float* Smat  = pool;                 // skip: 2048*2048
  float* X3b   = pool + 4194304;       // skip3: 2048*2048
  float* A3    = pool;                 // mask: 128*2048
  float* tnpt  = pool + 4194304;       // mask: 16*16384 split-K partials
  float* cat   = pool;                 // fuse: 2048*512
  float* cat2  = pool + 1048576;       // 2048*512
  float* Hbuf  = pool + 2097152;       // 2048*256
  float* fwpad = pool + 2621440;       // 256*512

  float* Bfuse = X3s;

  // ---- data_transform for B (g=0) and KB (g=1) ----
  for (int g = 0; g < 2; ++g) {
    conv12_mfma<<<1024, 256, 0, stream>>>(IN(g), IN(2), IN(3), IN(4), IN(5), h2h);
    gemm_mfma_nt64<EPI_LEAKY><<<dim3(4, 32), 256, 0, stream>>>(
        h2h, IN(6), IN(7), dt + (size_t)g * 2048 * 256, 2048, 256, 800);
  }
  float* B_dt = dt;
  float* KB_dt = dt + (size_t)2048 * 256;

  // ---- skip_block 1 (B_dt -> Xs) and 2 (KB_dt -> Ks) ----
  for (int g = 0; g < 2; ++g) {
    float* Xin = g ? KB_dt : B_dt;
    float* Xout = g ? Ks : Xs;
    int wi = g ? 14 : 8;
    gemm_mfma_nt64<EPI_LEAKY_BN><<<dim3(2, 32), 256, 0, stream>>>(
        Xin, IN(wi + 0), IN(wi + 1), X1, 2048, 128, 256);
    gemm_mfma_nt64<EPI_LEAKY_BN><<<dim3(2, 32), 256, 0, stream>>>(
        Xin, IN(wi + 2), IN(wi + 3), X2, 2048, 128, 256);
    gemm_mfma_nt64<EPI_LEAKY_BN><<<dim3(4, 32), 256, 0, stream>>>(
        Xin, IN(wi + 4), IN(wi + 5), X3s, 2048, 256, 256);
    gemm_mfma_nt<EPI_NONE><<<dim3(16, 16), 256, 0, stream>>>(
        X1, X2, nullptr, Smat, 2048, 2048, 128, nullptr, nullptr);
    softmax_col<<<128, 256, 0, stream>>>(Smat, 2048, 2048);
    gemm_mfma_nn_res64<<<dim3(4, 32), 256, 0, stream>>>(Smat, X3s, Xin, Xout, 2048, 256, 2048);
  }

  // ---- euclid -> aff ----
  row_norm<<<2048, 64, 0, stream>>>(Xs, nx, 256);
  row_norm<<<2048, 64, 0, stream>>>(Ks, ny, 256);
  gemm_mfma_nt<EPI_EUCLID><<<dim3(16, 16), 256, 0, stream>>>(
      Xs, Ks, nullptr, aff, 2048, 2048, 256, nx, ny);

  // ---- skip_block 3 (aff -> aff in-place) ----
  gemm_mfma_nt64<EPI_LEAKY_BN><<<dim3(2, 32), 256, 0, stream>>>(
      aff, IN(20), IN(21), X1, 2048, 128, 2048);
  gemm_mfma_nt64<EPI_LEAKY_BN><<<dim3(2, 32), 256, 0, stream>>>(
      aff, IN(22), IN(23), X2, 2048, 128, 2048);
  gemm_mfma_nt<EPI_LEAKY_BN><<<dim3(16, 16), 256, 0, stream>>>(
      aff, IN(24), IN(25), X3b, 2048, 2048, 2048, nullptr, nullptr);
  gemm_mfma_nt<EPI_NONE><<<dim3(16, 16), 256, 0, stream>>>(
      X1, X2, nullptr, Smat, 2048, 2048, 128, nullptr, nullptr);
  softmax_col<<<128, 256, 0, stream>>>(Smat, 2048, 2048);
  gemm_mfma_nn_res<<<dim3(16, 16), 256, 0, stream>>>(Smat, X3b, aff, aff, 2048, 2048, 2048);
  float* aff_s = aff;

  // ---- mask_scores -> top-S idx ----
  gemm_mfma_nt64<EPI_LEAKY><<<dim3(2, 32), 256, 0, stream>>>(
      aff_s, IN(26), IN(27), X1, 2048, 128, 2048);
  gemm_mfma_nt64<EPI_TANH><<<dim3(2, 32), 256, 0, stream>>>(
      aff_s, IN(28), IN(29), X2, 2048, 128, 2048);
  gemm_tn_part<<<dim3(8, 8, 16), 256, 0, stream>>>(X1, X2, tnpt);
  gemm_tn_reduce<<<64, 256, 0, stream>>>(tnpt, Mm);
  gemm_mfma_nt64<EPI_LEAKY><<<dim3(32, 2), 256, 0, stream>>>(
      Mm, IN(30), IN(31), A3, 128, 2048, 128);
  mask_score<<<8, 256, 0, stream>>>(A3, IN(32), IN(33), svec);
  topk_rank<<<8, 256, 0, stream>>>(svec, idxb, 2048, S);

  // ---- B_bag + concat (pad to 512) + fuse ----
  build_cat<<<2048, 256, 0, stream>>>(B_dt, aff_s, idxb, cat);
  pad_fuse<<<512, 256, 0, stream>>>(IN(34), fwpad);
  gemm_mfma_nt64<EPI_LEAKY><<<dim3(4, 32), 256, 0, stream>>>(
      cat, fwpad, IN(35), Bfuse, 2048, 256, 512);

  // ---- attention 1 ----
  gemm_mfma_nt64<EPI_LEAKY><<<dim3(4, 32), 256, 0, stream>>>(
      Bfuse, IN(36), IN(37), Hbuf, 2048, 256, 256);
  gemm_mfma_nt64<EPI_TANH><<<dim3(2, 32), 256, 0, stream>>>(
      Hbuf, IN(38), IN(39), AV, 2048, 128, 256);
  gemm_mfma_nt64<EPI_LEAKY><<<dim3(2, 32), 256, 0, stream>>>(
      Hbuf, IN(40), IN(41), AU, 2048, 128, 256);
  attn_gate<<<8, 256, 0, stream>>>(AV, AU, IN(42), IN(43), avec, 2048);
  softmax_vec<<<1, 256, 0, stream>>>(avec, Awv, nullptr, 2048);
  colsum_part<<<16, 256, 0, stream>>>(Awv, Hbuf, part, 2048);
  colsum_fin<<<1, 256, 0, stream>>>(part, AH);
  gemv_act<<<1, 256, 0, stream>>>(AH, IN(44), IN(45), M1v, 256, 256, 1);
  build_cat2<<<2048, 512, 0, stream>>>(Bfuse, M1v, cat2);

  // ---- attention 2 (A -> output) ----
  gemm_mfma_nt64<EPI_LEAKY><<<dim3(4, 32), 256, 0, stream>>>(
      cat2, IN(46), IN(47), Hbuf, 2048, 256, 512);
  gemm_mfma_nt64<EPI_TANH><<<dim3(2, 32), 256, 0, stream>>>(
      Hbuf, IN(48), IN(49), AV, 2048, 128, 256);
  gemm_mfma_nt64<EPI_LEAKY><<<dim3(2, 32), 256, 0, stream>>>(
      Hbuf, IN(50), IN(51), AU, 2048, 128, 256);
  attn_gate<<<8, 256, 0, stream>>>(AV, AU, IN(52), IN(53), avec, 2048);
  softmax_vec<<<1, 256, 0, stream>>>(avec, Awv, out_f + 1, 2048);
  colsum_part<<<16, 256, 0, stream>>>(Awv, Hbuf, part, 2048);
  colsum_fin<<<1, 256, 0, stream>>>(part, AH2);

  // ---- final head -> Y ----
  final_head<<<1, 512, 0, stream>>>(AH2, IN(54), IN(55), IN(56), IN(57),
                                    IN(58), IN(59), out_f);
}

// Round 7
// 1510.654 us; speedup vs baseline: 6.6905x; 1.1746x over previous
//
#include <hip/hip_runtime.h>
#include <math.h>

#define LEAKY(x) ((x) > 0.f ? (x) : 0.01f * (x))
static constexpr float BN_SCALE = 0.9999950000374997f;

typedef unsigned short ushort_t;
typedef float f32x4 __attribute__((ext_vector_type(4)));
typedef short bf16x8 __attribute__((ext_vector_type(8)));

__device__ __forceinline__ ushort_t f2bfu(float f) {
  union { float f; unsigned u; } v; v.f = f;
  unsigned r = v.u + 0x7fffu + ((v.u >> 16) & 1u);
  return (ushort_t)(r >> 16);
}
__device__ __forceinline__ float bfu2f(ushort_t u) {
  union { unsigned u; float f; } v; v.u = ((unsigned)u) << 16;
  return v.f;
}

// ---- fallback sentinel if workspace is too small ---------------------------
__global__ void fill_out(float* out, int n) {
  int i = blockIdx.x * 256 + threadIdx.x;
  if (i < n) out[i] = 0.25f;
}

// ---- one-shot fp32 -> bf16 conversion of up to 20 tensors -----------------
struct CvtArgs {
  const float* src[20];
  ushort_t* dst[20];
  int len[20];
};
__global__ void to_bf16_multi(CvtArgs a) {
  for (int s = 0; s < 20; ++s) {
    const float* sp = a.src[s];
    ushort_t* dp = a.dst[s];
    int n = a.len[s];
    for (int i = blockIdx.x * 256 + threadIdx.x; i < n; i += gridDim.x * 256)
      dp[i] = f2bfu(sp[i]);
  }
}

// ---- pad fuse_w [256,460] fp32 -> [256,512] bf16 --------------------------
__global__ void pad_fuse_bf16(const float* __restrict__ w, ushort_t* __restrict__ wp) {
  int idx = blockIdx.x * 256 + threadIdx.x;
  if (idx >= 256 * 512) return;
  int o = idx >> 9, k = idx & 511;
  wp[idx] = (k < 460) ? f2bfu(w[(size_t)o * 460 + k]) : (ushort_t)0;
}

// ============================================================================
// Fused conv1+pool+conv2+pool via MFMA implicit GEMM. 2 images/block.
// As staging uses register buffer to break LDS read->write dependency chain.
// ============================================================================
__launch_bounds__(256)
__global__ void conv12_mfma(const float* __restrict__ img, const float* __restrict__ w1,
                            const float* __restrict__ b1, const ushort_t* __restrict__ w2b,
                            const float* __restrict__ b2, ushort_t* __restrict__ out800) {
  __shared__ __align__(16) char smem[39168];
  ushort_t* sh1u = (ushort_t*)smem;                 // [2*2880]
  float* simg = (float*)(smem + 11520);             // [2*784] (phase 1)
  float* sw1  = (float*)(smem + 11520 + 6272);      // [500]   (phase 1)
  ushort_t* As = (ushort_t*)(smem + 11520);         // [128*72] (phase 2)
  ushort_t* Bs = (ushort_t*)(smem + 29952);         // [64*72]  (phase 2)
  float* Cf = (float*)smem;                         // [128*68] (epilogue)

  int tid = threadIdx.x;
  const float* imgb = img + (size_t)blockIdx.x * 2 * 784;

  // ---- phase 1: conv1 -> leaky -> pool -> sh1 (bf16) ----
  for (int i = tid; i < 1568; i += 256) simg[i] = imgb[i];
  for (int i = tid; i < 500; i += 256) sw1[i] = w1[i];
  __syncthreads();
  for (int o = tid; o < 5760; o += 256) {
    int im = o / 2880, oi = o % 2880;
    int c = oi / 144, rem = oi % 144, py = rem / 12, px = rem % 12;
    int y0 = py * 2, x0 = px * 2;
    const float* sb = &simg[im * 784];
    float p[6][6];
    #pragma unroll
    for (int yy = 0; yy < 6; ++yy)
      #pragma unroll
      for (int xx = 0; xx < 6; ++xx)
        p[yy][xx] = sb[(y0 + yy) * 28 + x0 + xx];
    float bb = b1[c];
    float t0 = bb, t1 = bb, t2 = bb, t3 = bb;
    const float* wc = &sw1[c * 25];
    #pragma unroll
    for (int ky = 0; ky < 5; ++ky)
      #pragma unroll
      for (int kx = 0; kx < 5; ++kx) {
        float wv = wc[ky * 5 + kx];
        t0 += p[ky][kx] * wv;
        t1 += p[ky][kx + 1] * wv;
        t2 += p[ky + 1][kx] * wv;
        t3 += p[ky + 1][kx + 1] * wv;
      }
    t0 = LEAKY(t0); t1 = LEAKY(t1); t2 = LEAKY(t2); t3 = LEAKY(t3);
    sh1u[o] = f2bfu(fmaxf(fmaxf(t0, t1), fmaxf(t2, t3)));
  }

  // ---- phase 2: implicit GEMM ----
  int wave = tid >> 6, lane = tid & 63;
  int wm = (wave >> 1) * 64, wn = (wave & 1) * 32;
  int mrow = lane & 15, kq = lane >> 4;
  int kl = tid & 63, rbase = tid >> 6;

  f32x4 acc[4][2];
  #pragma unroll
  for (int i = 0; i < 4; ++i)
    #pragma unroll
    for (int j = 0; j < 2; ++j)
      #pragma unroll
      for (int r = 0; r < 4; ++r) acc[i][j][r] = 0.f;

  for (int k0 = 0; k0 < 512; k0 += 64) {
    __syncthreads();
    int k = k0 + kl;
    bool valid = k < 500;
    int ic = k / 25, tap = k - ic * 25;
    int ky = tap / 5, kx = tap - ky * 5;
    int kof = ic * 144 + ky * 12 + kx;
    // read phase (independent LDS loads into registers)
    ushort_t tA[32];
    #pragma unroll
    for (int i = 0; i < 32; ++i) {
      int r = rbase + 4 * i;
      int im = r >> 6, pos = r & 63, oy = pos >> 3, ox = pos & 7;
      tA[i] = valid ? sh1u[im * 2880 + kof + oy * 12 + ox] : (ushort_t)0;
    }
    ushort_t tB[16];
    #pragma unroll
    for (int i = 0; i < 16; ++i) {
      int oc = rbase + 4 * i;
      tB[i] = (valid && oc < 50) ? w2b[(size_t)oc * 500 + k] : (ushort_t)0;
    }
    // write phase
    #pragma unroll
    for (int i = 0; i < 32; ++i) As[(rbase + 4 * i) * 72 + kl] = tA[i];
    #pragma unroll
    for (int i = 0; i < 16; ++i) Bs[(rbase + 4 * i) * 72 + kl] = tB[i];
    __syncthreads();
    #pragma unroll
    for (int ks = 0; ks < 2; ++ks) {
      bf16x8 af[4], bf[2];
      #pragma unroll
      for (int mt = 0; mt < 4; ++mt)
        af[mt] = *(const bf16x8*)&As[(wm + mt * 16 + mrow) * 72 + ks * 32 + kq * 8];
      #pragma unroll
      for (int nt = 0; nt < 2; ++nt)
        bf[nt] = *(const bf16x8*)&Bs[(wn + nt * 16 + mrow) * 72 + ks * 32 + kq * 8];
      #pragma unroll
      for (int mt = 0; mt < 4; ++mt)
        #pragma unroll
        for (int nt = 0; nt < 2; ++nt)
          acc[mt][nt] = __builtin_amdgcn_mfma_f32_16x16x32_bf16(af[mt], bf[nt], acc[mt][nt], 0, 0, 0);
    }
  }
  __syncthreads();
  #pragma unroll
  for (int mt = 0; mt < 4; ++mt)
    #pragma unroll
    for (int nt = 0; nt < 2; ++nt) {
      int n0 = wn + nt * 16 + (lane & 15);
      #pragma unroll
      for (int r = 0; r < 4; ++r)
        Cf[(wm + mt * 16 + kq * 4 + r) * 68 + n0] = acc[mt][nt][r];
    }
  __syncthreads();
  for (int o = tid; o < 1600; o += 256) {
    int im = o / 800, oi = o - im * 800;
    int oc = oi >> 4, p = oi & 15, py = p >> 2, px = p & 3;
    int r0 = im * 64 + py * 16 + px * 2;
    float bb = b2[oc];
    float t0 = LEAKY(Cf[r0 * 68 + oc] + bb);
    float t1 = LEAKY(Cf[(r0 + 1) * 68 + oc] + bb);
    float t2 = LEAKY(Cf[(r0 + 8) * 68 + oc] + bb);
    float t3 = LEAKY(Cf[(r0 + 9) * 68 + oc] + bb);
    out800[(size_t)(blockIdx.x * 2 + im) * 800 + oi] = f2bfu(fmaxf(fmaxf(t0, t1), fmaxf(t2, t3)));
  }
}

// ---------------- epilogue kinds -------------------------------------------
enum { EPI_NONE = 0, EPI_LEAKY = 1, EPI_LEAKY_BN = 2, EPI_TANH = 3, EPI_EUCLID = 4 };

#define LROW 40

// ---- 128x128 bf16 NT GEMM (M%128, N%128, K%32). Dual store C32/C16 --------
template <int EPI>
__launch_bounds__(256)
__global__ void gemm_bf16_nt(const ushort_t* __restrict__ A, const ushort_t* __restrict__ B,
                             const float* __restrict__ bias, float* __restrict__ C32,
                             ushort_t* __restrict__ C16, int M, int N, int Kd,
                             const float* __restrict__ e1, const float* __restrict__ e2) {
  __shared__ ushort_t As[128 * LROW];
  __shared__ ushort_t Bs[128 * LROW];
  int tid = threadIdx.x;
  int bm = blockIdx.y * 128, bn = blockIdx.x * 128;
  int wave = tid >> 6, lane = tid & 63;
  int wm = (wave >> 1) * 64, wn = (wave & 1) * 64;
  int mrow = lane & 15, kq = lane >> 4;
  int srow = tid >> 1, skof = (tid & 1) * 16;

  f32x4 acc[4][4];
  #pragma unroll
  for (int i = 0; i < 4; ++i)
    #pragma unroll
    for (int j = 0; j < 4; ++j)
      #pragma unroll
      for (int r = 0; r < 4; ++r) acc[i][j][r] = 0.f;

  for (int k0 = 0; k0 < Kd; k0 += 32) {
    const uint4* ap = (const uint4*)(A + (size_t)(bm + srow) * Kd + k0 + skof);
    const uint4* bp = (const uint4*)(B + (size_t)(bn + srow) * Kd + k0 + skof);
    uint4 a0 = ap[0], a1 = ap[1];
    uint4 b0 = bp[0], b1 = bp[1];
    __syncthreads();
    *(uint4*)&As[srow * LROW + skof] = a0;
    *(uint4*)&As[srow * LROW + skof + 8] = a1;
    *(uint4*)&Bs[srow * LROW + skof] = b0;
    *(uint4*)&Bs[srow * LROW + skof + 8] = b1;
    __syncthreads();
    bf16x8 af[4], bf[4];
    #pragma unroll
    for (int mt = 0; mt < 4; ++mt)
      af[mt] = *(const bf16x8*)&As[(wm + mt * 16 + mrow) * LROW + kq * 8];
    #pragma unroll
    for (int nt = 0; nt < 4; ++nt)
      bf[nt] = *(const bf16x8*)&Bs[(wn + nt * 16 + mrow) * LROW + kq * 8];
    #pragma unroll
    for (int mt = 0; mt < 4; ++mt)
      #pragma unroll
      for (int nt = 0; nt < 4; ++nt)
        acc[mt][nt] = __builtin_amdgcn_mfma_f32_16x16x32_bf16(af[mt], bf[nt], acc[mt][nt], 0, 0, 0);
  }
  #pragma unroll
  for (int mt = 0; mt < 4; ++mt)
    #pragma unroll
    for (int nt = 0; nt < 4; ++nt) {
      int n_g = bn + wn + nt * 16 + (lane & 15);
      #pragma unroll
      for (int r = 0; r < 4; ++r) {
        int m_g = bm + wm + mt * 16 + kq * 4 + r;
        float v = acc[mt][nt][r];
        if (EPI == EPI_EUCLID) {
          v = e1[m_g] + e2[n_g] - 2.f * v;
          v = sqrtf(fmaxf(v, 0.f));
        } else {
          if (bias) v += bias[n_g];
          if (EPI == EPI_LEAKY) v = LEAKY(v);
          else if (EPI == EPI_LEAKY_BN) { v = LEAKY(v); v *= BN_SCALE; }
          else if (EPI == EPI_TANH) v = tanhf(v);
        }
        if (C32) C32[(size_t)m_g * N + n_g] = v;
        if (C16) C16[(size_t)m_g * N + n_g] = f2bfu(v);
      }
    }
}

// ---- 64x64 bf16 NT GEMM (M%64, N%64, K%32) --------------------------------
template <int EPI>
__launch_bounds__(256)
__global__ void gemm_bf16_nt64(const ushort_t* __restrict__ A, const ushort_t* __restrict__ B,
                               const float* __restrict__ bias, float* __restrict__ C32,
                               ushort_t* __restrict__ C16, int M, int N, int Kd) {
  __shared__ ushort_t As[64 * LROW];
  __shared__ ushort_t Bs[64 * LROW];
  int tid = threadIdx.x;
  int bm = blockIdx.y * 64, bn = blockIdx.x * 64;
  int wave = tid >> 6, lane = tid & 63;
  int wm = (wave >> 1) * 32, wn = (wave & 1) * 32;
  int mrow = lane & 15, kq = lane >> 4;
  int srow = tid >> 2, skof = (tid & 3) * 8;

  f32x4 acc[2][2];
  #pragma unroll
  for (int i = 0; i < 2; ++i)
    #pragma unroll
    for (int j = 0; j < 2; ++j)
      #pragma unroll
      for (int r = 0; r < 4; ++r) acc[i][j][r] = 0.f;

  for (int k0 = 0; k0 < Kd; k0 += 32) {
    uint4 a0 = *(const uint4*)(A + (size_t)(bm + srow) * Kd + k0 + skof);
    uint4 b0 = *(const uint4*)(B + (size_t)(bn + srow) * Kd + k0 + skof);
    __syncthreads();
    *(uint4*)&As[srow * LROW + skof] = a0;
    *(uint4*)&Bs[srow * LROW + skof] = b0;
    __syncthreads();
    bf16x8 af[2], bf[2];
    #pragma unroll
    for (int mt = 0; mt < 2; ++mt)
      af[mt] = *(const bf16x8*)&As[(wm + mt * 16 + mrow) * LROW + kq * 8];
    #pragma unroll
    for (int nt = 0; nt < 2; ++nt)
      bf[nt] = *(const bf16x8*)&Bs[(wn + nt * 16 + mrow) * LROW + kq * 8];
    #pragma unroll
    for (int mt = 0; mt < 2; ++mt)
      #pragma unroll
      for (int nt = 0; nt < 2; ++nt)
        acc[mt][nt] = __builtin_amdgcn_mfma_f32_16x16x32_bf16(af[mt], bf[nt], acc[mt][nt], 0, 0, 0);
  }
  #pragma unroll
  for (int mt = 0; mt < 2; ++mt)
    #pragma unroll
    for (int nt = 0; nt < 2; ++nt) {
      int n_g = bn + wn + nt * 16 + (lane & 15);
      #pragma unroll
      for (int r = 0; r < 4; ++r) {
        int m_g = bm + wm + mt * 16 + kq * 4 + r;
        float v = acc[mt][nt][r];
        if (bias) v += bias[n_g];
        if (EPI == EPI_LEAKY) v = LEAKY(v);
        else if (EPI == EPI_LEAKY_BN) { v = LEAKY(v); v *= BN_SCALE; }
        else if (EPI == EPI_TANH) v = tanhf(v);
        if (C32) C32[(size_t)m_g * N + n_g] = v;
        if (C16) C16[(size_t)m_g * N + n_g] = f2bfu(v);
      }
    }
}

// ---- 128x128 bf16 NN GEMM + bf16 residual -> bf16 out (C16==R-layout safe)-
__launch_bounds__(256)
__global__ void gemm_bf16_nn_res(const ushort_t* __restrict__ A, const ushort_t* __restrict__ B,
                                 const ushort_t* __restrict__ R, ushort_t* __restrict__ C16,
                                 int M, int N, int Kd) {
  __shared__ ushort_t As[128 * LROW];
  __shared__ ushort_t Bs[128 * LROW];
  int tid = threadIdx.x;
  int bm = blockIdx.y * 128, bn = blockIdx.x * 128;
  int wave = tid >> 6, lane = tid & 63;
  int wm = (wave >> 1) * 64, wn = (wave & 1) * 64;
  int mrow = lane & 15, kq = lane >> 4;
  int srow = tid >> 1, skof = (tid & 1) * 16;
  int krow = tid >> 3, nof = (tid & 7) * 16;

  f32x4 acc[4][4];
  #pragma unroll
  for (int i = 0; i < 4; ++i)
    #pragma unroll
    for (int j = 0; j < 4; ++j)
      #pragma unroll
      for (int r = 0; r < 4; ++r) acc[i][j][r] = 0.f;

  for (int k0 = 0; k0 < Kd; k0 += 32) {
    const uint4* ap = (const uint4*)(A + (size_t)(bm + srow) * Kd + k0 + skof);
    uint4 a0 = ap[0], a1 = ap[1];
    ushort_t bb[16];
    *(uint4*)&bb[0] = *(const uint4*)(B + (size_t)(k0 + krow) * N + bn + nof);
    *(uint4*)&bb[8] = *(const uint4*)(B + (size_t)(k0 + krow) * N + bn + nof + 8);
    __syncthreads();
    *(uint4*)&As[srow * LROW + skof] = a0;
    *(uint4*)&As[srow * LROW + skof + 8] = a1;
    #pragma unroll
    for (int j = 0; j < 16; ++j)
      Bs[(nof + j) * LROW + krow] = bb[j];
    __syncthreads();
    bf16x8 af[4], bf[4];
    #pragma unroll
    for (int mt = 0; mt < 4; ++mt)
      af[mt] = *(const bf16x8*)&As[(wm + mt * 16 + mrow) * LROW + kq * 8];
    #pragma unroll
    for (int nt = 0; nt < 4; ++nt)
      bf[nt] = *(const bf16x8*)&Bs[(wn + nt * 16 + mrow) * LROW + kq * 8];
    #pragma unroll
    for (int mt = 0; mt < 4; ++mt)
      #pragma unroll
      for (int nt = 0; nt < 4; ++nt)
        acc[mt][nt] = __builtin_amdgcn_mfma_f32_16x16x32_bf16(af[mt], bf[nt], acc[mt][nt], 0, 0, 0);
  }
  #pragma unroll
  for (int mt = 0; mt < 4; ++mt)
    #pragma unroll
    for (int nt = 0; nt < 4; ++nt) {
      int n_g = bn + wn + nt * 16 + (lane & 15);
      #pragma unroll
      for (int r = 0; r < 4; ++r) {
        int m_g = bm + wm + mt * 16 + kq * 4 + r;
        float v = acc[mt][nt][r] + bfu2f(R[(size_t)m_g * N + n_g]);
        C16[(size_t)m_g * N + n_g] = f2bfu(v);
      }
    }
}

// ---- 64x64 bf16 NN GEMM + bf16 residual -> bf16 out -----------------------
__launch_bounds__(256)
__global__ void gemm_bf16_nn_res64(const ushort_t* __restrict__ A, const ushort_t* __restrict__ B,
                                   const ushort_t* __restrict__ R, ushort_t* __restrict__ C16,
                                   int M, int N, int Kd) {
  __shared__ ushort_t As[64 * LROW];
  __shared__ ushort_t Bs[64 * LROW];
  int tid = threadIdx.x;
  int bm = blockIdx.y * 64, bn = blockIdx.x * 64;
  int wave = tid >> 6, lane = tid & 63;
  int wm = (wave >> 1) * 32, wn = (wave & 1) * 32;
  int mrow = lane & 15, kq = lane >> 4;
  int srow = tid >> 2, skof = (tid & 3) * 8;
  int krow = tid >> 3, nof = (tid & 7) * 8;

  f32x4 acc[2][2];
  #pragma unroll
  for (int i = 0; i < 2; ++i)
    #pragma unroll
    for (int j = 0; j < 2; ++j)
      #pragma unroll
      for (int r = 0; r < 4; ++r) acc[i][j][r] = 0.f;

  for (int k0 = 0; k0 < Kd; k0 += 32) {
    uint4 a0 = *(const uint4*)(A + (size_t)(bm + srow) * Kd + k0 + skof);
    ushort_t bb[8];
    *(uint4*)&bb[0] = *(const uint4*)(B + (size_t)(k0 + krow) * N + bn + nof);
    __syncthreads();
    *(uint4*)&As[srow * LROW + skof] = a0;
    #pragma unroll
    for (int j = 0; j < 8; ++j)
      Bs[(nof + j) * LROW + krow] = bb[j];
    __syncthreads();
    bf16x8 af[2], bf[2];
    #pragma unroll
    for (int mt = 0; mt < 2; ++mt)
      af[mt] = *(const bf16x8*)&As[(wm + mt * 16 + mrow) * LROW + kq * 8];
    #pragma unroll
    for (int nt = 0; nt < 2; ++nt)
      bf[nt] = *(const bf16x8*)&Bs[(wn + nt * 16 + mrow) * LROW + kq * 8];
    #pragma unroll
    for (int mt = 0; mt < 2; ++mt)
      #pragma unroll
      for (int nt = 0; nt < 2; ++nt)
        acc[mt][nt] = __builtin_amdgcn_mfma_f32_16x16x32_bf16(af[mt], bf[nt], acc[mt][nt], 0, 0, 0);
  }
  #pragma unroll
  for (int mt = 0; mt < 2; ++mt)
    #pragma unroll
    for (int nt = 0; nt < 2; ++nt) {
      int n_g = bn + wn + nt * 16 + (lane & 15);
      #pragma unroll
      for (int r = 0; r < 4; ++r) {
        int m_g = bm + wm + mt * 16 + kq * 4 + r;
        float v = acc[mt][nt][r] + bfu2f(R[(size_t)m_g * N + n_g]);
        C16[(size_t)m_g * N + n_g] = f2bfu(v);
      }
    }
}

// ---- split-K TN GEMM on bf16 inputs (Mm = X1^T @ X2) ----------------------
__global__ void gemm_tn_part(const ushort_t* __restrict__ A, const ushort_t* __restrict__ B,
                             float* __restrict__ part) {
  int tx = threadIdx.x & 15, ty = threadIdx.x >> 4;
  int i = blockIdx.y * 16 + ty, j = blockIdx.x * 16 + tx;
  int ks = blockIdx.z;
  float acc = 0.f;
  for (int k = ks * 128; k < ks * 128 + 128; ++k)
    acc += bfu2f(A[(size_t)k * 128 + i]) * bfu2f(B[(size_t)k * 128 + j]);
  part[(size_t)ks * 16384 + i * 128 + j] = acc;
}
__global__ void gemm_tn_reduce(const float* __restrict__ part, ushort_t* __restrict__ Mm) {
  int idx = blockIdx.x * 256 + threadIdx.x;
  float s = 0.f;
  #pragma unroll
  for (int ks = 0; ks < 16; ++ks) s += part[(size_t)ks * 16384 + idx];
  Mm[idx] = f2bfu(s);
}

// ---- column softmax (axis 0) in-place on bf16 -----------------------------
__global__ void softmax_col_bf16(ushort_t* __restrict__ S, int M, int N) {
  int t = threadIdx.x;
  int cl = t & 15, g = t >> 4;
  int c = blockIdx.x * 16 + cl;
  __shared__ float red[16][17];
  float m = -1e30f;
  for (int r = g; r < M; r += 16) m = fmaxf(m, bfu2f(S[(size_t)r * N + c]));
  red[g][cl] = m;
  __syncthreads();
  for (int off = 8; off; off >>= 1) { if (g < off) red[g][cl] = fmaxf(red[g][cl], red[g + off][cl]); __syncthreads(); }
  m = red[0][cl];
  __syncthreads();
  float sum = 0.f;
  for (int r = g; r < M; r += 16) sum += expf(bfu2f(S[(size_t)r * N + c]) - m);
  red[g][cl] = sum;
  __syncthreads();
  for (int off = 8; off; off >>= 1) { if (g < off) red[g][cl] += red[g + off][cl]; __syncthreads(); }
  float inv = 1.f / red[0][cl];
  for (int r = g; r < M; r += 16) {
    size_t i = (size_t)r * N + c;
    S[i] = f2bfu(expf(bfu2f(S[i]) - m) * inv);
  }
}

// ---- row squared-norms from bf16 ------------------------------------------
__global__ void row_norm_bf16(const ushort_t* __restrict__ X, float* __restrict__ out, int Kd) {
  int r = blockIdx.x;
  int t = threadIdx.x;
  float s = 0.f;
  for (int k = t; k < Kd; k += 64) { float v = bfu2f(X[(size_t)r * Kd + k]); s += v * v; }
  for (int off = 32; off; off >>= 1) s += __shfl_down(s, off);
  if (t == 0) out[r] = s;
}

// ---- mask scores (A3 fp32) ------------------------------------------------
__global__ void mask_score(const float* __restrict__ A3, const float* __restrict__ w4,
                           const float* __restrict__ b4, float* __restrict__ s) {
  int k = blockIdx.x * 256 + threadIdx.x;
  float acc = b4[0];
  for (int h = 0; h < 128; ++h) acc += A3[(size_t)h * 2048 + k] * w4[h];
  s[k] = acc;
}

// ---- stable descending-argsort rank -> top-S indices ----------------------
__global__ void topk_rank(const float* __restrict__ s, int* __restrict__ idx, int K, int S) {
  int j = blockIdx.x * 256 + threadIdx.x;
  if (j >= K) return;
  float sj = s[j];
  int rank = 0;
  for (int i = 0; i < K; ++i) {
    float si = s[i];
    rank += (si > sj) || (si == sj && i < j);
  }
  if (rank < S) idx[rank] = j;
}

// ---- build cat = [B_dt | softmax(aff_s[:,idx],axis=1) | 0pad], bf16 -------
__global__ void build_cat(const ushort_t* __restrict__ Bdt, const ushort_t* __restrict__ affs,
                          const int* __restrict__ idx, ushort_t* __restrict__ cat) {
  int r = blockIdx.x, t = threadIdx.x;
  __shared__ float vals[256];
  __shared__ float red[256];
  float v = -1e30f;
  if (t < 204) {
    int ix = idx[t];
    ix = ix < 0 ? 0 : (ix > 2047 ? 2047 : ix);
    v = bfu2f(affs[(size_t)r * 2048 + ix]);
  }
  vals[t] = v;
  red[t] = v;
  __syncthreads();
  for (int off = 128; off; off >>= 1) { if (t < off) red[t] = fmaxf(red[t], red[t + off]); __syncthreads(); }
  float m = red[0];
  __syncthreads();
  float e = (t < 204) ? expf(vals[t] - m) : 0.f;
  red[t] = e;
  __syncthreads();
  for (int off = 128; off; off >>= 1) { if (t < off) red[t] += red[t + off]; __syncthreads(); }
  float inv = 1.f / red[0];
  cat[(size_t)r * 512 + t] = Bdt[(size_t)r * 256 + t];
  cat[(size_t)r * 512 + 256 + t] = (t < 204) ? f2bfu(e * inv) : (ushort_t)0;
}

// ---- a = leaky((AV*AU) @ aww.T + awb) -------------------------------------
__global__ void attn_gate(const float* __restrict__ AV, const float* __restrict__ AU,
                          const float* __restrict__ aww, const float* __restrict__ awb,
                          float* __restrict__ a, int n) {
  int r = blockIdx.x * 256 + threadIdx.x;
  if (r >= n) return;
  float acc = awb[0];
  for (int d = 0; d < 128; ++d) acc += AV[(size_t)r * 128 + d] * AU[(size_t)r * 128 + d] * aww[d];
  a[r] = LEAKY(acc);
}

// ---- 1-D softmax (single block) -------------------------------------------
__global__ void softmax_vec(const float* __restrict__ x, float* __restrict__ y,
                            float* __restrict__ y2, int n) {
  __shared__ float red[256];
  int t = threadIdx.x;
  float m = -1e30f;
  for (int i = t; i < n; i += 256) m = fmaxf(m, x[i]);
  red[t] = m;
  __syncthreads();
  for (int off = 128; off; off >>= 1) { if (t < off) red[t] = fmaxf(red[t], red[t + off]); __syncthreads(); }
  m = red[0];
  __syncthreads();
  float s = 0.f;
  for (int i = t; i < n; i += 256) s += expf(x[i] - m);
  red[t] = s;
  __syncthreads();
  for (int off = 128; off; off >>= 1) { if (t < off) red[t] += red[t + off]; __syncthreads(); }
  float inv = 1.f / red[0];
  for (int i = t; i < n; i += 256) {
    float v = expf(x[i] - m) * inv;
    y[i] = v;
    if (y2) y2[i] = v;
  }
}

// ---- weighted column sum over bf16 H, two-stage ---------------------------
__global__ void colsum_part(const float* __restrict__ wv, const ushort_t* __restrict__ H,
                            float* __restrict__ part, int n) {
  int bk = blockIdx.x, c = threadIdx.x;
  float s = 0.f;
  for (int r = bk; r < n; r += 16) s += wv[r] * bfu2f(H[(size_t)r * 256 + c]);
  part[bk * 256 + c] = s;
}
__global__ void colsum_fin(const float* __restrict__ part, float* __restrict__ out) {
  int c = threadIdx.x;
  float s = 0.f;
  #pragma unroll
  for (int k = 0; k < 16; ++k) s += part[k * 256 + c];
  out[c] = s;
}

// ---- small gemv -----------------------------------------------------------
__global__ void gemv_act(const float* __restrict__ x, const float* __restrict__ W,
                         const float* __restrict__ b, float* __restrict__ out,
                         int O, int Kd, int act) {
  int o = blockIdx.x * blockDim.x + threadIdx.x;
  if (o >= O) return;
  float acc = b ? b[o] : 0.f;
  for (int k = 0; k < Kd; ++k) acc += x[k] * W[(size_t)o * Kd + k];
  if (act == 1) acc = LEAKY(acc);
  out[o] = acc;
}

// ---- cat2 = [B_fuse | tile(M1)], bf16 -------------------------------------
__global__ void build_cat2(const ushort_t* __restrict__ Bf, const float* __restrict__ M1,
                           ushort_t* __restrict__ cat2) {
  int r = blockIdx.x, t = threadIdx.x;  // 512 threads
  cat2[(size_t)r * 512 + t] = (t < 256) ? Bf[(size_t)r * 256 + t] : f2bfu(M1[t - 256]);
}

// ---- final head -----------------------------------------------------------
__global__ void final_head(const float* __restrict__ AH2, const float* __restrict__ embw,
                           const float* __restrict__ embb, const float* __restrict__ sembw,
                           const float* __restrict__ sembb, const float* __restrict__ clsw,
                           const float* __restrict__ clsb, float* __restrict__ Yout) {
  __shared__ float bvec[512];
  __shared__ float red[512];
  int t = threadIdx.x;
  float acc = embb[t];
  for (int c = 0; c < 256; ++c) acc += AH2[c] * embw[(size_t)t * 256 + c];
  bvec[t] = LEAKY(acc);
  __syncthreads();
  float p = 0.f;
  if (t < 256) {
    float a2 = sembb[t];
    for (int c = 0; c < 512; ++c) a2 += bvec[c] * sembw[(size_t)t * 512 + c];
    a2 = LEAKY(a2);
    p = a2 * clsw[t];
  }
  red[t] = p;
  __syncthreads();
  for (int off = 256; off; off >>= 1) { if (t < off) red[t] += red[t + off]; __syncthreads(); }
  if (t == 0) {
    float y = red[0] + clsb[0];
    y = 1.f / (1.f + expf(-y));
    y = fminf(fmaxf(y, 1e-5f), 1.f - 1e-5f);
    Yout[0] = y;
  }
}

extern "C" void kernel_launch(void* const* d_in, const int* in_sizes, int n_in,
                              void* d_out, int out_size, void* d_ws, size_t ws_size,
                              hipStream_t stream) {
  auto IN = [&](int i) { return (const float*)d_in[i]; };
  (void)n_in; (void)in_sizes; (void)out_size;

  const int S = 204;
  float* out_f = (float*)d_out;  // out[0]=Y, out[1..2048]=A

  float* W = (float*)d_ws;
  size_t off = 0;
  auto F = [&](size_t n) { float* p = W + off; off += n; return p; };
  auto FU = [&](size_t nus) { return (ushort_t*)F((nus + 1) / 2); };

  ushort_t* dt_b  = FU((size_t)4096 * 256);
  ushort_t* Xs_b  = FU((size_t)2048 * 256);
  ushort_t* Ks_b  = FU((size_t)2048 * 256);
  ushort_t* X1b   = FU((size_t)2048 * 128);
  ushort_t* X2b   = FU((size_t)2048 * 128);
  ushort_t* aff_b = FU((size_t)2048 * 2048);  // euclid out; skip3 in-place -> aff_s
  float* AV    = F((size_t)2048 * 128);
  float* AU    = F((size_t)2048 * 128);
  ushort_t* Mm_b = FU((size_t)128 * 128);
  float* svec  = F(2048);
  int*   idxb  = (int*)F(256);
  float* avec  = F(2048);
  float* Awv   = F(2048);
  float* AH    = F(256);
  float* M1v   = F(256);
  float* AH2   = F(256);
  float* nx    = F(2048);
  float* ny    = F(2048);
  float* part  = F(4096);

  // bf16 weight arena
  size_t wo = 0;
  ushort_t* warena = (ushort_t*)F(3227872);
  auto WA = [&](size_t n) { ushort_t* p = warena + wo; wo = (wo + n + 15) & ~(size_t)15; return p; };
  ushort_t* w2b   = WA(25000);
  ushort_t* embb_ = WA(204800);
  ushort_t* s1w1 = WA(32768); ushort_t* s1w2 = WA(32768); ushort_t* s1w3 = WA(65536);
  ushort_t* s2w1 = WA(32768); ushort_t* s2w2 = WA(32768); ushort_t* s2w3 = WA(65536);
  ushort_t* s3w1 = WA(262144); ushort_t* s3w2 = WA(262144); ushort_t* s3w3 = WA(4194304);
  ushort_t* mw1 = WA(262144); ushort_t* mw2 = WA(262144); ushort_t* mw3 = WA(262144);
  ushort_t* fwp = WA(131072);
  ushort_t* a1fe = WA(65536); ushort_t* a1v = WA(32768); ushort_t* a1u = WA(32768);
  ushort_t* a2fe = WA(131072); ushort_t* a2v = WA(32768); ushort_t* a2u = WA(32768);

  float* pool = F((size_t)4194304);

  const size_t NEED_BYTES = off * 4;
  if (ws_size < NEED_BYTES) {
    fill_out<<<9, 256, 0, stream>>>(out_f, 2049);
    return;
  }

  // pool members (phase-disjoint)
  ushort_t* h2h_b  = (ushort_t*)pool;                 // conv: 2048*800 us
  ushort_t* Smat_b = (ushort_t*)pool;                 // skip: 2048*2048 us
  ushort_t* X3s_b  = (ushort_t*)(pool + 2097152);     // skip1/2: 2048*256 us
  ushort_t* X3b_b  = (ushort_t*)(pool + 2097152);     // skip3: 2048*2048 us
  float* A3   = pool;                                 // mask: 128*2048 fp32
  float* tnpt = pool + 262144;                        // mask: 16*16384 fp32
  ushort_t* cat_b   = (ushort_t*)pool;                // fuse: 2048*512 us
  ushort_t* cat2_b  = (ushort_t*)(pool + 524288);     // 2048*512 us
  ushort_t* Bfuse_b = (ushort_t*)(pool + 1048576);    // 2048*256 us
  ushort_t* Hbuf_b  = (ushort_t*)(pool + 1310720);    // 2048*256 us

  // ---- weight conversion (once per launch) ----
  CvtArgs ca;
  const float* srcs[20] = { IN(4), IN(6), IN(8), IN(10), IN(12), IN(14), IN(16), IN(18),
                            IN(20), IN(22), IN(24), IN(26), IN(28), IN(30),
                            IN(36), IN(38), IN(40), IN(46), IN(48), IN(50) };
  ushort_t* dsts[20] = { w2b, embb_, s1w1, s1w2, s1w3, s2w1, s2w2, s2w3,
                         s3w1, s3w2, s3w3, mw1, mw2, mw3,
                         a1fe, a1v, a1u, a2fe, a2v, a2u };
  int lens[20] = { 25000, 204800, 32768, 32768, 65536, 32768, 32768, 65536,
                   262144, 262144, 4194304, 262144, 262144, 262144,
                   65536, 32768, 32768, 131072, 32768, 32768 };
  for (int i = 0; i < 20; ++i) { ca.src[i] = srcs[i]; ca.dst[i] = dsts[i]; ca.len[i] = lens[i]; }
  to_bf16_multi<<<1024, 256, 0, stream>>>(ca);
  pad_fuse_bf16<<<512, 256, 0, stream>>>(IN(34), fwp);

  // ---- data_transform for B (g=0) and KB (g=1) ----
  for (int g = 0; g < 2; ++g) {
    conv12_mfma<<<1024, 256, 0, stream>>>(IN(g), IN(2), IN(3), w2b, IN(5), h2h_b);
    gemm_bf16_nt64<EPI_LEAKY><<<dim3(4, 32), 256, 0, stream>>>(
        h2h_b, embb_, IN(7), nullptr, dt_b + (size_t)g * 2048 * 256, 2048, 256, 800);
  }
  ushort_t* B_dtb = dt_b;
  ushort_t* KB_dtb = dt_b + (size_t)2048 * 256;

  // ---- skip_block 1 (B_dt -> Xs) and 2 (KB_dt -> Ks) ----
  for (int g = 0; g < 2; ++g) {
    ushort_t* Xin = g ? KB_dtb : B_dtb;
    ushort_t* Xout = g ? Ks_b : Xs_b;
    ushort_t* w1 = g ? s2w1 : s1w1;
    ushort_t* w2 = g ? s2w2 : s1w2;
    ushort_t* w3 = g ? s2w3 : s1w3;
    int wi = g ? 14 : 8;
    gemm_bf16_nt64<EPI_LEAKY_BN><<<dim3(2, 32), 256, 0, stream>>>(
        Xin, w1, IN(wi + 1), nullptr, X1b, 2048, 128, 256);
    gemm_bf16_nt64<EPI_LEAKY_BN><<<dim3(2, 32), 256, 0, stream>>>(
        Xin, w2, IN(wi + 3), nullptr, X2b, 2048, 128, 256);
    gemm_bf16_nt64<EPI_LEAKY_BN><<<dim3(4, 32), 256, 0, stream>>>(
        Xin, w3, IN(wi + 5), nullptr, X3s_b, 2048, 256, 256);
    gemm_bf16_nt<EPI_NONE><<<dim3(16, 16), 256, 0, stream>>>(
        X1b, X2b, nullptr, nullptr, Smat_b, 2048, 2048, 128, nullptr, nullptr);
    softmax_col_bf16<<<128, 256, 0, stream>>>(Smat_b, 2048, 2048);
    gemm_bf16_nn_res64<<<dim3(4, 32), 256, 0, stream>>>(Smat_b, X3s_b, Xin, Xout, 2048, 256, 2048);
  }

  // ---- euclid -> aff_b ----
  row_norm_bf16<<<2048, 64, 0, stream>>>(Xs_b, nx, 256);
  row_norm_bf16<<<2048, 64, 0, stream>>>(Ks_b, ny, 256);
  gemm_bf16_nt<EPI_EUCLID><<<dim3(16, 16), 256, 0, stream>>>(
      Xs_b, Ks_b, nullptr, nullptr, aff_b, 2048, 2048, 256, nx, ny);

  // ---- skip_block 3 (aff_b -> aff_b in-place) ----
  gemm_bf16_nt64<EPI_LEAKY_BN><<<dim3(2, 32), 256, 0, stream>>>(
      aff_b, s3w1, IN(21), nullptr, X1b, 2048, 128, 2048);
  gemm_bf16_nt64<EPI_LEAKY_BN><<<dim3(2, 32), 256, 0, stream>>>(
      aff_b, s3w2, IN(23), nullptr, X2b, 2048, 128, 2048);
  gemm_bf16_nt<EPI_LEAKY_BN><<<dim3(16, 16), 256, 0, stream>>>(
      aff_b, s3w3, IN(25), nullptr, X3b_b, 2048, 2048, 2048, nullptr, nullptr);
  gemm_bf16_nt<EPI_NONE><<<dim3(16, 16), 256, 0, stream>>>(
      X1b, X2b, nullptr, nullptr, Smat_b, 2048, 2048, 128, nullptr, nullptr);
  softmax_col_bf16<<<128, 256, 0, stream>>>(Smat_b, 2048, 2048);
  gemm_bf16_nn_res<<<dim3(16, 16), 256, 0, stream>>>(Smat_b, X3b_b, aff_b, aff_b, 2048, 2048, 2048);
  ushort_t* affs_b = aff_b;

  // ---- mask_scores -> top-S idx ----
  gemm_bf16_nt64<EPI_LEAKY><<<dim3(2, 32), 256, 0, stream>>>(
      affs_b, mw1, IN(27), nullptr, X1b, 2048, 128, 2048);
  gemm_bf16_nt64<EPI_TANH><<<dim3(2, 32), 256, 0, stream>>>(
      affs_b, mw2, IN(29), nullptr, X2b, 2048, 128, 2048);
  gemm_tn_part<<<dim3(8, 8, 16), 256, 0, stream>>>(X1b, X2b, tnpt);
  gemm_tn_reduce<<<64, 256, 0, stream>>>(tnpt, Mm_b);
  gemm_bf16_nt64<EPI_LEAKY><<<dim3(32, 2), 256, 0, stream>>>(
      Mm_b, mw3, IN(31), A3, nullptr, 128, 2048, 128);
  mask_score<<<8, 256, 0, stream>>>(A3, IN(32), IN(33), svec);
  topk_rank<<<8, 256, 0, stream>>>(svec, idxb, 2048, S);

  // ---- B_bag + concat (bf16, pad 512) + fuse ----
  build_cat<<<2048, 256, 0, stream>>>(B_dtb, affs_b, idxb, cat_b);
  gemm_bf16_nt64<EPI_LEAKY><<<dim3(4, 32), 256, 0, stream>>>(
      cat_b, fwp, IN(35), nullptr, Bfuse_b, 2048, 256, 512);

  // ---- attention 1 ----
  gemm_bf16_nt64<EPI_LEAKY><<<dim3(4, 32), 256, 0, stream>>>(
      Bfuse_b, a1fe, IN(37), nullptr, Hbuf_b, 2048, 256, 256);
  gemm_bf16_nt64<EPI_TANH><<<dim3(2, 32), 256, 0, stream>>>(
      Hbuf_b, a1v, IN(39), AV, nullptr, 2048, 128, 256);
  gemm_bf16_nt64<EPI_LEAKY><<<dim3(2, 32), 256, 0, stream>>>(
      Hbuf_b, a1u, IN(41), AU, nullptr, 2048, 128, 256);
  attn_gate<<<8, 256, 0, stream>>>(AV, AU, IN(42), IN(43), avec, 2048);
  softmax_vec<<<1, 256, 0, stream>>>(avec, Awv, nullptr, 2048);
  colsum_part<<<16, 256, 0, stream>>>(Awv, Hbuf_b, part, 2048);
  colsum_fin<<<1, 256, 0, stream>>>(part, AH);
  gemv_act<<<1, 256, 0, stream>>>(AH, IN(44), IN(45), M1v, 256, 256, 1);
  build_cat2<<<2048, 512, 0, stream>>>(Bfuse_b, M1v, cat2_b);

  // ---- attention 2 (A -> output) ----
  gemm_bf16_nt64<EPI_LEAKY><<<dim3(4, 32), 256, 0, stream>>>(
      cat2_b, a2fe, IN(47), nullptr, Hbuf_b, 2048, 256, 512);
  gemm_bf16_nt64<EPI_TANH><<<dim3(2, 32), 256, 0, stream>>>(
      Hbuf_b, a2v, IN(49), AV, nullptr, 2048, 128, 256);
  gemm_bf16_nt64<EPI_LEAKY><<<dim3(2, 32), 256, 0, stream>>>(
      Hbuf_b, a2u, IN(51), AU, nullptr, 2048, 128, 256);
  attn_gate<<<8, 256, 0, stream>>>(AV, AU, IN(52), IN(53), avec, 2048);
  softmax_vec<<<1, 256, 0, stream>>>(avec, Awv, out_f + 1, 2048);
  colsum_part<<<16, 256, 0, stream>>>(Awv, Hbuf_b, part, 2048);
  colsum_fin<<<1, 256, 0, stream>>>(part, AH2);

  // ---- final head -> Y ----
  final_head<<<1, 512, 0, stream>>>(AH2, IN(54), IN(55), IN(56), IN(57),
                                    IN(58), IN(59), out_f);
}

// Round 8
// 1243.642 us; speedup vs baseline: 8.1270x; 1.2147x over previous
//
#include <hip/hip_runtime.h>
#include <math.h>

#define LEAKY(x) ((x) > 0.f ? (x) : 0.01f * (x))
static constexpr float BN_SCALE = 0.9999950000374997f;

typedef unsigned short ushort_t;
typedef float f32x4 __attribute__((ext_vector_type(4)));
typedef short bf16x8 __attribute__((ext_vector_type(8)));

__device__ __forceinline__ ushort_t f2bfu(float f) {
  union { float f; unsigned u; } v; v.f = f;
  unsigned r = v.u + 0x7fffu + ((v.u >> 16) & 1u);
  return (ushort_t)(r >> 16);
}
__device__ __forceinline__ float bfu2f(ushort_t u) {
  union { unsigned u; float f; } v; v.u = ((unsigned)u) << 16;
  return v.f;
}

// ---- fallback sentinel if workspace is too small ---------------------------
__global__ void fill_out(float* out, int n) {
  int i = blockIdx.x * 256 + threadIdx.x;
  if (i < n) out[i] = 0.25f;
}

// ---- one-shot fp32 -> bf16 conversion of up to 20 tensors -----------------
struct CvtArgs {
  const float* src[20];
  ushort_t* dst[20];
  int len[20];
};
__global__ void to_bf16_multi(CvtArgs a) {
  for (int s = 0; s < 20; ++s) {
    const float* sp = a.src[s];
    ushort_t* dp = a.dst[s];
    int n = a.len[s];
    for (int i = blockIdx.x * 256 + threadIdx.x; i < n; i += gridDim.x * 256)
      dp[i] = f2bfu(sp[i]);
  }
}

// ---- pad fuse_w [256,460] fp32 -> [256,512] bf16 --------------------------
__global__ void pad_fuse_bf16(const float* __restrict__ w, ushort_t* __restrict__ wp) {
  int idx = blockIdx.x * 256 + threadIdx.x;
  if (idx >= 256 * 512) return;
  int o = idx >> 9, k = idx & 511;
  wp[idx] = (k < 460) ? f2bfu(w[(size_t)o * 460 + k]) : (ushort_t)0;
}

// ============================================================================
// Fused conv1+pool+conv2+pool via MFMA implicit GEMM. 2 images/block.
// ============================================================================
__launch_bounds__(256)
__global__ void conv12_mfma(const float* __restrict__ img, const float* __restrict__ w1,
                            const float* __restrict__ b1, const ushort_t* __restrict__ w2b,
                            const float* __restrict__ b2, ushort_t* __restrict__ out800) {
  __shared__ __align__(16) char smem[39168];
  ushort_t* sh1u = (ushort_t*)smem;                 // [2*2880]
  float* simg = (float*)(smem + 11520);             // [2*784] (phase 1)
  float* sw1  = (float*)(smem + 11520 + 6272);      // [500]   (phase 1)
  ushort_t* As = (ushort_t*)(smem + 11520);         // [128*72] (phase 2)
  ushort_t* Bs = (ushort_t*)(smem + 29952);         // [64*72]  (phase 2)
  float* Cf = (float*)smem;                         // [128*68] (epilogue)

  int tid = threadIdx.x;
  const float* imgb = img + (size_t)blockIdx.x * 2 * 784;

  for (int i = tid; i < 1568; i += 256) simg[i] = imgb[i];
  for (int i = tid; i < 500; i += 256) sw1[i] = w1[i];
  __syncthreads();
  for (int o = tid; o < 5760; o += 256) {
    int im = o / 2880, oi = o % 2880;
    int c = oi / 144, rem = oi % 144, py = rem / 12, px = rem % 12;
    int y0 = py * 2, x0 = px * 2;
    const float* sb = &simg[im * 784];
    float p[6][6];
    #pragma unroll
    for (int yy = 0; yy < 6; ++yy)
      #pragma unroll
      for (int xx = 0; xx < 6; ++xx)
        p[yy][xx] = sb[(y0 + yy) * 28 + x0 + xx];
    float bb = b1[c];
    float t0 = bb, t1 = bb, t2 = bb, t3 = bb;
    const float* wc = &sw1[c * 25];
    #pragma unroll
    for (int ky = 0; ky < 5; ++ky)
      #pragma unroll
      for (int kx = 0; kx < 5; ++kx) {
        float wv = wc[ky * 5 + kx];
        t0 += p[ky][kx] * wv;
        t1 += p[ky][kx + 1] * wv;
        t2 += p[ky + 1][kx] * wv;
        t3 += p[ky + 1][kx + 1] * wv;
      }
    t0 = LEAKY(t0); t1 = LEAKY(t1); t2 = LEAKY(t2); t3 = LEAKY(t3);
    sh1u[o] = f2bfu(fmaxf(fmaxf(t0, t1), fmaxf(t2, t3)));
  }

  int wave = tid >> 6, lane = tid & 63;
  int wm = (wave >> 1) * 64, wn = (wave & 1) * 32;
  int mrow = lane & 15, kq = lane >> 4;
  int kl = tid & 63, rbase = tid >> 6;

  f32x4 acc[4][2];
  #pragma unroll
  for (int i = 0; i < 4; ++i)
    #pragma unroll
    for (int j = 0; j < 2; ++j)
      #pragma unroll
      for (int r = 0; r < 4; ++r) acc[i][j][r] = 0.f;

  for (int k0 = 0; k0 < 512; k0 += 64) {
    __syncthreads();
    int k = k0 + kl;
    bool valid = k < 500;
    int ic = k / 25, tap = k - ic * 25;
    int ky = tap / 5, kx = tap - ky * 5;
    int kof = ic * 144 + ky * 12 + kx;
    ushort_t tA[32];
    #pragma unroll
    for (int i = 0; i < 32; ++i) {
      int r = rbase + 4 * i;
      int im = r >> 6, pos = r & 63, oy = pos >> 3, ox = pos & 7;
      tA[i] = valid ? sh1u[im * 2880 + kof + oy * 12 + ox] : (ushort_t)0;
    }
    ushort_t tB[16];
    #pragma unroll
    for (int i = 0; i < 16; ++i) {
      int oc = rbase + 4 * i;
      tB[i] = (valid && oc < 50) ? w2b[(size_t)oc * 500 + k] : (ushort_t)0;
    }
    #pragma unroll
    for (int i = 0; i < 32; ++i) As[(rbase + 4 * i) * 72 + kl] = tA[i];
    #pragma unroll
    for (int i = 0; i < 16; ++i) Bs[(rbase + 4 * i) * 72 + kl] = tB[i];
    __syncthreads();
    #pragma unroll
    for (int ks = 0; ks < 2; ++ks) {
      bf16x8 af[4], bf[2];
      #pragma unroll
      for (int mt = 0; mt < 4; ++mt)
        af[mt] = *(const bf16x8*)&As[(wm + mt * 16 + mrow) * 72 + ks * 32 + kq * 8];
      #pragma unroll
      for (int nt = 0; nt < 2; ++nt)
        bf[nt] = *(const bf16x8*)&Bs[(wn + nt * 16 + mrow) * 72 + ks * 32 + kq * 8];
      #pragma unroll
      for (int mt = 0; mt < 4; ++mt)
        #pragma unroll
        for (int nt = 0; nt < 2; ++nt)
          acc[mt][nt] = __builtin_amdgcn_mfma_f32_16x16x32_bf16(af[mt], bf[nt], acc[mt][nt], 0, 0, 0);
    }
  }
  __syncthreads();
  #pragma unroll
  for (int mt = 0; mt < 4; ++mt)
    #pragma unroll
    for (int nt = 0; nt < 2; ++nt) {
      int n0 = wn + nt * 16 + (lane & 15);
      #pragma unroll
      for (int r = 0; r < 4; ++r)
        Cf[(wm + mt * 16 + kq * 4 + r) * 68 + n0] = acc[mt][nt][r];
    }
  __syncthreads();
  for (int o = tid; o < 1600; o += 256) {
    int im = o / 800, oi = o - im * 800;
    int oc = oi >> 4, p = oi & 15, py = p >> 2, px = p & 3;
    int r0 = im * 64 + py * 16 + px * 2;
    float bb = b2[oc];
    float t0 = LEAKY(Cf[r0 * 68 + oc] + bb);
    float t1 = LEAKY(Cf[(r0 + 1) * 68 + oc] + bb);
    float t2 = LEAKY(Cf[(r0 + 8) * 68 + oc] + bb);
    float t3 = LEAKY(Cf[(r0 + 9) * 68 + oc] + bb);
    out800[(size_t)(blockIdx.x * 2 + im) * 800 + oi] = f2bfu(fmaxf(fmaxf(t0, t1), fmaxf(t2, t3)));
  }
}

// ---------------- epilogue kinds -------------------------------------------
enum { EPI_NONE = 0, EPI_LEAKY = 1, EPI_LEAKY_BN = 2, EPI_TANH = 3, EPI_EUCLID = 4 };

#define LROW 40

// ---- 128x128 bf16 NT GEMM. Dual store C32/C16 -----------------------------
template <int EPI>
__launch_bounds__(256)
__global__ void gemm_bf16_nt(const ushort_t* __restrict__ A, const ushort_t* __restrict__ B,
                             const float* __restrict__ bias, float* __restrict__ C32,
                             ushort_t* __restrict__ C16, int M, int N, int Kd,
                             const float* __restrict__ e1, const float* __restrict__ e2) {
  __shared__ ushort_t As[128 * LROW];
  __shared__ ushort_t Bs[128 * LROW];
  int tid = threadIdx.x;
  int bm = blockIdx.y * 128, bn = blockIdx.x * 128;
  int wave = tid >> 6, lane = tid & 63;
  int wm = (wave >> 1) * 64, wn = (wave & 1) * 64;
  int mrow = lane & 15, kq = lane >> 4;
  int srow = tid >> 1, skof = (tid & 1) * 16;

  f32x4 acc[4][4];
  #pragma unroll
  for (int i = 0; i < 4; ++i)
    #pragma unroll
    for (int j = 0; j < 4; ++j)
      #pragma unroll
      for (int r = 0; r < 4; ++r) acc[i][j][r] = 0.f;

  for (int k0 = 0; k0 < Kd; k0 += 32) {
    const uint4* ap = (const uint4*)(A + (size_t)(bm + srow) * Kd + k0 + skof);
    const uint4* bp = (const uint4*)(B + (size_t)(bn + srow) * Kd + k0 + skof);
    uint4 a0 = ap[0], a1 = ap[1];
    uint4 b0 = bp[0], b1 = bp[1];
    __syncthreads();
    *(uint4*)&As[srow * LROW + skof] = a0;
    *(uint4*)&As[srow * LROW + skof + 8] = a1;
    *(uint4*)&Bs[srow * LROW + skof] = b0;
    *(uint4*)&Bs[srow * LROW + skof + 8] = b1;
    __syncthreads();
    bf16x8 af[4], bf[4];
    #pragma unroll
    for (int mt = 0; mt < 4; ++mt)
      af[mt] = *(const bf16x8*)&As[(wm + mt * 16 + mrow) * LROW + kq * 8];
    #pragma unroll
    for (int nt = 0; nt < 4; ++nt)
      bf[nt] = *(const bf16x8*)&Bs[(wn + nt * 16 + mrow) * LROW + kq * 8];
    #pragma unroll
    for (int mt = 0; mt < 4; ++mt)
      #pragma unroll
      for (int nt = 0; nt < 4; ++nt)
        acc[mt][nt] = __builtin_amdgcn_mfma_f32_16x16x32_bf16(af[mt], bf[nt], acc[mt][nt], 0, 0, 0);
  }
  #pragma unroll
  for (int mt = 0; mt < 4; ++mt)
    #pragma unroll
    for (int nt = 0; nt < 4; ++nt) {
      int n_g = bn + wn + nt * 16 + (lane & 15);
      #pragma unroll
      for (int r = 0; r < 4; ++r) {
        int m_g = bm + wm + mt * 16 + kq * 4 + r;
        float v = acc[mt][nt][r];
        if (EPI == EPI_EUCLID) {
          v = e1[m_g] + e2[n_g] - 2.f * v;
          v = sqrtf(fmaxf(v, 0.f));
        } else {
          if (bias) v += bias[n_g];
          if (EPI == EPI_LEAKY) v = LEAKY(v);
          else if (EPI == EPI_LEAKY_BN) { v = LEAKY(v); v *= BN_SCALE; }
          else if (EPI == EPI_TANH) v = tanhf(v);
        }
        if (C32) C32[(size_t)m_g * N + n_g] = v;
        if (C16) C16[(size_t)m_g * N + n_g] = f2bfu(v);
      }
    }
}

// ---- 64x64 bf16 NT GEMM ---------------------------------------------------
template <int EPI>
__launch_bounds__(256)
__global__ void gemm_bf16_nt64(const ushort_t* __restrict__ A, const ushort_t* __restrict__ B,
                               const float* __restrict__ bias, float* __restrict__ C32,
                               ushort_t* __restrict__ C16, int M, int N, int Kd) {
  __shared__ ushort_t As[64 * LROW];
  __shared__ ushort_t Bs[64 * LROW];
  int tid = threadIdx.x;
  int bm = blockIdx.y * 64, bn = blockIdx.x * 64;
  int wave = tid >> 6, lane = tid & 63;
  int wm = (wave >> 1) * 32, wn = (wave & 1) * 32;
  int mrow = lane & 15, kq = lane >> 4;
  int srow = tid >> 2, skof = (tid & 3) * 8;

  f32x4 acc[2][2];
  #pragma unroll
  for (int i = 0; i < 2; ++i)
    #pragma unroll
    for (int j = 0; j < 2; ++j)
      #pragma unroll
      for (int r = 0; r < 4; ++r) acc[i][j][r] = 0.f;

  for (int k0 = 0; k0 < Kd; k0 += 32) {
    uint4 a0 = *(const uint4*)(A + (size_t)(bm + srow) * Kd + k0 + skof);
    uint4 b0 = *(const uint4*)(B + (size_t)(bn + srow) * Kd + k0 + skof);
    __syncthreads();
    *(uint4*)&As[srow * LROW + skof] = a0;
    *(uint4*)&Bs[srow * LROW + skof] = b0;
    __syncthreads();
    bf16x8 af[2], bf[2];
    #pragma unroll
    for (int mt = 0; mt < 2; ++mt)
      af[mt] = *(const bf16x8*)&As[(wm + mt * 16 + mrow) * LROW + kq * 8];
    #pragma unroll
    for (int nt = 0; nt < 2; ++nt)
      bf[nt] = *(const bf16x8*)&Bs[(wn + nt * 16 + mrow) * LROW + kq * 8];
    #pragma unroll
    for (int mt = 0; mt < 2; ++mt)
      #pragma unroll
      for (int nt = 0; nt < 2; ++nt)
        acc[mt][nt] = __builtin_amdgcn_mfma_f32_16x16x32_bf16(af[mt], bf[nt], acc[mt][nt], 0, 0, 0);
  }
  #pragma unroll
  for (int mt = 0; mt < 2; ++mt)
    #pragma unroll
    for (int nt = 0; nt < 2; ++nt) {
      int n_g = bn + wn + nt * 16 + (lane & 15);
      #pragma unroll
      for (int r = 0; r < 4; ++r) {
        int m_g = bm + wm + mt * 16 + kq * 4 + r;
        float v = acc[mt][nt][r];
        if (bias) v += bias[n_g];
        if (EPI == EPI_LEAKY) v = LEAKY(v);
        else if (EPI == EPI_LEAKY_BN) { v = LEAKY(v); v *= BN_SCALE; }
        else if (EPI == EPI_TANH) v = tanhf(v);
        if (C32) C32[(size_t)m_g * N + n_g] = v;
        if (C16) C16[(size_t)m_g * N + n_g] = f2bfu(v);
      }
    }
}

// ---- 128x128 bf16 NN GEMM + bf16 residual -> bf16 out ---------------------
__launch_bounds__(256)
__global__ void gemm_bf16_nn_res(const ushort_t* __restrict__ A, const ushort_t* __restrict__ B,
                                 const ushort_t* __restrict__ R, ushort_t* __restrict__ C16,
                                 int M, int N, int Kd) {
  __shared__ ushort_t As[128 * LROW];
  __shared__ ushort_t Bs[128 * LROW];
  int tid = threadIdx.x;
  int bm = blockIdx.y * 128, bn = blockIdx.x * 128;
  int wave = tid >> 6, lane = tid & 63;
  int wm = (wave >> 1) * 64, wn = (wave & 1) * 64;
  int mrow = lane & 15, kq = lane >> 4;
  int srow = tid >> 1, skof = (tid & 1) * 16;
  int krow = tid >> 3, nof = (tid & 7) * 16;

  f32x4 acc[4][4];
  #pragma unroll
  for (int i = 0; i < 4; ++i)
    #pragma unroll
    for (int j = 0; j < 4; ++j)
      #pragma unroll
      for (int r = 0; r < 4; ++r) acc[i][j][r] = 0.f;

  for (int k0 = 0; k0 < Kd; k0 += 32) {
    const uint4* ap = (const uint4*)(A + (size_t)(bm + srow) * Kd + k0 + skof);
    uint4 a0 = ap[0], a1 = ap[1];
    ushort_t bb[16];
    *(uint4*)&bb[0] = *(const uint4*)(B + (size_t)(k0 + krow) * N + bn + nof);
    *(uint4*)&bb[8] = *(const uint4*)(B + (size_t)(k0 + krow) * N + bn + nof + 8);
    __syncthreads();
    *(uint4*)&As[srow * LROW + skof] = a0;
    *(uint4*)&As[srow * LROW + skof + 8] = a1;
    #pragma unroll
    for (int j = 0; j < 16; ++j)
      Bs[(nof + j) * LROW + krow] = bb[j];
    __syncthreads();
    bf16x8 af[4], bf[4];
    #pragma unroll
    for (int mt = 0; mt < 4; ++mt)
      af[mt] = *(const bf16x8*)&As[(wm + mt * 16 + mrow) * LROW + kq * 8];
    #pragma unroll
    for (int nt = 0; nt < 4; ++nt)
      bf[nt] = *(const bf16x8*)&Bs[(wn + nt * 16 + mrow) * LROW + kq * 8];
    #pragma unroll
    for (int mt = 0; mt < 4; ++mt)
      #pragma unroll
      for (int nt = 0; nt < 4; ++nt)
        acc[mt][nt] = __builtin_amdgcn_mfma_f32_16x16x32_bf16(af[mt], bf[nt], acc[mt][nt], 0, 0, 0);
  }
  #pragma unroll
  for (int mt = 0; mt < 4; ++mt)
    #pragma unroll
    for (int nt = 0; nt < 4; ++nt) {
      int n_g = bn + wn + nt * 16 + (lane & 15);
      #pragma unroll
      for (int r = 0; r < 4; ++r) {
        int m_g = bm + wm + mt * 16 + kq * 4 + r;
        float v = acc[mt][nt][r] + bfu2f(R[(size_t)m_g * N + n_g]);
        C16[(size_t)m_g * N + n_g] = f2bfu(v);
      }
    }
}

// ---- 64x64 bf16 NN GEMM + bf16 residual -> bf16 out -----------------------
__launch_bounds__(256)
__global__ void gemm_bf16_nn_res64(const ushort_t* __restrict__ A, const ushort_t* __restrict__ B,
                                   const ushort_t* __restrict__ R, ushort_t* __restrict__ C16,
                                   int M, int N, int Kd) {
  __shared__ ushort_t As[64 * LROW];
  __shared__ ushort_t Bs[64 * LROW];
  int tid = threadIdx.x;
  int bm = blockIdx.y * 64, bn = blockIdx.x * 64;
  int wave = tid >> 6, lane = tid & 63;
  int wm = (wave >> 1) * 32, wn = (wave & 1) * 32;
  int mrow = lane & 15, kq = lane >> 4;
  int srow = tid >> 2, skof = (tid & 3) * 8;
  int krow = tid >> 3, nof = (tid & 7) * 8;

  f32x4 acc[2][2];
  #pragma unroll
  for (int i = 0; i < 2; ++i)
    #pragma unroll
    for (int j = 0; j < 2; ++j)
      #pragma unroll
      for (int r = 0; r < 4; ++r) acc[i][j][r] = 0.f;

  for (int k0 = 0; k0 < Kd; k0 += 32) {
    uint4 a0 = *(const uint4*)(A + (size_t)(bm + srow) * Kd + k0 + skof);
    ushort_t bb[8];
    *(uint4*)&bb[0] = *(const uint4*)(B + (size_t)(k0 + krow) * N + bn + nof);
    __syncthreads();
    *(uint4*)&As[srow * LROW + skof] = a0;
    #pragma unroll
    for (int j = 0; j < 8; ++j)
      Bs[(nof + j) * LROW + krow] = bb[j];
    __syncthreads();
    bf16x8 af[2], bf[2];
    #pragma unroll
    for (int mt = 0; mt < 2; ++mt)
      af[mt] = *(const bf16x8*)&As[(wm + mt * 16 + mrow) * LROW + kq * 8];
    #pragma unroll
    for (int nt = 0; nt < 2; ++nt)
      bf[nt] = *(const bf16x8*)&Bs[(wn + nt * 16 + mrow) * LROW + kq * 8];
    #pragma unroll
    for (int mt = 0; mt < 2; ++mt)
      #pragma unroll
      for (int nt = 0; nt < 2; ++nt)
        acc[mt][nt] = __builtin_amdgcn_mfma_f32_16x16x32_bf16(af[mt], bf[nt], acc[mt][nt], 0, 0, 0);
  }
  #pragma unroll
  for (int mt = 0; mt < 2; ++mt)
    #pragma unroll
    for (int nt = 0; nt < 2; ++nt) {
      int n_g = bn + wn + nt * 16 + (lane & 15);
      #pragma unroll
      for (int r = 0; r < 4; ++r) {
        int m_g = bm + wm + mt * 16 + kq * 4 + r;
        float v = acc[mt][nt][r] + bfu2f(R[(size_t)m_g * N + n_g]);
        C16[(size_t)m_g * N + n_g] = f2bfu(v);
      }
    }
}

// ---- split-K TN GEMM on bf16 inputs (Mm = X1^T @ X2) ----------------------
__global__ void gemm_tn_part(const ushort_t* __restrict__ A, const ushort_t* __restrict__ B,
                             float* __restrict__ part) {
  int tx = threadIdx.x & 15, ty = threadIdx.x >> 4;
  int i = blockIdx.y * 16 + ty, j = blockIdx.x * 16 + tx;
  int ks = blockIdx.z;
  float acc = 0.f;
  for (int k = ks * 128; k < ks * 128 + 128; ++k)
    acc += bfu2f(A[(size_t)k * 128 + i]) * bfu2f(B[(size_t)k * 128 + j]);
  part[(size_t)ks * 16384 + i * 128 + j] = acc;
}
__global__ void gemm_tn_reduce(const float* __restrict__ part, ushort_t* __restrict__ Mm) {
  int idx = blockIdx.x * 256 + threadIdx.x;
  float s = 0.f;
  #pragma unroll
  for (int ks = 0; ks < 16; ++ks) s += part[(size_t)ks * 16384 + idx];
  Mm[idx] = f2bfu(s);
}

// ============================================================================
// 3-stage column softmax (axis 0) on bf16 matrix, M=2048 rows, N=2048 cols.
// Stage A: per-(rowblk,col) partial (max, sumexp). Grid (N/64, M/128).
// Stage B: combine 16 partials per col. Stage C: normalize, coalesced.
// ============================================================================
__global__ void smax_partA(const ushort_t* __restrict__ S, float* __restrict__ pm,
                           float* __restrict__ pl, int N) {
  int t = threadIdx.x;
  int col = blockIdx.x * 64 + (t & 63);
  int g = t >> 6;
  int r0 = blockIdx.y * 128 + g;
  float vals[32];
  #pragma unroll
  for (int i = 0; i < 32; ++i)
    vals[i] = bfu2f(S[(size_t)(r0 + 4 * i) * N + col]);
  float m = -1e30f;
  #pragma unroll
  for (int i = 0; i < 32; ++i) m = fmaxf(m, vals[i]);
  float l = 0.f;
  #pragma unroll
  for (int i = 0; i < 32; ++i) l += expf(vals[i] - m);
  __shared__ float rm[4][64], rl[4][64];
  rm[g][t & 63] = m; rl[g][t & 63] = l;
  __syncthreads();
  if (g == 0) {
    int c = t & 63;
    float M0 = rm[0][c], L0 = rl[0][c];
    #pragma unroll
    for (int j = 1; j < 4; ++j) {
      float Mj = rm[j][c], Lj = rl[j][c];
      float nm = fmaxf(M0, Mj);
      L0 = L0 * expf(M0 - nm) + Lj * expf(Mj - nm);
      M0 = nm;
    }
    pm[(size_t)blockIdx.y * N + col] = M0;
    pl[(size_t)blockIdx.y * N + col] = L0;
  }
}
__global__ void smax_partB(const float* __restrict__ pm, const float* __restrict__ pl,
                           float* __restrict__ gm, float* __restrict__ gi, int N) {
  int col = blockIdx.x * 256 + threadIdx.x;
  float m = -1e30f, l = 0.f;
  for (int b = 0; b < 16; ++b) {
    float bm = pm[(size_t)b * N + col], bl = pl[(size_t)b * N + col];
    float nm = fmaxf(m, bm);
    l = l * expf(m - nm) + bl * expf(bm - nm);
    m = nm;
  }
  gm[col] = m;
  gi[col] = 1.f / l;
}
__global__ void smax_partC(ushort_t* __restrict__ S, const float* __restrict__ gm,
                           const float* __restrict__ gi, int N) {
  int t = threadIdx.x;
  int col = blockIdx.x * 64 + (t & 63);
  int g = t >> 6;
  float m = gm[col], inv = gi[col];
  int r0 = blockIdx.y * 128 + g;
  #pragma unroll 8
  for (int i = 0; i < 32; ++i) {
    size_t idx = (size_t)(r0 + 4 * i) * N + col;
    S[idx] = f2bfu(expf(bfu2f(S[idx]) - m) * inv);
  }
}

// ---- row squared-norms from bf16 ------------------------------------------
__global__ void row_norm_bf16(const ushort_t* __restrict__ X, float* __restrict__ out, int Kd) {
  int r = blockIdx.x;
  int t = threadIdx.x;
  float s = 0.f;
  for (int k = t; k < Kd; k += 64) { float v = bfu2f(X[(size_t)r * Kd + k]); s += v * v; }
  for (int off = 32; off; off >>= 1) s += __shfl_down(s, off);
  if (t == 0) out[r] = s;
}

// ---- mask scores (A3 fp32) ------------------------------------------------
__global__ void mask_score(const float* __restrict__ A3, const float* __restrict__ w4,
                           const float* __restrict__ b4, float* __restrict__ s) {
  int k = blockIdx.x * 256 + threadIdx.x;
  float acc = b4[0];
  for (int h = 0; h < 128; ++h) acc += A3[(size_t)h * 2048 + k] * w4[h];
  s[k] = acc;
}

// ---- stable descending-argsort rank -> top-S indices ----------------------
__global__ void topk_rank(const float* __restrict__ s, int* __restrict__ idx, int K, int S) {
  int j = blockIdx.x * 256 + threadIdx.x;
  if (j >= K) return;
  float sj = s[j];
  int rank = 0;
  for (int i = 0; i < K; ++i) {
    float si = s[i];
    rank += (si > sj) || (si == sj && i < j);
  }
  if (rank < S) idx[rank] = j;
}

// ---- build cat = [B_dt | softmax(aff_s[:,idx],axis=1) | 0pad], bf16 -------
__global__ void build_cat(const ushort_t* __restrict__ Bdt, const ushort_t* __restrict__ affs,
                          const int* __restrict__ idx, ushort_t* __restrict__ cat) {
  int r = blockIdx.x, t = threadIdx.x;
  __shared__ float vals[256];
  __shared__ float red[256];
  float v = -1e30f;
  if (t < 204) {
    int ix = idx[t];
    ix = ix < 0 ? 0 : (ix > 2047 ? 2047 : ix);
    v = bfu2f(affs[(size_t)r * 2048 + ix]);
  }
  vals[t] = v;
  red[t] = v;
  __syncthreads();
  for (int off = 128; off; off >>= 1) { if (t < off) red[t] = fmaxf(red[t], red[t + off]); __syncthreads(); }
  float m = red[0];
  __syncthreads();
  float e = (t < 204) ? expf(vals[t] - m) : 0.f;
  red[t] = e;
  __syncthreads();
  for (int off = 128; off; off >>= 1) { if (t < off) red[t] += red[t + off]; __syncthreads(); }
  float inv = 1.f / red[0];
  cat[(size_t)r * 512 + t] = Bdt[(size_t)r * 256 + t];
  cat[(size_t)r * 512 + 256 + t] = (t < 204) ? f2bfu(e * inv) : (ushort_t)0;
}

// ---- a = leaky((AV*AU) @ aww.T + awb) -------------------------------------
__global__ void attn_gate(const float* __restrict__ AV, const float* __restrict__ AU,
                          const float* __restrict__ aww, const float* __restrict__ awb,
                          float* __restrict__ a, int n) {
  int r = blockIdx.x * 256 + threadIdx.x;
  if (r >= n) return;
  float acc = awb[0];
  for (int d = 0; d < 128; ++d) acc += AV[(size_t)r * 128 + d] * AU[(size_t)r * 128 + d] * aww[d];
  a[r] = LEAKY(acc);
}

// ---- 1-D softmax (single block) -------------------------------------------
__global__ void softmax_vec(const float* __restrict__ x, float* __restrict__ y,
                            float* __restrict__ y2, int n) {
  __shared__ float red[256];
  int t = threadIdx.x;
  float m = -1e30f;
  for (int i = t; i < n; i += 256) m = fmaxf(m, x[i]);
  red[t] = m;
  __syncthreads();
  for (int off = 128; off; off >>= 1) { if (t < off) red[t] = fmaxf(red[t], red[t + off]); __syncthreads(); }
  m = red[0];
  __syncthreads();
  float s = 0.f;
  for (int i = t; i < n; i += 256) s += expf(x[i] - m);
  red[t] = s;
  __syncthreads();
  for (int off = 128; off; off >>= 1) { if (t < off) red[t] += red[t + off]; __syncthreads(); }
  float inv = 1.f / red[0];
  for (int i = t; i < n; i += 256) {
    float v = expf(x[i] - m) * inv;
    y[i] = v;
    if (y2) y2[i] = v;
  }
}

// ---- weighted column sum over bf16 H, two-stage ---------------------------
__global__ void colsum_part(const float* __restrict__ wv, const ushort_t* __restrict__ H,
                            float* __restrict__ part, int n) {
  int bk = blockIdx.x, c = threadIdx.x;
  float s = 0.f;
  for (int r = bk; r < n; r += 16) s += wv[r] * bfu2f(H[(size_t)r * 256 + c]);
  part[bk * 256 + c] = s;
}
__global__ void colsum_fin(const float* __restrict__ part, float* __restrict__ out) {
  int c = threadIdx.x;
  float s = 0.f;
  #pragma unroll
  for (int k = 0; k < 16; ++k) s += part[k * 256 + c];
  out[c] = s;
}

// ---- small gemv -----------------------------------------------------------
__global__ void gemv_act(const float* __restrict__ x, const float* __restrict__ W,
                         const float* __restrict__ b, float* __restrict__ out,
                         int O, int Kd, int act) {
  int o = blockIdx.x * blockDim.x + threadIdx.x;
  if (o >= O) return;
  float acc = b ? b[o] : 0.f;
  for (int k = 0; k < Kd; ++k) acc += x[k] * W[(size_t)o * Kd + k];
  if (act == 1) acc = LEAKY(acc);
  out[o] = acc;
}

// ---- cat2 = [B_fuse | tile(M1)], bf16 -------------------------------------
__global__ void build_cat2(const ushort_t* __restrict__ Bf, const float* __restrict__ M1,
                           ushort_t* __restrict__ cat2) {
  int r = blockIdx.x, t = threadIdx.x;  // 512 threads
  cat2[(size_t)r * 512 + t] = (t < 256) ? Bf[(size_t)r * 256 + t] : f2bfu(M1[t - 256]);
}

// ---- final head -----------------------------------------------------------
__global__ void final_head(const float* __restrict__ AH2, const float* __restrict__ embw,
                           const float* __restrict__ embb, const float* __restrict__ sembw,
                           const float* __restrict__ sembb, const float* __restrict__ clsw,
                           const float* __restrict__ clsb, float* __restrict__ Yout) {
  __shared__ float bvec[512];
  __shared__ float red[512];
  int t = threadIdx.x;
  float acc = embb[t];
  for (int c = 0; c < 256; ++c) acc += AH2[c] * embw[(size_t)t * 256 + c];
  bvec[t] = LEAKY(acc);
  __syncthreads();
  float p = 0.f;
  if (t < 256) {
    float a2 = sembb[t];
    for (int c = 0; c < 512; ++c) a2 += bvec[c] * sembw[(size_t)t * 512 + c];
    a2 = LEAKY(a2);
    p = a2 * clsw[t];
  }
  red[t] = p;
  __syncthreads();
  for (int off = 256; off; off >>= 1) { if (t < off) red[t] += red[t + off]; __syncthreads(); }
  if (t == 0) {
    float y = red[0] + clsb[0];
    y = 1.f / (1.f + expf(-y));
    y = fminf(fmaxf(y, 1e-5f), 1.f - 1e-5f);
    Yout[0] = y;
  }
}

extern "C" void kernel_launch(void* const* d_in, const int* in_sizes, int n_in,
                              void* d_out, int out_size, void* d_ws, size_t ws_size,
                              hipStream_t stream) {
  auto IN = [&](int i) { return (const float*)d_in[i]; };
  (void)n_in; (void)in_sizes; (void)out_size;

  const int S = 204;
  float* out_f = (float*)d_out;  // out[0]=Y, out[1..2048]=A

  float* W = (float*)d_ws;
  size_t off = 0;
  auto F = [&](size_t n) { float* p = W + off; off += n; return p; };
  auto FU = [&](size_t nus) { return (ushort_t*)F((nus + 1) / 2); };

  ushort_t* dt_b  = FU((size_t)4096 * 256);
  ushort_t* Xs_b  = FU((size_t)2048 * 256);
  ushort_t* Ks_b  = FU((size_t)2048 * 256);
  ushort_t* X1b   = FU((size_t)2048 * 128);
  ushort_t* X2b   = FU((size_t)2048 * 128);
  ushort_t* aff_b = FU((size_t)2048 * 2048);  // euclid out; skip3 in-place -> aff_s
  float* AV    = F((size_t)2048 * 128);
  float* AU    = F((size_t)2048 * 128);
  ushort_t* Mm_b = FU((size_t)128 * 128);
  float* svec  = F(2048);
  int*   idxb  = (int*)F(256);
  float* avec  = F(2048);
  float* Awv   = F(2048);
  float* AH    = F(256);
  float* M1v   = F(256);
  float* AH2   = F(256);
  float* nx    = F(2048);
  float* ny    = F(2048);
  float* part  = F(4096);
  float* sm_pm = F((size_t)16 * 2048);
  float* sm_pl = F((size_t)16 * 2048);
  float* sm_gm = F(2048);
  float* sm_gi = F(2048);

  // bf16 weight arena
  size_t wo = 0;
  ushort_t* warena = (ushort_t*)F(3227872);
  auto WA = [&](size_t n) { ushort_t* p = warena + wo; wo = (wo + n + 15) & ~(size_t)15; return p; };
  ushort_t* w2b   = WA(25000);
  ushort_t* embb_ = WA(204800);
  ushort_t* s1w1 = WA(32768); ushort_t* s1w2 = WA(32768); ushort_t* s1w3 = WA(65536);
  ushort_t* s2w1 = WA(32768); ushort_t* s2w2 = WA(32768); ushort_t* s2w3 = WA(65536);
  ushort_t* s3w1 = WA(262144); ushort_t* s3w2 = WA(262144); ushort_t* s3w3 = WA(4194304);
  ushort_t* mw1 = WA(262144); ushort_t* mw2 = WA(262144); ushort_t* mw3 = WA(262144);
  ushort_t* fwp = WA(131072);
  ushort_t* a1fe = WA(65536); ushort_t* a1v = WA(32768); ushort_t* a1u = WA(32768);
  ushort_t* a2fe = WA(131072); ushort_t* a2v = WA(32768); ushort_t* a2u = WA(32768);

  float* pool = F((size_t)4194304);

  const size_t NEED_BYTES = off * 4;
  if (ws_size < NEED_BYTES) {
    fill_out<<<9, 256, 0, stream>>>(out_f, 2049);
    return;
  }

  // pool members (phase-disjoint)
  ushort_t* h2h_b  = (ushort_t*)pool;                 // conv: 2048*800 us
  ushort_t* Smat_b = (ushort_t*)pool;                 // skip: 2048*2048 us
  ushort_t* X3s_b  = (ushort_t*)(pool + 2097152);     // skip1/2: 2048*256 us
  ushort_t* X3b_b  = (ushort_t*)(pool + 2097152);     // skip3: 2048*2048 us
  float* A3   = pool;                                 // mask: 128*2048 fp32
  float* tnpt = pool + 262144;                        // mask: 16*16384 fp32
  ushort_t* cat_b   = (ushort_t*)pool;                // fuse: 2048*512 us
  ushort_t* cat2_b  = (ushort_t*)(pool + 524288);     // 2048*512 us
  ushort_t* Bfuse_b = (ushort_t*)(pool + 1048576);    // 2048*256 us
  ushort_t* Hbuf_b  = (ushort_t*)(pool + 1310720);    // 2048*256 us

  // ---- weight conversion (once per launch) ----
  CvtArgs ca;
  const float* srcs[20] = { IN(4), IN(6), IN(8), IN(10), IN(12), IN(14), IN(16), IN(18),
                            IN(20), IN(22), IN(24), IN(26), IN(28), IN(30),
                            IN(36), IN(38), IN(40), IN(46), IN(48), IN(50) };
  ushort_t* dsts[20] = { w2b, embb_, s1w1, s1w2, s1w3, s2w1, s2w2, s2w3,
                         s3w1, s3w2, s3w3, mw1, mw2, mw3,
                         a1fe, a1v, a1u, a2fe, a2v, a2u };
  int lens[20] = { 25000, 204800, 32768, 32768, 65536, 32768, 32768, 65536,
                   262144, 262144, 4194304, 262144, 262144, 262144,
                   65536, 32768, 32768, 131072, 32768, 32768 };
  for (int i = 0; i < 20; ++i) { ca.src[i] = srcs[i]; ca.dst[i] = dsts[i]; ca.len[i] = lens[i]; }
  to_bf16_multi<<<1024, 256, 0, stream>>>(ca);
  pad_fuse_bf16<<<512, 256, 0, stream>>>(IN(34), fwp);

  auto softmax_col = [&](ushort_t* Smat) {
    smax_partA<<<dim3(32, 16), 256, 0, stream>>>(Smat, sm_pm, sm_pl, 2048);
    smax_partB<<<8, 256, 0, stream>>>(sm_pm, sm_pl, sm_gm, sm_gi, 2048);
    smax_partC<<<dim3(32, 16), 256, 0, stream>>>(Smat, sm_gm, sm_gi, 2048);
  };

  // ---- data_transform for B (g=0) and KB (g=1) ----
  for (int g = 0; g < 2; ++g) {
    conv12_mfma<<<1024, 256, 0, stream>>>(IN(g), IN(2), IN(3), w2b, IN(5), h2h_b);
    gemm_bf16_nt64<EPI_LEAKY><<<dim3(4, 32), 256, 0, stream>>>(
        h2h_b, embb_, IN(7), nullptr, dt_b + (size_t)g * 2048 * 256, 2048, 256, 800);
  }
  ushort_t* B_dtb = dt_b;
  ushort_t* KB_dtb = dt_b + (size_t)2048 * 256;

  // ---- skip_block 1 (B_dt -> Xs) and 2 (KB_dt -> Ks) ----
  for (int g = 0; g < 2; ++g) {
    ushort_t* Xin = g ? KB_dtb : B_dtb;
    ushort_t* Xout = g ? Ks_b : Xs_b;
    ushort_t* w1 = g ? s2w1 : s1w1;
    ushort_t* w2 = g ? s2w2 : s1w2;
    ushort_t* w3 = g ? s2w3 : s1w3;
    int wi = g ? 14 : 8;
    gemm_bf16_nt64<EPI_LEAKY_BN><<<dim3(2, 32), 256, 0, stream>>>(
        Xin, w1, IN(wi + 1), nullptr, X1b, 2048, 128, 256);
    gemm_bf16_nt64<EPI_LEAKY_BN><<<dim3(2, 32), 256, 0, stream>>>(
        Xin, w2, IN(wi + 3), nullptr, X2b, 2048, 128, 256);
    gemm_bf16_nt64<EPI_LEAKY_BN><<<dim3(4, 32), 256, 0, stream>>>(
        Xin, w3, IN(wi + 5), nullptr, X3s_b, 2048, 256, 256);
    gemm_bf16_nt<EPI_NONE><<<dim3(16, 16), 256, 0, stream>>>(
        X1b, X2b, nullptr, nullptr, Smat_b, 2048, 2048, 128, nullptr, nullptr);
    softmax_col(Smat_b);
    gemm_bf16_nn_res64<<<dim3(4, 32), 256, 0, stream>>>(Smat_b, X3s_b, Xin, Xout, 2048, 256, 2048);
  }

  // ---- euclid -> aff_b ----
  row_norm_bf16<<<2048, 64, 0, stream>>>(Xs_b, nx, 256);
  row_norm_bf16<<<2048, 64, 0, stream>>>(Ks_b, ny, 256);
  gemm_bf16_nt<EPI_EUCLID><<<dim3(16, 16), 256, 0, stream>>>(
      Xs_b, Ks_b, nullptr, nullptr, aff_b, 2048, 2048, 256, nx, ny);

  // ---- skip_block 3 (aff_b -> aff_b in-place) ----
  gemm_bf16_nt64<EPI_LEAKY_BN><<<dim3(2, 32), 256, 0, stream>>>(
      aff_b, s3w1, IN(21), nullptr, X1b, 2048, 128, 2048);
  gemm_bf16_nt64<EPI_LEAKY_BN><<<dim3(2, 32), 256, 0, stream>>>(
      aff_b, s3w2, IN(23), nullptr, X2b, 2048, 128, 2048);
  gemm_bf16_nt<EPI_LEAKY_BN><<<dim3(16, 16), 256, 0, stream>>>(
      aff_b, s3w3, IN(25), nullptr, X3b_b, 2048, 2048, 2048, nullptr, nullptr);
  gemm_bf16_nt<EPI_NONE><<<dim3(16, 16), 256, 0, stream>>>(
      X1b, X2b, nullptr, nullptr, Smat_b, 2048, 2048, 128, nullptr, nullptr);
  softmax_col(Smat_b);
  gemm_bf16_nn_res<<<dim3(16, 16), 256, 0, stream>>>(Smat_b, X3b_b, aff_b, aff_b, 2048, 2048, 2048);
  ushort_t* affs_b = aff_b;

  // ---- mask_scores -> top-S idx ----
  gemm_bf16_nt64<EPI_LEAKY><<<dim3(2, 32), 256, 0, stream>>>(
      affs_b, mw1, IN(27), nullptr, X1b, 2048, 128, 2048);
  gemm_bf16_nt64<EPI_TANH><<<dim3(2, 32), 256, 0, stream>>>(
      affs_b, mw2, IN(29), nullptr, X2b, 2048, 128, 2048);
  gemm_tn_part<<<dim3(8, 8, 16), 256, 0, stream>>>(X1b, X2b, tnpt);
  gemm_tn_reduce<<<64, 256, 0, stream>>>(tnpt, Mm_b);
  gemm_bf16_nt64<EPI_LEAKY><<<dim3(32, 2), 256, 0, stream>>>(
      Mm_b, mw3, IN(31), A3, nullptr, 128, 2048, 128);
  mask_score<<<8, 256, 0, stream>>>(A3, IN(32), IN(33), svec);
  topk_rank<<<8, 256, 0, stream>>>(svec, idxb, 2048, S);

  // ---- B_bag + concat (bf16, pad 512) + fuse ----
  build_cat<<<2048, 256, 0, stream>>>(B_dtb, affs_b, idxb, cat_b);
  gemm_bf16_nt64<EPI_LEAKY><<<dim3(4, 32), 256, 0, stream>>>(
      cat_b, fwp, IN(35), nullptr, Bfuse_b, 2048, 256, 512);

  // ---- attention 1 ----
  gemm_bf16_nt64<EPI_LEAKY><<<dim3(4, 32), 256, 0, stream>>>(
      Bfuse_b, a1fe, IN(37), nullptr, Hbuf_b, 2048, 256, 256);
  gemm_bf16_nt64<EPI_TANH><<<dim3(2, 32), 256, 0, stream>>>(
      Hbuf_b, a1v, IN(39), AV, nullptr, 2048, 128, 256);
  gemm_bf16_nt64<EPI_LEAKY><<<dim3(2, 32), 256, 0, stream>>>(
      Hbuf_b, a1u, IN(41), AU, nullptr, 2048, 128, 256);
  attn_gate<<<8, 256, 0, stream>>>(AV, AU, IN(42), IN(43), avec, 2048);
  softmax_vec<<<1, 256, 0, stream>>>(avec, Awv, nullptr, 2048);
  colsum_part<<<16, 256, 0, stream>>>(Awv, Hbuf_b, part, 2048);
  colsum_fin<<<1, 256, 0, stream>>>(part, AH);
  gemv_act<<<1, 256, 0, stream>>>(AH, IN(44), IN(45), M1v, 256, 256, 1);
  build_cat2<<<2048, 512, 0, stream>>>(Bfuse_b, M1v, cat2_b);

  // ---- attention 2 (A -> output) ----
  gemm_bf16_nt64<EPI_LEAKY><<<dim3(4, 32), 256, 0, stream>>>(
      cat2_b, a2fe, IN(47), nullptr, Hbuf_b, 2048, 256, 512);
  gemm_bf16_nt64<EPI_TANH><<<dim3(2, 32), 256, 0, stream>>>(
      Hbuf_b, a2v, IN(49), AV, nullptr, 2048, 128, 256);
  gemm_bf16_nt64<EPI_LEAKY><<<dim3(2, 32), 256, 0, stream>>>(
      Hbuf_b, a2u, IN(51), AU, nullptr, 2048, 128, 256);
  attn_gate<<<8, 256, 0, stream>>>(AV, AU, IN(52), IN(53), avec, 2048);
  softmax_vec<<<1, 256, 0, stream>>>(avec, Awv, out_f + 1, 2048);
  colsum_part<<<16, 256, 0, stream>>>(Awv, Hbuf_b, part, 2048);
  colsum_fin<<<1, 256, 0, stream>>>(part, AH2);

  // ---- final head -> Y ----
  final_head<<<1, 512, 0, stream>>>(AH2, IN(54), IN(55), IN(56), IN(57),
                                    IN(58), IN(59), out_f);
}

// Round 9
// 1196.519 us; speedup vs baseline: 8.4471x; 1.0394x over previous
//
#include <hip/hip_runtime.h>
#include <math.h>

#define LEAKY(x) ((x) > 0.f ? (x) : 0.01f * (x))
static constexpr float BN_SCALE = 0.9999950000374997f;

typedef unsigned short ushort_t;
typedef float f32x4 __attribute__((ext_vector_type(4)));
typedef short bf16x8 __attribute__((ext_vector_type(8)));

__device__ __forceinline__ ushort_t f2bfu(float f) {
  union { float f; unsigned u; } v; v.f = f;
  unsigned r = v.u + 0x7fffu + ((v.u >> 16) & 1u);
  return (ushort_t)(r >> 16);
}
__device__ __forceinline__ float bfu2f(ushort_t u) {
  union { unsigned u; float f; } v; v.u = ((unsigned)u) << 16;
  return v.f;
}

// ---- fallback sentinel if workspace is too small ---------------------------
__global__ void fill_out(float* out, int n) {
  int i = blockIdx.x * 256 + threadIdx.x;
  if (i < n) out[i] = 0.25f;
}

// ---- one-shot fp32 -> bf16 conversion of up to 20 tensors -----------------
struct CvtArgs {
  const float* src[20];
  ushort_t* dst[20];
  int len[20];
};
__global__ void to_bf16_multi(CvtArgs a) {
  for (int s = 0; s < 20; ++s) {
    const float* sp = a.src[s];
    ushort_t* dp = a.dst[s];
    int n = a.len[s];
    for (int i = blockIdx.x * 256 + threadIdx.x; i < n; i += gridDim.x * 256)
      dp[i] = f2bfu(sp[i]);
  }
}

// ---- pad fuse_w [256,460] fp32 -> [256,512] bf16 --------------------------
__global__ void pad_fuse_bf16(const float* __restrict__ w, ushort_t* __restrict__ wp) {
  int idx = blockIdx.x * 256 + threadIdx.x;
  if (idx >= 256 * 512) return;
  int o = idx >> 9, k = idx & 511;
  wp[idx] = (k < 460) ? f2bfu(w[(size_t)o * 460 + k]) : (ushort_t)0;
}

// ============================================================================
// Fused conv1+pool+conv2+pool via MFMA implicit GEMM. 2 images/block.
// ============================================================================
__launch_bounds__(256)
__global__ void conv12_mfma(const float* __restrict__ img, const float* __restrict__ w1,
                            const float* __restrict__ b1, const ushort_t* __restrict__ w2b,
                            const float* __restrict__ b2, ushort_t* __restrict__ out800) {
  __shared__ __align__(16) char smem[39168];
  ushort_t* sh1u = (ushort_t*)smem;                 // [2*2880]
  float* simg = (float*)(smem + 11520);             // [2*784] (phase 1)
  float* sw1  = (float*)(smem + 11520 + 6272);      // [500]   (phase 1)
  ushort_t* As = (ushort_t*)(smem + 11520);         // [128*72] (phase 2)
  ushort_t* Bs = (ushort_t*)(smem + 29952);         // [64*72]  (phase 2)
  float* Cf = (float*)smem;                         // [128*68] (epilogue)

  int tid = threadIdx.x;
  const float* imgb = img + (size_t)blockIdx.x * 2 * 784;

  for (int i = tid; i < 1568; i += 256) simg[i] = imgb[i];
  for (int i = tid; i < 500; i += 256) sw1[i] = w1[i];
  __syncthreads();
  for (int o = tid; o < 5760; o += 256) {
    int im = o / 2880, oi = o % 2880;
    int c = oi / 144, rem = oi % 144, py = rem / 12, px = rem % 12;
    int y0 = py * 2, x0 = px * 2;
    const float* sb = &simg[im * 784];
    float p[6][6];
    #pragma unroll
    for (int yy = 0; yy < 6; ++yy)
      #pragma unroll
      for (int xx = 0; xx < 6; ++xx)
        p[yy][xx] = sb[(y0 + yy) * 28 + x0 + xx];
    float bb = b1[c];
    float t0 = bb, t1 = bb, t2 = bb, t3 = bb;
    const float* wc = &sw1[c * 25];
    #pragma unroll
    for (int ky = 0; ky < 5; ++ky)
      #pragma unroll
      for (int kx = 0; kx < 5; ++kx) {
        float wv = wc[ky * 5 + kx];
        t0 += p[ky][kx] * wv;
        t1 += p[ky][kx + 1] * wv;
        t2 += p[ky + 1][kx] * wv;
        t3 += p[ky + 1][kx + 1] * wv;
      }
    t0 = LEAKY(t0); t1 = LEAKY(t1); t2 = LEAKY(t2); t3 = LEAKY(t3);
    sh1u[o] = f2bfu(fmaxf(fmaxf(t0, t1), fmaxf(t2, t3)));
  }

  int wave = tid >> 6, lane = tid & 63;
  int wm = (wave >> 1) * 64, wn = (wave & 1) * 32;
  int mrow = lane & 15, kq = lane >> 4;
  int kl = tid & 63, rbase = tid >> 6;

  f32x4 acc[4][2];
  #pragma unroll
  for (int i = 0; i < 4; ++i)
    #pragma unroll
    for (int j = 0; j < 2; ++j)
      #pragma unroll
      for (int r = 0; r < 4; ++r) acc[i][j][r] = 0.f;

  for (int k0 = 0; k0 < 512; k0 += 64) {
    __syncthreads();
    int k = k0 + kl;
    bool valid = k < 500;
    int ic = k / 25, tap = k - ic * 25;
    int ky = tap / 5, kx = tap - ky * 5;
    int kof = ic * 144 + ky * 12 + kx;
    ushort_t tA[32];
    #pragma unroll
    for (int i = 0; i < 32; ++i) {
      int r = rbase + 4 * i;
      int im = r >> 6, pos = r & 63, oy = pos >> 3, ox = pos & 7;
      tA[i] = valid ? sh1u[im * 2880 + kof + oy * 12 + ox] : (ushort_t)0;
    }
    ushort_t tB[16];
    #pragma unroll
    for (int i = 0; i < 16; ++i) {
      int oc = rbase + 4 * i;
      tB[i] = (valid && oc < 50) ? w2b[(size_t)oc * 500 + k] : (ushort_t)0;
    }
    #pragma unroll
    for (int i = 0; i < 32; ++i) As[(rbase + 4 * i) * 72 + kl] = tA[i];
    #pragma unroll
    for (int i = 0; i < 16; ++i) Bs[(rbase + 4 * i) * 72 + kl] = tB[i];
    __syncthreads();
    #pragma unroll
    for (int ks = 0; ks < 2; ++ks) {
      bf16x8 af[4], bf[2];
      #pragma unroll
      for (int mt = 0; mt < 4; ++mt)
        af[mt] = *(const bf16x8*)&As[(wm + mt * 16 + mrow) * 72 + ks * 32 + kq * 8];
      #pragma unroll
      for (int nt = 0; nt < 2; ++nt)
        bf[nt] = *(const bf16x8*)&Bs[(wn + nt * 16 + mrow) * 72 + ks * 32 + kq * 8];
      #pragma unroll
      for (int mt = 0; mt < 4; ++mt)
        #pragma unroll
        for (int nt = 0; nt < 2; ++nt)
          acc[mt][nt] = __builtin_amdgcn_mfma_f32_16x16x32_bf16(af[mt], bf[nt], acc[mt][nt], 0, 0, 0);
    }
  }
  __syncthreads();
  #pragma unroll
  for (int mt = 0; mt < 4; ++mt)
    #pragma unroll
    for (int nt = 0; nt < 2; ++nt) {
      int n0 = wn + nt * 16 + (lane & 15);
      #pragma unroll
      for (int r = 0; r < 4; ++r)
        Cf[(wm + mt * 16 + kq * 4 + r) * 68 + n0] = acc[mt][nt][r];
    }
  __syncthreads();
  for (int o = tid; o < 1600; o += 256) {
    int im = o / 800, oi = o - im * 800;
    int oc = oi >> 4, p = oi & 15, py = p >> 2, px = p & 3;
    int r0 = im * 64 + py * 16 + px * 2;
    float bb = b2[oc];
    float t0 = LEAKY(Cf[r0 * 68 + oc] + bb);
    float t1 = LEAKY(Cf[(r0 + 1) * 68 + oc] + bb);
    float t2 = LEAKY(Cf[(r0 + 8) * 68 + oc] + bb);
    float t3 = LEAKY(Cf[(r0 + 9) * 68 + oc] + bb);
    out800[(size_t)(blockIdx.x * 2 + im) * 800 + oi] = f2bfu(fmaxf(fmaxf(t0, t1), fmaxf(t2, t3)));
  }
}

// ---------------- epilogue kinds -------------------------------------------
enum { EPI_NONE = 0, EPI_LEAKY = 1, EPI_LEAKY_BN = 2, EPI_TANH = 3, EPI_EUCLID = 4 };

#define LROW 40

// ---- 128x128 bf16 NT GEMM. Dual store C32/C16 -----------------------------
template <int EPI>
__launch_bounds__(256)
__global__ void gemm_bf16_nt(const ushort_t* __restrict__ A, const ushort_t* __restrict__ B,
                             const float* __restrict__ bias, float* __restrict__ C32,
                             ushort_t* __restrict__ C16, int M, int N, int Kd,
                             const float* __restrict__ e1, const float* __restrict__ e2) {
  __shared__ ushort_t As[128 * LROW];
  __shared__ ushort_t Bs[128 * LROW];
  int tid = threadIdx.x;
  int bm = blockIdx.y * 128, bn = blockIdx.x * 128;
  int wave = tid >> 6, lane = tid & 63;
  int wm = (wave >> 1) * 64, wn = (wave & 1) * 64;
  int mrow = lane & 15, kq = lane >> 4;
  int srow = tid >> 1, skof = (tid & 1) * 16;

  f32x4 acc[4][4];
  #pragma unroll
  for (int i = 0; i < 4; ++i)
    #pragma unroll
    for (int j = 0; j < 4; ++j)
      #pragma unroll
      for (int r = 0; r < 4; ++r) acc[i][j][r] = 0.f;

  for (int k0 = 0; k0 < Kd; k0 += 32) {
    const uint4* ap = (const uint4*)(A + (size_t)(bm + srow) * Kd + k0 + skof);
    const uint4* bp = (const uint4*)(B + (size_t)(bn + srow) * Kd + k0 + skof);
    uint4 a0 = ap[0], a1 = ap[1];
    uint4 b0 = bp[0], b1 = bp[1];
    __syncthreads();
    *(uint4*)&As[srow * LROW + skof] = a0;
    *(uint4*)&As[srow * LROW + skof + 8] = a1;
    *(uint4*)&Bs[srow * LROW + skof] = b0;
    *(uint4*)&Bs[srow * LROW + skof + 8] = b1;
    __syncthreads();
    bf16x8 af[4], bf[4];
    #pragma unroll
    for (int mt = 0; mt < 4; ++mt)
      af[mt] = *(const bf16x8*)&As[(wm + mt * 16 + mrow) * LROW + kq * 8];
    #pragma unroll
    for (int nt = 0; nt < 4; ++nt)
      bf[nt] = *(const bf16x8*)&Bs[(wn + nt * 16 + mrow) * LROW + kq * 8];
    #pragma unroll
    for (int mt = 0; mt < 4; ++mt)
      #pragma unroll
      for (int nt = 0; nt < 4; ++nt)
        acc[mt][nt] = __builtin_amdgcn_mfma_f32_16x16x32_bf16(af[mt], bf[nt], acc[mt][nt], 0, 0, 0);
  }
  #pragma unroll
  for (int mt = 0; mt < 4; ++mt)
    #pragma unroll
    for (int nt = 0; nt < 4; ++nt) {
      int n_g = bn + wn + nt * 16 + (lane & 15);
      #pragma unroll
      for (int r = 0; r < 4; ++r) {
        int m_g = bm + wm + mt * 16 + kq * 4 + r;
        float v = acc[mt][nt][r];
        if (EPI == EPI_EUCLID) {
          v = e1[m_g] + e2[n_g] - 2.f * v;
          v = sqrtf(fmaxf(v, 0.f));
        } else {
          if (bias) v += bias[n_g];
          if (EPI == EPI_LEAKY) v = LEAKY(v);
          else if (EPI == EPI_LEAKY_BN) { v = LEAKY(v); v *= BN_SCALE; }
          else if (EPI == EPI_TANH) v = tanhf(v);
        }
        if (C32) C32[(size_t)m_g * N + n_g] = v;
        if (C16) C16[(size_t)m_g * N + n_g] = f2bfu(v);
      }
    }
}

// ---- 64x64 bf16 NT GEMM ---------------------------------------------------
template <int EPI>
__launch_bounds__(256)
__global__ void gemm_bf16_nt64(const ushort_t* __restrict__ A, const ushort_t* __restrict__ B,
                               const float* __restrict__ bias, float* __restrict__ C32,
                               ushort_t* __restrict__ C16, int M, int N, int Kd) {
  __shared__ ushort_t As[64 * LROW];
  __shared__ ushort_t Bs[64 * LROW];
  int tid = threadIdx.x;
  int bm = blockIdx.y * 64, bn = blockIdx.x * 64;
  int wave = tid >> 6, lane = tid & 63;
  int wm = (wave >> 1) * 32, wn = (wave & 1) * 32;
  int mrow = lane & 15, kq = lane >> 4;
  int srow = tid >> 2, skof = (tid & 3) * 8;

  f32x4 acc[2][2];
  #pragma unroll
  for (int i = 0; i < 2; ++i)
    #pragma unroll
    for (int j = 0; j < 2; ++j)
      #pragma unroll
      for (int r = 0; r < 4; ++r) acc[i][j][r] = 0.f;

  for (int k0 = 0; k0 < Kd; k0 += 32) {
    uint4 a0 = *(const uint4*)(A + (size_t)(bm + srow) * Kd + k0 + skof);
    uint4 b0 = *(const uint4*)(B + (size_t)(bn + srow) * Kd + k0 + skof);
    __syncthreads();
    *(uint4*)&As[srow * LROW + skof] = a0;
    *(uint4*)&Bs[srow * LROW + skof] = b0;
    __syncthreads();
    bf16x8 af[2], bf[2];
    #pragma unroll
    for (int mt = 0; mt < 2; ++mt)
      af[mt] = *(const bf16x8*)&As[(wm + mt * 16 + mrow) * LROW + kq * 8];
    #pragma unroll
    for (int nt = 0; nt < 2; ++nt)
      bf[nt] = *(const bf16x8*)&Bs[(wn + nt * 16 + mrow) * LROW + kq * 8];
    #pragma unroll
    for (int mt = 0; mt < 2; ++mt)
      #pragma unroll
      for (int nt = 0; nt < 2; ++nt)
        acc[mt][nt] = __builtin_amdgcn_mfma_f32_16x16x32_bf16(af[mt], bf[nt], acc[mt][nt], 0, 0, 0);
  }
  #pragma unroll
  for (int mt = 0; mt < 2; ++mt)
    #pragma unroll
    for (int nt = 0; nt < 2; ++nt) {
      int n_g = bn + wn + nt * 16 + (lane & 15);
      #pragma unroll
      for (int r = 0; r < 4; ++r) {
        int m_g = bm + wm + mt * 16 + kq * 4 + r;
        float v = acc[mt][nt][r];
        if (bias) v += bias[n_g];
        if (EPI == EPI_LEAKY) v = LEAKY(v);
        else if (EPI == EPI_LEAKY_BN) { v = LEAKY(v); v *= BN_SCALE; }
        else if (EPI == EPI_TANH) v = tanhf(v);
        if (C32) C32[(size_t)m_g * N + n_g] = v;
        if (C16) C16[(size_t)m_g * N + n_g] = f2bfu(v);
      }
    }
}

// ---- 128x128 bf16 NN GEMM + bf16 residual -> bf16 out ---------------------
__launch_bounds__(256)
__global__ void gemm_bf16_nn_res(const ushort_t* __restrict__ A, const ushort_t* __restrict__ B,
                                 const ushort_t* __restrict__ R, ushort_t* __restrict__ C16,
                                 int M, int N, int Kd) {
  __shared__ ushort_t As[128 * LROW];
  __shared__ ushort_t Bs[128 * LROW];
  int tid = threadIdx.x;
  int bm = blockIdx.y * 128, bn = blockIdx.x * 128;
  int wave = tid >> 6, lane = tid & 63;
  int wm = (wave >> 1) * 64, wn = (wave & 1) * 64;
  int mrow = lane & 15, kq = lane >> 4;
  int srow = tid >> 1, skof = (tid & 1) * 16;
  int krow = tid >> 3, nof = (tid & 7) * 16;

  f32x4 acc[4][4];
  #pragma unroll
  for (int i = 0; i < 4; ++i)
    #pragma unroll
    for (int j = 0; j < 4; ++j)
      #pragma unroll
      for (int r = 0; r < 4; ++r) acc[i][j][r] = 0.f;

  for (int k0 = 0; k0 < Kd; k0 += 32) {
    const uint4* ap = (const uint4*)(A + (size_t)(bm + srow) * Kd + k0 + skof);
    uint4 a0 = ap[0], a1 = ap[1];
    ushort_t bb[16];
    *(uint4*)&bb[0] = *(const uint4*)(B + (size_t)(k0 + krow) * N + bn + nof);
    *(uint4*)&bb[8] = *(const uint4*)(B + (size_t)(k0 + krow) * N + bn + nof + 8);
    __syncthreads();
    *(uint4*)&As[srow * LROW + skof] = a0;
    *(uint4*)&As[srow * LROW + skof + 8] = a1;
    #pragma unroll
    for (int j = 0; j < 16; ++j)
      Bs[(nof + j) * LROW + krow] = bb[j];
    __syncthreads();
    bf16x8 af[4], bf[4];
    #pragma unroll
    for (int mt = 0; mt < 4; ++mt)
      af[mt] = *(const bf16x8*)&As[(wm + mt * 16 + mrow) * LROW + kq * 8];
    #pragma unroll
    for (int nt = 0; nt < 4; ++nt)
      bf[nt] = *(const bf16x8*)&Bs[(wn + nt * 16 + mrow) * LROW + kq * 8];
    #pragma unroll
    for (int mt = 0; mt < 4; ++mt)
      #pragma unroll
      for (int nt = 0; nt < 4; ++nt)
        acc[mt][nt] = __builtin_amdgcn_mfma_f32_16x16x32_bf16(af[mt], bf[nt], acc[mt][nt], 0, 0, 0);
  }
  #pragma unroll
  for (int mt = 0; mt < 4; ++mt)
    #pragma unroll
    for (int nt = 0; nt < 4; ++nt) {
      int n_g = bn + wn + nt * 16 + (lane & 15);
      #pragma unroll
      for (int r = 0; r < 4; ++r) {
        int m_g = bm + wm + mt * 16 + kq * 4 + r;
        float v = acc[mt][nt][r] + bfu2f(R[(size_t)m_g * N + n_g]);
        C16[(size_t)m_g * N + n_g] = f2bfu(v);
      }
    }
}

// ---- 64x64 bf16 NN GEMM + bf16 residual -> bf16 out -----------------------
__launch_bounds__(256)
__global__ void gemm_bf16_nn_res64(const ushort_t* __restrict__ A, const ushort_t* __restrict__ B,
                                   const ushort_t* __restrict__ R, ushort_t* __restrict__ C16,
                                   int M, int N, int Kd) {
  __shared__ ushort_t As[64 * LROW];
  __shared__ ushort_t Bs[64 * LROW];
  int tid = threadIdx.x;
  int bm = blockIdx.y * 64, bn = blockIdx.x * 64;
  int wave = tid >> 6, lane = tid & 63;
  int wm = (wave >> 1) * 32, wn = (wave & 1) * 32;
  int mrow = lane & 15, kq = lane >> 4;
  int srow = tid >> 2, skof = (tid & 3) * 8;
  int krow = tid >> 3, nof = (tid & 7) * 8;

  f32x4 acc[2][2];
  #pragma unroll
  for (int i = 0; i < 2; ++i)
    #pragma unroll
    for (int j = 0; j < 2; ++j)
      #pragma unroll
      for (int r = 0; r < 4; ++r) acc[i][j][r] = 0.f;

  for (int k0 = 0; k0 < Kd; k0 += 32) {
    uint4 a0 = *(const uint4*)(A + (size_t)(bm + srow) * Kd + k0 + skof);
    ushort_t bb[8];
    *(uint4*)&bb[0] = *(const uint4*)(B + (size_t)(k0 + krow) * N + bn + nof);
    __syncthreads();
    *(uint4*)&As[srow * LROW + skof] = a0;
    #pragma unroll
    for (int j = 0; j < 8; ++j)
      Bs[(nof + j) * LROW + krow] = bb[j];
    __syncthreads();
    bf16x8 af[2], bf[2];
    #pragma unroll
    for (int mt = 0; mt < 2; ++mt)
      af[mt] = *(const bf16x8*)&As[(wm + mt * 16 + mrow) * LROW + kq * 8];
    #pragma unroll
    for (int nt = 0; nt < 2; ++nt)
      bf[nt] = *(const bf16x8*)&Bs[(wn + nt * 16 + mrow) * LROW + kq * 8];
    #pragma unroll
    for (int mt = 0; mt < 2; ++mt)
      #pragma unroll
      for (int nt = 0; nt < 2; ++nt)
        acc[mt][nt] = __builtin_amdgcn_mfma_f32_16x16x32_bf16(af[mt], bf[nt], acc[mt][nt], 0, 0, 0);
  }
  #pragma unroll
  for (int mt = 0; mt < 2; ++mt)
    #pragma unroll
    for (int nt = 0; nt < 2; ++nt) {
      int n_g = bn + wn + nt * 16 + (lane & 15);
      #pragma unroll
      for (int r = 0; r < 4; ++r) {
        int m_g = bm + wm + mt * 16 + kq * 4 + r;
        float v = acc[mt][nt][r] + bfu2f(R[(size_t)m_g * N + n_g]);
        C16[(size_t)m_g * N + n_g] = f2bfu(v);
      }
    }
}

// ---- split-K TN GEMM on bf16 inputs (Mm = X1^T @ X2) ----------------------
__global__ void gemm_tn_part(const ushort_t* __restrict__ A, const ushort_t* __restrict__ B,
                             float* __restrict__ part) {
  int tx = threadIdx.x & 15, ty = threadIdx.x >> 4;
  int i = blockIdx.y * 16 + ty, j = blockIdx.x * 16 + tx;
  int ks = blockIdx.z;
  float acc = 0.f;
  for (int k = ks * 128; k < ks * 128 + 128; ++k)
    acc += bfu2f(A[(size_t)k * 128 + i]) * bfu2f(B[(size_t)k * 128 + j]);
  part[(size_t)ks * 16384 + i * 128 + j] = acc;
}
__global__ void gemm_tn_reduce(const float* __restrict__ part, ushort_t* __restrict__ Mm) {
  int idx = blockIdx.x * 256 + threadIdx.x;
  float s = 0.f;
  #pragma unroll
  for (int ks = 0; ks < 16; ++ks) s += part[(size_t)ks * 16384 + idx];
  Mm[idx] = f2bfu(s);
}

// ============================================================================
// 3-stage column softmax (axis 0) on bf16 matrix, M=2048 rows, N=2048 cols.
// ============================================================================
__global__ void smax_partA(const ushort_t* __restrict__ S, float* __restrict__ pm,
                           float* __restrict__ pl, int N) {
  int t = threadIdx.x;
  int col = blockIdx.x * 64 + (t & 63);
  int g = t >> 6;
  int r0 = blockIdx.y * 128 + g;
  float vals[32];
  #pragma unroll
  for (int i = 0; i < 32; ++i)
    vals[i] = bfu2f(S[(size_t)(r0 + 4 * i) * N + col]);
  float m = -1e30f;
  #pragma unroll
  for (int i = 0; i < 32; ++i) m = fmaxf(m, vals[i]);
  float l = 0.f;
  #pragma unroll
  for (int i = 0; i < 32; ++i) l += expf(vals[i] - m);
  __shared__ float rm[4][64], rl[4][64];
  rm[g][t & 63] = m; rl[g][t & 63] = l;
  __syncthreads();
  if (g == 0) {
    int c = t & 63;
    float M0 = rm[0][c], L0 = rl[0][c];
    #pragma unroll
    for (int j = 1; j < 4; ++j) {
      float Mj = rm[j][c], Lj = rl[j][c];
      float nm = fmaxf(M0, Mj);
      L0 = L0 * expf(M0 - nm) + Lj * expf(Mj - nm);
      M0 = nm;
    }
    pm[(size_t)blockIdx.y * N + col] = M0;
    pl[(size_t)blockIdx.y * N + col] = L0;
  }
}
__global__ void smax_partB(const float* __restrict__ pm, const float* __restrict__ pl,
                           float* __restrict__ gm, float* __restrict__ gi, int N) {
  int col = blockIdx.x * 256 + threadIdx.x;
  float m = -1e30f, l = 0.f;
  for (int b = 0; b < 16; ++b) {
    float bm = pm[(size_t)b * N + col], bl = pl[(size_t)b * N + col];
    float nm = fmaxf(m, bm);
    l = l * expf(m - nm) + bl * expf(bm - nm);
    m = nm;
  }
  gm[col] = m;
  gi[col] = 1.f / l;
}
__global__ void smax_partC(ushort_t* __restrict__ S, const float* __restrict__ gm,
                           const float* __restrict__ gi, int N) {
  int t = threadIdx.x;
  int col = blockIdx.x * 64 + (t & 63);
  int g = t >> 6;
  float m = gm[col], inv = gi[col];
  int r0 = blockIdx.y * 128 + g;
  #pragma unroll 8
  for (int i = 0; i < 32; ++i) {
    size_t idx = (size_t)(r0 + 4 * i) * N + col;
    S[idx] = f2bfu(expf(bfu2f(S[idx]) - m) * inv);
  }
}

// ---- row squared-norms from bf16 ------------------------------------------
__global__ void row_norm_bf16(const ushort_t* __restrict__ X, float* __restrict__ out, int Kd) {
  int r = blockIdx.x;
  int t = threadIdx.x;
  float s = 0.f;
  for (int k = t; k < Kd; k += 64) { float v = bfu2f(X[(size_t)r * Kd + k]); s += v * v; }
  for (int off = 32; off; off >>= 1) s += __shfl_down(s, off);
  if (t == 0) out[r] = s;
}

// ---- mask scores (A3 fp32) ------------------------------------------------
__global__ void mask_score(const float* __restrict__ A3, const float* __restrict__ w4,
                           const float* __restrict__ b4, float* __restrict__ s) {
  int k = blockIdx.x * 256 + threadIdx.x;
  float acc = b4[0];
  for (int h = 0; h < 128; ++h) acc += A3[(size_t)h * 2048 + k] * w4[h];
  s[k] = acc;
}

// ---- stable descending-argsort rank via LDS-staged scores -----------------
__global__ void topk_rank(const float* __restrict__ s, int* __restrict__ idx, int K, int S) {
  __shared__ float sv[2048];
  int t = threadIdx.x;
  for (int i = t; i < K; i += 256) sv[i] = s[i];
  __syncthreads();
  int j = blockIdx.x * 256 + t;
  if (j >= K) return;
  float sj = sv[j];
  int rank = 0;
  #pragma unroll 8
  for (int i = 0; i < 2048; ++i) {
    float si = sv[i];
    rank += (si > sj) || (si == sj && i < j);
  }
  if (rank < S) idx[rank] = j;
}

// ---- build cat = [B_dt | softmax(aff_s[:,idx],axis=1) | 0pad], bf16 -------
__global__ void build_cat(const ushort_t* __restrict__ Bdt, const ushort_t* __restrict__ affs,
                          const int* __restrict__ idx, ushort_t* __restrict__ cat) {
  int r = blockIdx.x, t = threadIdx.x;
  __shared__ float vals[256];
  __shared__ float red[256];
  float v = -1e30f;
  if (t < 204) {
    int ix = idx[t];
    ix = ix < 0 ? 0 : (ix > 2047 ? 2047 : ix);
    v = bfu2f(affs[(size_t)r * 2048 + ix]);
  }
  vals[t] = v;
  red[t] = v;
  __syncthreads();
  for (int off = 128; off; off >>= 1) { if (t < off) red[t] = fmaxf(red[t], red[t + off]); __syncthreads(); }
  float m = red[0];
  __syncthreads();
  float e = (t < 204) ? expf(vals[t] - m) : 0.f;
  red[t] = e;
  __syncthreads();
  for (int off = 128; off; off >>= 1) { if (t < off) red[t] += red[t + off]; __syncthreads(); }
  float inv = 1.f / red[0];
  cat[(size_t)r * 512 + t] = Bdt[(size_t)r * 256 + t];
  cat[(size_t)r * 512 + 256 + t] = (t < 204) ? f2bfu(e * inv) : (ushort_t)0;
}

// ---- a = leaky((AV*AU) @ aww.T + awb), wave-per-row coalesced -------------
__global__ void attn_gate(const float* __restrict__ AV, const float* __restrict__ AU,
                          const float* __restrict__ aww, const float* __restrict__ awb,
                          float* __restrict__ a, int n) {
  int wave = threadIdx.x >> 6, lane = threadIdx.x & 63;
  int r = blockIdx.x * 4 + wave;
  if (r >= n) return;
  float s = 0.f;
  #pragma unroll
  for (int j = 0; j < 2; ++j) {
    int d = lane + 64 * j;
    s += AV[(size_t)r * 128 + d] * AU[(size_t)r * 128 + d] * aww[d];
  }
  for (int off = 32; off; off >>= 1) s += __shfl_down(s, off);
  if (lane == 0) {
    float acc = s + awb[0];
    a[r] = LEAKY(acc);
  }
}

// ---- 1-D softmax (single block) -------------------------------------------
__global__ void softmax_vec(const float* __restrict__ x, float* __restrict__ y,
                            float* __restrict__ y2, int n) {
  __shared__ float red[256];
  int t = threadIdx.x;
  float m = -1e30f;
  for (int i = t; i < n; i += 256) m = fmaxf(m, x[i]);
  red[t] = m;
  __syncthreads();
  for (int off = 128; off; off >>= 1) { if (t < off) red[t] = fmaxf(red[t], red[t + off]); __syncthreads(); }
  m = red[0];
  __syncthreads();
  float s = 0.f;
  for (int i = t; i < n; i += 256) s += expf(x[i] - m);
  red[t] = s;
  __syncthreads();
  for (int off = 128; off; off >>= 1) { if (t < off) red[t] += red[t + off]; __syncthreads(); }
  float inv = 1.f / red[0];
  for (int i = t; i < n; i += 256) {
    float v = expf(x[i] - m) * inv;
    y[i] = v;
    if (y2) y2[i] = v;
  }
}

// ---- weighted column sum over bf16 H, two-stage ---------------------------
__global__ void colsum_part(const float* __restrict__ wv, const ushort_t* __restrict__ H,
                            float* __restrict__ part, int n) {
  int bk = blockIdx.x, c = threadIdx.x;
  float s = 0.f;
  for (int r = bk; r < n; r += 16) s += wv[r] * bfu2f(H[(size_t)r * 256 + c]);
  part[bk * 256 + c] = s;
}
__global__ void colsum_fin(const float* __restrict__ part, float* __restrict__ out) {
  int c = threadIdx.x;
  float s = 0.f;
  #pragma unroll
  for (int k = 0; k < 16; ++k) s += part[k * 256 + c];
  out[c] = s;
}

// ---- small gemv -----------------------------------------------------------
__global__ void gemv_act(const float* __restrict__ x, const float* __restrict__ W,
                         const float* __restrict__ b, float* __restrict__ out,
                         int O, int Kd, int act) {
  int o = blockIdx.x * blockDim.x + threadIdx.x;
  if (o >= O) return;
  float acc = b ? b[o] : 0.f;
  for (int k = 0; k < Kd; ++k) acc += x[k] * W[(size_t)o * Kd + k];
  if (act == 1) acc = LEAKY(acc);
  out[o] = acc;
}

// ---- cat2 = [B_fuse | tile(M1)], bf16 -------------------------------------
__global__ void build_cat2(const ushort_t* __restrict__ Bf, const float* __restrict__ M1,
                           ushort_t* __restrict__ cat2) {
  int r = blockIdx.x, t = threadIdx.x;  // 512 threads
  cat2[(size_t)r * 512 + t] = (t < 256) ? Bf[(size_t)r * 256 + t] : f2bfu(M1[t - 256]);
}

// ---- final head -----------------------------------------------------------
__global__ void final_head(const float* __restrict__ AH2, const float* __restrict__ embw,
                           const float* __restrict__ embb, const float* __restrict__ sembw,
                           const float* __restrict__ sembb, const float* __restrict__ clsw,
                           const float* __restrict__ clsb, float* __restrict__ Yout) {
  __shared__ float bvec[512];
  __shared__ float red[512];
  int t = threadIdx.x;
  float acc = embb[t];
  for (int c = 0; c < 256; ++c) acc += AH2[c] * embw[(size_t)t * 256 + c];
  bvec[t] = LEAKY(acc);
  __syncthreads();
  float p = 0.f;
  if (t < 256) {
    float a2 = sembb[t];
    for (int c = 0; c < 512; ++c) a2 += bvec[c] * sembw[(size_t)t * 512 + c];
    a2 = LEAKY(a2);
    p = a2 * clsw[t];
  }
  red[t] = p;
  __syncthreads();
  for (int off = 256; off; off >>= 1) { if (t < off) red[t] += red[t + off]; __syncthreads(); }
  if (t == 0) {
    float y = red[0] + clsb[0];
    y = 1.f / (1.f + expf(-y));
    y = fminf(fmaxf(y, 1e-5f), 1.f - 1e-5f);
    Yout[0] = y;
  }
}

extern "C" void kernel_launch(void* const* d_in, const int* in_sizes, int n_in,
                              void* d_out, int out_size, void* d_ws, size_t ws_size,
                              hipStream_t stream) {
  auto IN = [&](int i) { return (const float*)d_in[i]; };
  (void)n_in; (void)in_sizes; (void)out_size;

  const int S = 204;
  float* out_f = (float*)d_out;  // out[0]=Y, out[1..2048]=A

  float* W = (float*)d_ws;
  size_t off = 0;
  auto F = [&](size_t n) { float* p = W + off; off += n; return p; };
  auto FU = [&](size_t nus) { return (ushort_t*)F((nus + 1) / 2); };

  ushort_t* dt_b  = FU((size_t)4096 * 256);
  ushort_t* Xs_b  = FU((size_t)2048 * 256);
  ushort_t* Ks_b  = FU((size_t)2048 * 256);
  ushort_t* X1b   = FU((size_t)2048 * 128);
  ushort_t* X2b   = FU((size_t)2048 * 128);
  ushort_t* aff_b = FU((size_t)2048 * 2048);  // euclid out; skip3 in-place -> aff_s
  float* AV    = F((size_t)2048 * 128);
  float* AU    = F((size_t)2048 * 128);
  ushort_t* Mm_b = FU((size_t)128 * 128);
  float* svec  = F(2048);
  int*   idxb  = (int*)F(256);
  float* avec  = F(2048);
  float* Awv   = F(2048);
  float* AH    = F(256);
  float* M1v   = F(256);
  float* AH2   = F(256);
  float* nx    = F(2048);
  float* ny    = F(2048);
  float* part  = F(4096);
  float* sm_pm = F((size_t)16 * 2048);
  float* sm_pl = F((size_t)16 * 2048);
  float* sm_gm = F(2048);
  float* sm_gi = F(2048);

  // bf16 weight arena
  size_t wo = 0;
  ushort_t* warena = (ushort_t*)F(3227872);
  auto WA = [&](size_t n) { ushort_t* p = warena + wo; wo = (wo + n + 15) & ~(size_t)15; return p; };
  ushort_t* w2b   = WA(25000);
  ushort_t* embb_ = WA(204800);
  ushort_t* s1w1 = WA(32768); ushort_t* s1w2 = WA(32768); ushort_t* s1w3 = WA(65536);
  ushort_t* s2w1 = WA(32768); ushort_t* s2w2 = WA(32768); ushort_t* s2w3 = WA(65536);
  ushort_t* s3w1 = WA(262144); ushort_t* s3w2 = WA(262144); ushort_t* s3w3 = WA(4194304);
  ushort_t* mw1 = WA(262144); ushort_t* mw2 = WA(262144); ushort_t* mw3 = WA(262144);
  ushort_t* fwp = WA(131072);
  ushort_t* a1fe = WA(65536); ushort_t* a1v = WA(32768); ushort_t* a1u = WA(32768);
  ushort_t* a2fe = WA(131072); ushort_t* a2v = WA(32768); ushort_t* a2u = WA(32768);

  float* pool = F((size_t)4194304);

  const size_t NEED_BYTES = off * 4;
  if (ws_size < NEED_BYTES) {
    fill_out<<<9, 256, 0, stream>>>(out_f, 2049);
    return;
  }

  // pool members (phase-disjoint)
  ushort_t* h2h_b  = (ushort_t*)pool;                 // conv: 2048*800 us
  ushort_t* Smat_b = (ushort_t*)pool;                 // skip: 2048*2048 us
  ushort_t* X3s_b  = (ushort_t*)(pool + 2097152);     // skip1/2: 2048*256 us
  ushort_t* X3b_b  = (ushort_t*)(pool + 2097152);     // skip3: 2048*2048 us
  float* A3   = pool;                                 // mask: 128*2048 fp32
  float* tnpt = pool + 262144;                        // mask: 16*16384 fp32
  ushort_t* cat_b   = (ushort_t*)pool;                // fuse: 2048*512 us
  ushort_t* cat2_b  = (ushort_t*)(pool + 524288);     // 2048*512 us
  ushort_t* Bfuse_b = (ushort_t*)(pool + 1048576);    // 2048*256 us
  ushort_t* Hbuf_b  = (ushort_t*)(pool + 1310720);    // 2048*256 us

  // ---- weight conversion (once per launch) ----
  CvtArgs ca;
  const float* srcs[20] = { IN(4), IN(6), IN(8), IN(10), IN(12), IN(14), IN(16), IN(18),
                            IN(20), IN(22), IN(24), IN(26), IN(28), IN(30),
                            IN(36), IN(38), IN(40), IN(46), IN(48), IN(50) };
  ushort_t* dsts[20] = { w2b, embb_, s1w1, s1w2, s1w3, s2w1, s2w2, s2w3,
                         s3w1, s3w2, s3w3, mw1, mw2, mw3,
                         a1fe, a1v, a1u, a2fe, a2v, a2u };
  int lens[20] = { 25000, 204800, 32768, 32768, 65536, 32768, 32768, 65536,
                   262144, 262144, 4194304, 262144, 262144, 262144,
                   65536, 32768, 32768, 131072, 32768, 32768 };
  for (int i = 0; i < 20; ++i) { ca.src[i] = srcs[i]; ca.dst[i] = dsts[i]; ca.len[i] = lens[i]; }
  to_bf16_multi<<<1024, 256, 0, stream>>>(ca);
  pad_fuse_bf16<<<512, 256, 0, stream>>>(IN(34), fwp);

  auto softmax_col = [&](ushort_t* Smat) {
    smax_partA<<<dim3(32, 16), 256, 0, stream>>>(Smat, sm_pm, sm_pl, 2048);
    smax_partB<<<8, 256, 0, stream>>>(sm_pm, sm_pl, sm_gm, sm_gi, 2048);
    smax_partC<<<dim3(32, 16), 256, 0, stream>>>(Smat, sm_gm, sm_gi, 2048);
  };

  // ---- data_transform for B (g=0) and KB (g=1) ----
  for (int g = 0; g < 2; ++g) {
    conv12_mfma<<<1024, 256, 0, stream>>>(IN(g), IN(2), IN(3), w2b, IN(5), h2h_b);
    gemm_bf16_nt64<EPI_LEAKY><<<dim3(4, 32), 256, 0, stream>>>(
        h2h_b, embb_, IN(7), nullptr, dt_b + (size_t)g * 2048 * 256, 2048, 256, 800);
  }
  ushort_t* B_dtb = dt_b;
  ushort_t* KB_dtb = dt_b + (size_t)2048 * 256;

  // ---- skip_block 1 (B_dt -> Xs) and 2 (KB_dt -> Ks) ----
  for (int g = 0; g < 2; ++g) {
    ushort_t* Xin = g ? KB_dtb : B_dtb;
    ushort_t* Xout = g ? Ks_b : Xs_b;
    ushort_t* w1 = g ? s2w1 : s1w1;
    ushort_t* w2 = g ? s2w2 : s1w2;
    ushort_t* w3 = g ? s2w3 : s1w3;
    int wi = g ? 14 : 8;
    gemm_bf16_nt64<EPI_LEAKY_BN><<<dim3(2, 32), 256, 0, stream>>>(
        Xin, w1, IN(wi + 1), nullptr, X1b, 2048, 128, 256);
    gemm_bf16_nt64<EPI_LEAKY_BN><<<dim3(2, 32), 256, 0, stream>>>(
        Xin, w2, IN(wi + 3), nullptr, X2b, 2048, 128, 256);
    gemm_bf16_nt64<EPI_LEAKY_BN><<<dim3(4, 32), 256, 0, stream>>>(
        Xin, w3, IN(wi + 5), nullptr, X3s_b, 2048, 256, 256);
    gemm_bf16_nt<EPI_NONE><<<dim3(16, 16), 256, 0, stream>>>(
        X1b, X2b, nullptr, nullptr, Smat_b, 2048, 2048, 128, nullptr, nullptr);
    softmax_col(Smat_b);
    gemm_bf16_nn_res64<<<dim3(4, 32), 256, 0, stream>>>(Smat_b, X3s_b, Xin, Xout, 2048, 256, 2048);
  }

  // ---- euclid -> aff_b ----
  row_norm_bf16<<<2048, 64, 0, stream>>>(Xs_b, nx, 256);
  row_norm_bf16<<<2048, 64, 0, stream>>>(Ks_b, ny, 256);
  gemm_bf16_nt<EPI_EUCLID><<<dim3(16, 16), 256, 0, stream>>>(
      Xs_b, Ks_b, nullptr, nullptr, aff_b, 2048, 2048, 256, nx, ny);

  // ---- skip_block 3 (aff_b -> aff_b in-place) ----
  gemm_bf16_nt64<EPI_LEAKY_BN><<<dim3(2, 32), 256, 0, stream>>>(
      aff_b, s3w1, IN(21), nullptr, X1b, 2048, 128, 2048);
  gemm_bf16_nt64<EPI_LEAKY_BN><<<dim3(2, 32), 256, 0, stream>>>(
      aff_b, s3w2, IN(23), nullptr, X2b, 2048, 128, 2048);
  gemm_bf16_nt<EPI_LEAKY_BN><<<dim3(16, 16), 256, 0, stream>>>(
      aff_b, s3w3, IN(25), nullptr, X3b_b, 2048, 2048, 2048, nullptr, nullptr);
  gemm_bf16_nt<EPI_NONE><<<dim3(16, 16), 256, 0, stream>>>(
      X1b, X2b, nullptr, nullptr, Smat_b, 2048, 2048, 128, nullptr, nullptr);
  softmax_col(Smat_b);
  gemm_bf16_nn_res<<<dim3(16, 16), 256, 0, stream>>>(Smat_b, X3b_b, aff_b, aff_b, 2048, 2048, 2048);
  ushort_t* affs_b = aff_b;

  // ---- mask_scores -> top-S idx ----
  gemm_bf16_nt64<EPI_LEAKY><<<dim3(2, 32), 256, 0, stream>>>(
      affs_b, mw1, IN(27), nullptr, X1b, 2048, 128, 2048);
  gemm_bf16_nt64<EPI_TANH><<<dim3(2, 32), 256, 0, stream>>>(
      affs_b, mw2, IN(29), nullptr, X2b, 2048, 128, 2048);
  gemm_tn_part<<<dim3(8, 8, 16), 256, 0, stream>>>(X1b, X2b, tnpt);
  gemm_tn_reduce<<<64, 256, 0, stream>>>(tnpt, Mm_b);
  gemm_bf16_nt64<EPI_LEAKY><<<dim3(32, 2), 256, 0, stream>>>(
      Mm_b, mw3, IN(31), A3, nullptr, 128, 2048, 128);
  mask_score<<<8, 256, 0, stream>>>(A3, IN(32), IN(33), svec);
  topk_rank<<<8, 256, 0, stream>>>(svec, idxb, 2048, S);

  // ---- B_bag + concat (bf16, pad 512) + fuse ----
  build_cat<<<2048, 256, 0, stream>>>(B_dtb, affs_b, idxb, cat_b);
  gemm_bf16_nt64<EPI_LEAKY><<<dim3(4, 32), 256, 0, stream>>>(
      cat_b, fwp, IN(35), nullptr, Bfuse_b, 2048, 256, 512);

  // ---- attention 1 ----
  gemm_bf16_nt64<EPI_LEAKY><<<dim3(4, 32), 256, 0, stream>>>(
      Bfuse_b, a1fe, IN(37), nullptr, Hbuf_b, 2048, 256, 256);
  gemm_bf16_nt64<EPI_TANH><<<dim3(2, 32), 256, 0, stream>>>(
      Hbuf_b, a1v, IN(39), AV, nullptr, 2048, 128, 256);
  gemm_bf16_nt64<EPI_LEAKY><<<dim3(2, 32), 256, 0, stream>>>(
      Hbuf_b, a1u, IN(41), AU, nullptr, 2048, 128, 256);
  attn_gate<<<512, 256, 0, stream>>>(AV, AU, IN(42), IN(43), avec, 2048);
  softmax_vec<<<1, 256, 0, stream>>>(avec, Awv, nullptr, 2048);
  colsum_part<<<16, 256, 0, stream>>>(Awv, Hbuf_b, part, 2048);
  colsum_fin<<<1, 256, 0, stream>>>(part, AH);
  gemv_act<<<1, 256, 0, stream>>>(AH, IN(44), IN(45), M1v, 256, 256, 1);
  build_cat2<<<2048, 512, 0, stream>>>(Bfuse_b, M1v, cat2_b);

  // ---- attention 2 (A -> output) ----
  gemm_bf16_nt64<EPI_LEAKY><<<dim3(4, 32), 256, 0, stream>>>(
      cat2_b, a2fe, IN(47), nullptr, Hbuf_b, 2048, 256, 512);
  gemm_bf16_nt64<EPI_TANH><<<dim3(2, 32), 256, 0, stream>>>(
      Hbuf_b, a2v, IN(49), AV, nullptr, 2048, 128, 256);
  gemm_bf16_nt64<EPI_LEAKY><<<dim3(2, 32), 256, 0, stream>>>(
      Hbuf_b, a2u, IN(51), AU, nullptr, 2048, 128, 256);
  attn_gate<<<512, 256, 0, stream>>>(AV, AU, IN(52), IN(53), avec, 2048);
  softmax_vec<<<1, 256, 0, stream>>>(avec, Awv, out_f + 1, 2048);
  colsum_part<<<16, 256, 0, stream>>>(Awv, Hbuf_b, part, 2048);
  colsum_fin<<<1, 256, 0, stream>>>(part, AH2);

  // ---- final head -> Y ----
  final_head<<<1, 512, 0, stream>>>(AH2, IN(54), IN(55), IN(56), IN(57),
                                    IN(58), IN(59), out_f);
}

// Round 10
// 957.799 us; speedup vs baseline: 10.5524x; 1.2492x over previous
//
#include <hip/hip_runtime.h>
#include <math.h>

#define LEAKY(x) ((x) > 0.f ? (x) : 0.01f * (x))
static constexpr float BN_SCALE = 0.9999950000374997f;

typedef unsigned short ushort_t;
typedef float f32x4 __attribute__((ext_vector_type(4)));
typedef short bf16x8 __attribute__((ext_vector_type(8)));

__device__ __forceinline__ ushort_t f2bfu(float f) {
  union { float f; unsigned u; } v; v.f = f;
  unsigned r = v.u + 0x7fffu + ((v.u >> 16) & 1u);
  return (ushort_t)(r >> 16);
}
__device__ __forceinline__ float bfu2f(ushort_t u) {
  union { unsigned u; float f; } v; v.u = ((unsigned)u) << 16;
  return v.f;
}

__global__ void fill_out(float* out, int n) {
  int i = blockIdx.x * 256 + threadIdx.x;
  if (i < n) out[i] = 0.25f;
}

// ---- one-shot fp32 -> bf16 conversion of up to 20 tensors -----------------
struct CvtArgs {
  const float* src[20];
  ushort_t* dst[20];
  int len[20];
};
__global__ void to_bf16_multi(CvtArgs a) {
  for (int s = 0; s < 20; ++s) {
    const float* sp = a.src[s];
    ushort_t* dp = a.dst[s];
    int n = a.len[s];
    for (int i = blockIdx.x * 256 + threadIdx.x; i < n; i += gridDim.x * 256)
      dp[i] = f2bfu(sp[i]);
  }
}

// ---- pack 6 bias pairs [128|128] -> fp32 [6][256] -------------------------
struct BiasPk { const float* a[12]; float* out; };
__global__ void bias_pack(BiasPk p) {
  int b = blockIdx.x, t = threadIdx.x;
  p.out[b * 256 + t] = (t < 128) ? p.a[2 * b][t] : p.a[2 * b + 1][t - 128];
}

// ---- pad fuse_w [256,460] fp32 -> [256,512] bf16 --------------------------
__global__ void pad_fuse_bf16(const float* __restrict__ w, ushort_t* __restrict__ wp) {
  int idx = blockIdx.x * 256 + threadIdx.x;
  if (idx >= 256 * 512) return;
  int o = idx >> 9, k = idx & 511;
  wp[idx] = (k < 460) ? f2bfu(w[(size_t)o * 460 + k]) : (ushort_t)0;
}

// ============================================================================
// Fused conv1+pool+conv2+pool via MFMA implicit GEMM. 2 images/block.
// Covers both B (blocks 0..1023) and KB (1024..2047) in one dispatch.
// ============================================================================
__launch_bounds__(256)
__global__ void conv12_mfma(const float* __restrict__ imgB, const float* __restrict__ imgK,
                            const float* __restrict__ w1, const float* __restrict__ b1,
                            const ushort_t* __restrict__ w2b, const float* __restrict__ b2,
                            ushort_t* __restrict__ out800) {
  __shared__ __align__(16) char smem[39168];
  ushort_t* sh1u = (ushort_t*)smem;
  float* simg = (float*)(smem + 11520);
  float* sw1  = (float*)(smem + 11520 + 6272);
  ushort_t* As = (ushort_t*)(smem + 11520);
  ushort_t* Bs = (ushort_t*)(smem + 29952);
  float* Cf = (float*)smem;

  int tid = threadIdx.x;
  int bx = blockIdx.x;
  const float* imgb = (bx < 1024) ? imgB + (size_t)bx * 2 * 784
                                  : imgK + (size_t)(bx - 1024) * 2 * 784;

  for (int i = tid; i < 1568; i += 256) simg[i] = imgb[i];
  for (int i = tid; i < 500; i += 256) sw1[i] = w1[i];
  __syncthreads();
  for (int o = tid; o < 5760; o += 256) {
    int im = o / 2880, oi = o % 2880;
    int c = oi / 144, rem = oi % 144, py = rem / 12, px = rem % 12;
    int y0 = py * 2, x0 = px * 2;
    const float* sb = &simg[im * 784];
    float p[6][6];
    #pragma unroll
    for (int yy = 0; yy < 6; ++yy)
      #pragma unroll
      for (int xx = 0; xx < 6; ++xx)
        p[yy][xx] = sb[(y0 + yy) * 28 + x0 + xx];
    float bb = b1[c];
    float t0 = bb, t1 = bb, t2 = bb, t3 = bb;
    const float* wc = &sw1[c * 25];
    #pragma unroll
    for (int ky = 0; ky < 5; ++ky)
      #pragma unroll
      for (int kx = 0; kx < 5; ++kx) {
        float wv = wc[ky * 5 + kx];
        t0 += p[ky][kx] * wv;
        t1 += p[ky][kx + 1] * wv;
        t2 += p[ky + 1][kx] * wv;
        t3 += p[ky + 1][kx + 1] * wv;
      }
    t0 = LEAKY(t0); t1 = LEAKY(t1); t2 = LEAKY(t2); t3 = LEAKY(t3);
    sh1u[o] = f2bfu(fmaxf(fmaxf(t0, t1), fmaxf(t2, t3)));
  }

  int wave = tid >> 6, lane = tid & 63;
  int wm = (wave >> 1) * 64, wn = (wave & 1) * 32;
  int mrow = lane & 15, kq = lane >> 4;
  int kl = tid & 63, rbase = tid >> 6;

  f32x4 acc[4][2];
  #pragma unroll
  for (int i = 0; i < 4; ++i)
    #pragma unroll
    for (int j = 0; j < 2; ++j)
      #pragma unroll
      for (int r = 0; r < 4; ++r) acc[i][j][r] = 0.f;

  for (int k0 = 0; k0 < 512; k0 += 64) {
    __syncthreads();
    int k = k0 + kl;
    bool valid = k < 500;
    int ic = k / 25, tap = k - ic * 25;
    int ky = tap / 5, kx = tap - ky * 5;
    int kof = ic * 144 + ky * 12 + kx;
    ushort_t tA[32];
    #pragma unroll
    for (int i = 0; i < 32; ++i) {
      int r = rbase + 4 * i;
      int im = r >> 6, pos = r & 63, oy = pos >> 3, ox = pos & 7;
      tA[i] = valid ? sh1u[im * 2880 + kof + oy * 12 + ox] : (ushort_t)0;
    }
    ushort_t tB[16];
    #pragma unroll
    for (int i = 0; i < 16; ++i) {
      int oc = rbase + 4 * i;
      tB[i] = (valid && oc < 50) ? w2b[(size_t)oc * 500 + k] : (ushort_t)0;
    }
    #pragma unroll
    for (int i = 0; i < 32; ++i) As[(rbase + 4 * i) * 72 + kl] = tA[i];
    #pragma unroll
    for (int i = 0; i < 16; ++i) Bs[(rbase + 4 * i) * 72 + kl] = tB[i];
    __syncthreads();
    #pragma unroll
    for (int ks = 0; ks < 2; ++ks) {
      bf16x8 af[4], bf[2];
      #pragma unroll
      for (int mt = 0; mt < 4; ++mt)
        af[mt] = *(const bf16x8*)&As[(wm + mt * 16 + mrow) * 72 + ks * 32 + kq * 8];
      #pragma unroll
      for (int nt = 0; nt < 2; ++nt)
        bf[nt] = *(const bf16x8*)&Bs[(wn + nt * 16 + mrow) * 72 + ks * 32 + kq * 8];
      #pragma unroll
      for (int mt = 0; mt < 4; ++mt)
        #pragma unroll
        for (int nt = 0; nt < 2; ++nt)
          acc[mt][nt] = __builtin_amdgcn_mfma_f32_16x16x32_bf16(af[mt], bf[nt], acc[mt][nt], 0, 0, 0);
    }
  }
  __syncthreads();
  #pragma unroll
  for (int mt = 0; mt < 4; ++mt)
    #pragma unroll
    for (int nt = 0; nt < 2; ++nt) {
      int n0 = wn + nt * 16 + (lane & 15);
      #pragma unroll
      for (int r = 0; r < 4; ++r)
        Cf[(wm + mt * 16 + kq * 4 + r) * 68 + n0] = acc[mt][nt][r];
    }
  __syncthreads();
  for (int o = tid; o < 1600; o += 256) {
    int im = o / 800, oi = o - im * 800;
    int oc = oi >> 4, p = oi & 15, py = p >> 2, px = p & 3;
    int r0 = im * 64 + py * 16 + px * 2;
    float bb = b2[oc];
    float t0 = LEAKY(Cf[r0 * 68 + oc] + bb);
    float t1 = LEAKY(Cf[(r0 + 1) * 68 + oc] + bb);
    float t2 = LEAKY(Cf[(r0 + 8) * 68 + oc] + bb);
    float t3 = LEAKY(Cf[(r0 + 9) * 68 + oc] + bb);
    out800[(size_t)(bx * 2 + im) * 800 + oi] = f2bfu(fmaxf(fmaxf(t0, t1), fmaxf(t2, t3)));
  }
}

enum { EPI_NONE = 0, EPI_LEAKY = 1, EPI_LEAKY_BN = 2, EPI_TANH = 3, EPI_EUCLID = 4 };

#define LROW 40

// ---- 128x128 bf16 NT GEMM (euclid / skip3 X3b) ----------------------------
template <int EPI>
__launch_bounds__(256)
__global__ void gemm_bf16_nt(const ushort_t* __restrict__ A, const ushort_t* __restrict__ B,
                             const float* __restrict__ bias, float* __restrict__ C32,
                             ushort_t* __restrict__ C16, int M, int N, int Kd,
                             const float* __restrict__ e1, const float* __restrict__ e2) {
  __shared__ ushort_t As[128 * LROW];
  __shared__ ushort_t Bs[128 * LROW];
  int tid = threadIdx.x;
  int bm = blockIdx.y * 128, bn = blockIdx.x * 128;
  int wave = tid >> 6, lane = tid & 63;
  int wm = (wave >> 1) * 64, wn = (wave & 1) * 64;
  int mrow = lane & 15, kq = lane >> 4;
  int srow = tid >> 1, skof = (tid & 1) * 16;

  f32x4 acc[4][4];
  #pragma unroll
  for (int i = 0; i < 4; ++i)
    #pragma unroll
    for (int j = 0; j < 4; ++j)
      #pragma unroll
      for (int r = 0; r < 4; ++r) acc[i][j][r] = 0.f;

  for (int k0 = 0; k0 < Kd; k0 += 32) {
    const uint4* ap = (const uint4*)(A + (size_t)(bm + srow) * Kd + k0 + skof);
    const uint4* bp = (const uint4*)(B + (size_t)(bn + srow) * Kd + k0 + skof);
    uint4 a0 = ap[0], a1 = ap[1];
    uint4 b0 = bp[0], b1 = bp[1];
    __syncthreads();
    *(uint4*)&As[srow * LROW + skof] = a0;
    *(uint4*)&As[srow * LROW + skof + 8] = a1;
    *(uint4*)&Bs[srow * LROW + skof] = b0;
    *(uint4*)&Bs[srow * LROW + skof + 8] = b1;
    __syncthreads();
    bf16x8 af[4], bf[4];
    #pragma unroll
    for (int mt = 0; mt < 4; ++mt)
      af[mt] = *(const bf16x8*)&As[(wm + mt * 16 + mrow) * LROW + kq * 8];
    #pragma unroll
    for (int nt = 0; nt < 4; ++nt)
      bf[nt] = *(const bf16x8*)&Bs[(wn + nt * 16 + mrow) * LROW + kq * 8];
    #pragma unroll
    for (int mt = 0; mt < 4; ++mt)
      #pragma unroll
      for (int nt = 0; nt < 4; ++nt)
        acc[mt][nt] = __builtin_amdgcn_mfma_f32_16x16x32_bf16(af[mt], bf[nt], acc[mt][nt], 0, 0, 0);
  }
  #pragma unroll
  for (int mt = 0; mt < 4; ++mt)
    #pragma unroll
    for (int nt = 0; nt < 4; ++nt) {
      int n_g = bn + wn + nt * 16 + (lane & 15);
      #pragma unroll
      for (int r = 0; r < 4; ++r) {
        int m_g = bm + wm + mt * 16 + kq * 4 + r;
        float v = acc[mt][nt][r];
        if (EPI == EPI_EUCLID) {
          v = e1[m_g] + e2[n_g] - 2.f * v;
          v = sqrtf(fmaxf(v, 0.f));
        } else {
          if (bias) v += bias[n_g];
          if (EPI == EPI_LEAKY) v = LEAKY(v);
          else if (EPI == EPI_LEAKY_BN) { v = LEAKY(v); v *= BN_SCALE; }
          else if (EPI == EPI_TANH) v = tanhf(v);
        }
        if (C32) C32[(size_t)m_g * N + n_g] = v;
        if (C16) C16[(size_t)m_g * N + n_g] = f2bfu(v);
      }
    }
}

// ---- Smat z-GEMM: Smat_z = X12_z[:, :128] @ X12_z[:, 128:]^T --------------
// X12 rows stride 256; M=N=2048, K=128; bf16 out.
__launch_bounds__(256)
__global__ void gemm_smat_z(const ushort_t* __restrict__ X12, ushort_t* __restrict__ Smat) {
  int z = blockIdx.z;
  const ushort_t* A = X12 + (size_t)z * 2048 * 256;
  const ushort_t* B = A + 128;
  ushort_t* C = Smat + (size_t)z * 2048 * 2048;
  __shared__ ushort_t As[128 * LROW];
  __shared__ ushort_t Bs[128 * LROW];
  int tid = threadIdx.x;
  int bm = blockIdx.y * 128, bn = blockIdx.x * 128;
  int wave = tid >> 6, lane = tid & 63;
  int wm = (wave >> 1) * 64, wn = (wave & 1) * 64;
  int mrow = lane & 15, kq = lane >> 4;
  int srow = tid >> 1, skof = (tid & 1) * 16;

  f32x4 acc[4][4];
  #pragma unroll
  for (int i = 0; i < 4; ++i)
    #pragma unroll
    for (int j = 0; j < 4; ++j)
      #pragma unroll
      for (int r = 0; r < 4; ++r) acc[i][j][r] = 0.f;

  for (int k0 = 0; k0 < 128; k0 += 32) {
    const uint4* ap = (const uint4*)(A + (size_t)(bm + srow) * 256 + k0 + skof);
    const uint4* bp = (const uint4*)(B + (size_t)(bn + srow) * 256 + k0 + skof);
    uint4 a0 = ap[0], a1 = ap[1];
    uint4 b0 = bp[0], b1 = bp[1];
    __syncthreads();
    *(uint4*)&As[srow * LROW + skof] = a0;
    *(uint4*)&As[srow * LROW + skof + 8] = a1;
    *(uint4*)&Bs[srow * LROW + skof] = b0;
    *(uint4*)&Bs[srow * LROW + skof + 8] = b1;
    __syncthreads();
    bf16x8 af[4], bf[4];
    #pragma unroll
    for (int mt = 0; mt < 4; ++mt)
      af[mt] = *(const bf16x8*)&As[(wm + mt * 16 + mrow) * LROW + kq * 8];
    #pragma unroll
    for (int nt = 0; nt < 4; ++nt)
      bf[nt] = *(const bf16x8*)&Bs[(wn + nt * 16 + mrow) * LROW + kq * 8];
    #pragma unroll
    for (int mt = 0; mt < 4; ++mt)
      #pragma unroll
      for (int nt = 0; nt < 4; ++nt)
        acc[mt][nt] = __builtin_amdgcn_mfma_f32_16x16x32_bf16(af[mt], bf[nt], acc[mt][nt], 0, 0, 0);
  }
  #pragma unroll
  for (int mt = 0; mt < 4; ++mt)
    #pragma unroll
    for (int nt = 0; nt < 4; ++nt) {
      int n_g = bn + wn + nt * 16 + (lane & 15);
      #pragma unroll
      for (int r = 0; r < 4; ++r) {
        int m_g = bm + wm + mt * 16 + kq * 4 + r;
        C[(size_t)m_g * 2048 + n_g] = f2bfu(acc[mt][nt][r]);
      }
    }
}

// ---- 64x64 bf16 NT GEMM ---------------------------------------------------
template <int EPI>
__launch_bounds__(256)
__global__ void gemm_bf16_nt64(const ushort_t* __restrict__ A, const ushort_t* __restrict__ B,
                               const float* __restrict__ bias, float* __restrict__ C32,
                               ushort_t* __restrict__ C16, int M, int N, int Kd) {
  __shared__ ushort_t As[64 * LROW];
  __shared__ ushort_t Bs[64 * LROW];
  int tid = threadIdx.x;
  int bm = blockIdx.y * 64, bn = blockIdx.x * 64;
  int wave = tid >> 6, lane = tid & 63;
  int wm = (wave >> 1) * 32, wn = (wave & 1) * 32;
  int mrow = lane & 15, kq = lane >> 4;
  int srow = tid >> 2, skof = (tid & 3) * 8;

  f32x4 acc[2][2];
  #pragma unroll
  for (int i = 0; i < 2; ++i)
    #pragma unroll
    for (int j = 0; j < 2; ++j)
      #pragma unroll
      for (int r = 0; r < 4; ++r) acc[i][j][r] = 0.f;

  for (int k0 = 0; k0 < Kd; k0 += 32) {
    uint4 a0 = *(const uint4*)(A + (size_t)(bm + srow) * Kd + k0 + skof);
    uint4 b0 = *(const uint4*)(B + (size_t)(bn + srow) * Kd + k0 + skof);
    __syncthreads();
    *(uint4*)&As[srow * LROW + skof] = a0;
    *(uint4*)&Bs[srow * LROW + skof] = b0;
    __syncthreads();
    bf16x8 af[2], bf[2];
    #pragma unroll
    for (int mt = 0; mt < 2; ++mt)
      af[mt] = *(const bf16x8*)&As[(wm + mt * 16 + mrow) * LROW + kq * 8];
    #pragma unroll
    for (int nt = 0; nt < 2; ++nt)
      bf[nt] = *(const bf16x8*)&Bs[(wn + nt * 16 + mrow) * LROW + kq * 8];
    #pragma unroll
    for (int mt = 0; mt < 2; ++mt)
      #pragma unroll
      for (int nt = 0; nt < 2; ++nt)
        acc[mt][nt] = __builtin_amdgcn_mfma_f32_16x16x32_bf16(af[mt], bf[nt], acc[mt][nt], 0, 0, 0);
  }
  #pragma unroll
  for (int mt = 0; mt < 2; ++mt)
    #pragma unroll
    for (int nt = 0; nt < 2; ++nt) {
      int n_g = bn + wn + nt * 16 + (lane & 15);
      #pragma unroll
      for (int r = 0; r < 4; ++r) {
        int m_g = bm + wm + mt * 16 + kq * 4 + r;
        float v = acc[mt][nt][r];
        if (bias) v += bias[n_g];
        if (EPI == EPI_LEAKY) v = LEAKY(v);
        else if (EPI == EPI_LEAKY_BN) { v = LEAKY(v); v *= BN_SCALE; }
        else if (EPI == EPI_TANH) v = tanhf(v);
        if (C32) C32[(size_t)m_g * N + n_g] = v;
        if (C16) C16[(size_t)m_g * N + n_g] = f2bfu(v);
      }
    }
}

// ---- 64x64 NT GEMM, dual weight/bias selected by M-half -------------------
template <int EPI>
__launch_bounds__(256)
__global__ void gemm_nt64_dual(const ushort_t* __restrict__ A, const ushort_t* __restrict__ B1,
                               const ushort_t* __restrict__ B2, const float* __restrict__ bias1,
                               const float* __restrict__ bias2, ushort_t* __restrict__ C16,
                               int M, int N, int Kd, int Msplit) {
  __shared__ ushort_t As[64 * LROW];
  __shared__ ushort_t Bs[64 * LROW];
  int tid = threadIdx.x;
  int bm = blockIdx.y * 64, bn = blockIdx.x * 64;
  const ushort_t* B = (bm < Msplit) ? B1 : B2;
  const float* bias = (bm < Msplit) ? bias1 : bias2;
  int wave = tid >> 6, lane = tid & 63;
  int wm = (wave >> 1) * 32, wn = (wave & 1) * 32;
  int mrow = lane & 15, kq = lane >> 4;
  int srow = tid >> 2, skof = (tid & 3) * 8;

  f32x4 acc[2][2];
  #pragma unroll
  for (int i = 0; i < 2; ++i)
    #pragma unroll
    for (int j = 0; j < 2; ++j)
      #pragma unroll
      for (int r = 0; r < 4; ++r) acc[i][j][r] = 0.f;

  for (int k0 = 0; k0 < Kd; k0 += 32) {
    uint4 a0 = *(const uint4*)(A + (size_t)(bm + srow) * Kd + k0 + skof);
    uint4 b0 = *(const uint4*)(B + (size_t)(bn + srow) * Kd + k0 + skof);
    __syncthreads();
    *(uint4*)&As[srow * LROW + skof] = a0;
    *(uint4*)&Bs[srow * LROW + skof] = b0;
    __syncthreads();
    bf16x8 af[2], bf[2];
    #pragma unroll
    for (int mt = 0; mt < 2; ++mt)
      af[mt] = *(const bf16x8*)&As[(wm + mt * 16 + mrow) * LROW + kq * 8];
    #pragma unroll
    for (int nt = 0; nt < 2; ++nt)
      bf[nt] = *(const bf16x8*)&Bs[(wn + nt * 16 + mrow) * LROW + kq * 8];
    #pragma unroll
    for (int mt = 0; mt < 2; ++mt)
      #pragma unroll
      for (int nt = 0; nt < 2; ++nt)
        acc[mt][nt] = __builtin_amdgcn_mfma_f32_16x16x32_bf16(af[mt], bf[nt], acc[mt][nt], 0, 0, 0);
  }
  #pragma unroll
  for (int mt = 0; mt < 2; ++mt)
    #pragma unroll
    for (int nt = 0; nt < 2; ++nt) {
      int n_g = bn + wn + nt * 16 + (lane & 15);
      #pragma unroll
      for (int r = 0; r < 4; ++r) {
        int m_g = bm + wm + mt * 16 + kq * 4 + r;
        float v = acc[mt][nt][r] + bias[n_g];
        if (EPI == EPI_LEAKY) v = LEAKY(v);
        else if (EPI == EPI_LEAKY_BN) { v = LEAKY(v); v *= BN_SCALE; }
        C16[(size_t)m_g * N + n_g] = f2bfu(v);
      }
    }
}

// ---- 64x64 NT GEMM with column-split epilogue (EPI1 for n<Nsplit) ---------
template <int EPI1, int EPI2>
__launch_bounds__(256)
__global__ void gemm_nt64_split(const ushort_t* __restrict__ A, const ushort_t* __restrict__ B,
                                const float* __restrict__ biasPk, float* __restrict__ C32,
                                ushort_t* __restrict__ C16, int M, int N, int Kd, int Nsplit) {
  __shared__ ushort_t As[64 * LROW];
  __shared__ ushort_t Bs[64 * LROW];
  int tid = threadIdx.x;
  int bm = blockIdx.y * 64, bn = blockIdx.x * 64;
  int wave = tid >> 6, lane = tid & 63;
  int wm = (wave >> 1) * 32, wn = (wave & 1) * 32;
  int mrow = lane & 15, kq = lane >> 4;
  int srow = tid >> 2, skof = (tid & 3) * 8;

  f32x4 acc[2][2];
  #pragma unroll
  for (int i = 0; i < 2; ++i)
    #pragma unroll
    for (int j = 0; j < 2; ++j)
      #pragma unroll
      for (int r = 0; r < 4; ++r) acc[i][j][r] = 0.f;

  for (int k0 = 0; k0 < Kd; k0 += 32) {
    uint4 a0 = *(const uint4*)(A + (size_t)(bm + srow) * Kd + k0 + skof);
    uint4 b0 = *(const uint4*)(B + (size_t)(bn + srow) * Kd + k0 + skof);
    __syncthreads();
    *(uint4*)&As[srow * LROW + skof] = a0;
    *(uint4*)&Bs[srow * LROW + skof] = b0;
    __syncthreads();
    bf16x8 af[2], bf[2];
    #pragma unroll
    for (int mt = 0; mt < 2; ++mt)
      af[mt] = *(const bf16x8*)&As[(wm + mt * 16 + mrow) * LROW + kq * 8];
    #pragma unroll
    for (int nt = 0; nt < 2; ++nt)
      bf[nt] = *(const bf16x8*)&Bs[(wn + nt * 16 + mrow) * LROW + kq * 8];
    #pragma unroll
    for (int mt = 0; mt < 2; ++mt)
      #pragma unroll
      for (int nt = 0; nt < 2; ++nt)
        acc[mt][nt] = __builtin_amdgcn_mfma_f32_16x16x32_bf16(af[mt], bf[nt], acc[mt][nt], 0, 0, 0);
  }
  #pragma unroll
  for (int mt = 0; mt < 2; ++mt)
    #pragma unroll
    for (int nt = 0; nt < 2; ++nt) {
      int n_g = bn + wn + nt * 16 + (lane & 15);
      #pragma unroll
      for (int r = 0; r < 4; ++r) {
        int m_g = bm + wm + mt * 16 + kq * 4 + r;
        float v = acc[mt][nt][r] + biasPk[n_g];
        if (n_g < Nsplit) {
          if (EPI1 == EPI_LEAKY) v = LEAKY(v);
          else if (EPI1 == EPI_TANH) v = tanhf(v);
        } else {
          if (EPI2 == EPI_LEAKY) v = LEAKY(v);
          else if (EPI2 == EPI_TANH) v = tanhf(v);
        }
        if (C32) C32[(size_t)m_g * N + n_g] = v;
        if (C16) C16[(size_t)m_g * N + n_g] = f2bfu(v);
      }
    }
}

// ---- 128x128 bf16 NN GEMM + bf16 residual (skip3) -------------------------
__launch_bounds__(256)
__global__ void gemm_bf16_nn_res(const ushort_t* __restrict__ A, const ushort_t* __restrict__ B,
                                 const ushort_t* __restrict__ R, ushort_t* __restrict__ C16,
                                 int M, int N, int Kd) {
  __shared__ ushort_t As[128 * LROW];
  __shared__ ushort_t Bs[128 * LROW];
  int tid = threadIdx.x;
  int bm = blockIdx.y * 128, bn = blockIdx.x * 128;
  int wave = tid >> 6, lane = tid & 63;
  int wm = (wave >> 1) * 64, wn = (wave & 1) * 64;
  int mrow = lane & 15, kq = lane >> 4;
  int srow = tid >> 1, skof = (tid & 1) * 16;
  int krow = tid >> 3, nof = (tid & 7) * 16;

  f32x4 acc[4][4];
  #pragma unroll
  for (int i = 0; i < 4; ++i)
    #pragma unroll
    for (int j = 0; j < 4; ++j)
      #pragma unroll
      for (int r = 0; r < 4; ++r) acc[i][j][r] = 0.f;

  for (int k0 = 0; k0 < Kd; k0 += 32) {
    const uint4* ap = (const uint4*)(A + (size_t)(bm + srow) * Kd + k0 + skof);
    uint4 a0 = ap[0], a1 = ap[1];
    ushort_t bb[16];
    *(uint4*)&bb[0] = *(const uint4*)(B + (size_t)(k0 + krow) * N + bn + nof);
    *(uint4*)&bb[8] = *(const uint4*)(B + (size_t)(k0 + krow) * N + bn + nof + 8);
    __syncthreads();
    *(uint4*)&As[srow * LROW + skof] = a0;
    *(uint4*)&As[srow * LROW + skof + 8] = a1;
    #pragma unroll
    for (int j = 0; j < 16; ++j)
      Bs[(nof + j) * LROW + krow] = bb[j];
    __syncthreads();
    bf16x8 af[4], bf[4];
    #pragma unroll
    for (int mt = 0; mt < 4; ++mt)
      af[mt] = *(const bf16x8*)&As[(wm + mt * 16 + mrow) * LROW + kq * 8];
    #pragma unroll
    for (int nt = 0; nt < 4; ++nt)
      bf[nt] = *(const bf16x8*)&Bs[(wn + nt * 16 + mrow) * LROW + kq * 8];
    #pragma unroll
    for (int mt = 0; mt < 4; ++mt)
      #pragma unroll
      for (int nt = 0; nt < 4; ++nt)
        acc[mt][nt] = __builtin_amdgcn_mfma_f32_16x16x32_bf16(af[mt], bf[nt], acc[mt][nt], 0, 0, 0);
  }
  #pragma unroll
  for (int mt = 0; mt < 4; ++mt)
    #pragma unroll
    for (int nt = 0; nt < 4; ++nt) {
      int n_g = bn + wn + nt * 16 + (lane & 15);
      #pragma unroll
      for (int r = 0; r < 4; ++r) {
        int m_g = bm + wm + mt * 16 + kq * 4 + r;
        float v = acc[mt][nt][r] + bfu2f(R[(size_t)m_g * N + n_g]);
        C16[(size_t)m_g * N + n_g] = f2bfu(v);
      }
    }
}

// ---- 64x64 NN GEMM + residual, z over both skip branches ------------------
// A = Smat_z [2048x2048], B = X3sb_z [2048x256], R = dt_z, C = XsKs_z.
__launch_bounds__(256)
__global__ void gemm_nn_res64_z(const ushort_t* __restrict__ SmatBase,
                                const ushort_t* __restrict__ X3sb,
                                const ushort_t* __restrict__ dtb,
                                ushort_t* __restrict__ XsKs) {
  int z = blockIdx.z;
  const ushort_t* A = SmatBase + (size_t)z * 2048 * 2048;
  const ushort_t* B = X3sb + (size_t)z * 2048 * 256;
  const ushort_t* R = dtb + (size_t)z * 2048 * 256;
  ushort_t* C = XsKs + (size_t)z * 2048 * 256;
  const int N = 256, Kd = 2048;
  __shared__ ushort_t As[64 * LROW];
  __shared__ ushort_t Bs[64 * LROW];
  int tid = threadIdx.x;
  int bm = blockIdx.y * 64, bn = blockIdx.x * 64;
  int wave = tid >> 6, lane = tid & 63;
  int wm = (wave >> 1) * 32, wn = (wave & 1) * 32;
  int mrow = lane & 15, kq = lane >> 4;
  int srow = tid >> 2, skof = (tid & 3) * 8;
  int krow = tid >> 3, nof = (tid & 7) * 8;

  f32x4 acc[2][2];
  #pragma unroll
  for (int i = 0; i < 2; ++i)
    #pragma unroll
    for (int j = 0; j < 2; ++j)
      #pragma unroll
      for (int r = 0; r < 4; ++r) acc[i][j][r] = 0.f;

  for (int k0 = 0; k0 < Kd; k0 += 32) {
    uint4 a0 = *(const uint4*)(A + (size_t)(bm + srow) * Kd + k0 + skof);
    ushort_t bb[8];
    *(uint4*)&bb[0] = *(const uint4*)(B + (size_t)(k0 + krow) * N + bn + nof);
    __syncthreads();
    *(uint4*)&As[srow * LROW + skof] = a0;
    #pragma unroll
    for (int j = 0; j < 8; ++j)
      Bs[(nof + j) * LROW + krow] = bb[j];
    __syncthreads();
    bf16x8 af[2], bf[2];
    #pragma unroll
    for (int mt = 0; mt < 2; ++mt)
      af[mt] = *(const bf16x8*)&As[(wm + mt * 16 + mrow) * LROW + kq * 8];
    #pragma unroll
    for (int nt = 0; nt < 2; ++nt)
      bf[nt] = *(const bf16x8*)&Bs[(wn + nt * 16 + mrow) * LROW + kq * 8];
    #pragma unroll
    for (int mt = 0; mt < 2; ++mt)
      #pragma unroll
      for (int nt = 0; nt < 2; ++nt)
        acc[mt][nt] = __builtin_amdgcn_mfma_f32_16x16x32_bf16(af[mt], bf[nt], acc[mt][nt], 0, 0, 0);
  }
  #pragma unroll
  for (int mt = 0; mt < 2; ++mt)
    #pragma unroll
    for (int nt = 0; nt < 2; ++nt) {
      int n_g = bn + wn + nt * 16 + (lane & 15);
      #pragma unroll
      for (int r = 0; r < 4; ++r) {
        int m_g = bm + wm + mt * 16 + kq * 4 + r;
        float v = acc[mt][nt][r] + bfu2f(R[(size_t)m_g * N + n_g]);
        C[(size_t)m_g * N + n_g] = f2bfu(v);
      }
    }
}

// ---- split-K TN GEMM: Mm = X12m[:, :128]^T @ X12m[:, 128:] ----------------
__global__ void gemm_tn_part(const ushort_t* __restrict__ X, float* __restrict__ part) {
  int tx = threadIdx.x & 15, ty = threadIdx.x >> 4;
  int i = blockIdx.y * 16 + ty, j = blockIdx.x * 16 + tx;
  int ks = blockIdx.z;
  float acc = 0.f;
  for (int k = ks * 128; k < ks * 128 + 128; ++k)
    acc += bfu2f(X[(size_t)k * 256 + i]) * bfu2f(X[(size_t)k * 256 + 128 + j]);
  part[(size_t)ks * 16384 + i * 128 + j] = acc;
}
__global__ void gemm_tn_reduce(const float* __restrict__ part, ushort_t* __restrict__ Mm) {
  int idx = blockIdx.x * 256 + threadIdx.x;
  float s = 0.f;
  #pragma unroll
  for (int ks = 0; ks < 16; ++ks) s += part[(size_t)ks * 16384 + idx];
  Mm[idx] = f2bfu(s);
}

// ---- 3-stage column softmax with z over matrices --------------------------
__global__ void smax_partA(const ushort_t* __restrict__ Sb, float* __restrict__ pm,
                           float* __restrict__ pl, int N) {
  int z = blockIdx.z;
  const ushort_t* S = Sb + (size_t)z * 2048 * 2048;
  int t = threadIdx.x;
  int col = blockIdx.x * 64 + (t & 63);
  int g = t >> 6;
  int r0 = blockIdx.y * 128 + g;
  float vals[32];
  #pragma unroll
  for (int i = 0; i < 32; ++i)
    vals[i] = bfu2f(S[(size_t)(r0 + 4 * i) * N + col]);
  float m = -1e30f;
  #pragma unroll
  for (int i = 0; i < 32; ++i) m = fmaxf(m, vals[i]);
  float l = 0.f;
  #pragma unroll
  for (int i = 0; i < 32; ++i) l += expf(vals[i] - m);
  __shared__ float rm[4][64], rl[4][64];
  rm[g][t & 63] = m; rl[g][t & 63] = l;
  __syncthreads();
  if (g == 0) {
    int c = t & 63;
    float M0 = rm[0][c], L0 = rl[0][c];
    #pragma unroll
    for (int j = 1; j < 4; ++j) {
      float Mj = rm[j][c], Lj = rl[j][c];
      float nm = fmaxf(M0, Mj);
      L0 = L0 * expf(M0 - nm) + Lj * expf(Mj - nm);
      M0 = nm;
    }
    pm[((size_t)z * 16 + blockIdx.y) * N + col] = M0;
    pl[((size_t)z * 16 + blockIdx.y) * N + col] = L0;
  }
}
__global__ void smax_partB(const float* __restrict__ pm, const float* __restrict__ pl,
                           float* __restrict__ gm, float* __restrict__ gi, int N) {
  int z = blockIdx.y;
  int col = blockIdx.x * 256 + threadIdx.x;
  float m = -1e30f, l = 0.f;
  for (int b = 0; b < 16; ++b) {
    float bm = pm[((size_t)z * 16 + b) * N + col], bl = pl[((size_t)z * 16 + b) * N + col];
    float nm = fmaxf(m, bm);
    l = l * expf(m - nm) + bl * expf(bm - nm);
    m = nm;
  }
  gm[(size_t)z * N + col] = m;
  gi[(size_t)z * N + col] = 1.f / l;
}
__global__ void smax_partC(ushort_t* __restrict__ Sb, const float* __restrict__ gm,
                           const float* __restrict__ gi, int N) {
  int z = blockIdx.z;
  ushort_t* S = Sb + (size_t)z * 2048 * 2048;
  int t = threadIdx.x;
  int col = blockIdx.x * 64 + (t & 63);
  int g = t >> 6;
  float m = gm[(size_t)z * N + col], inv = gi[(size_t)z * N + col];
  int r0 = blockIdx.y * 128 + g;
  #pragma unroll 8
  for (int i = 0; i < 32; ++i) {
    size_t idx = (size_t)(r0 + 4 * i) * N + col;
    S[idx] = f2bfu(expf(bfu2f(S[idx]) - m) * inv);
  }
}

// ---- row squared-norms from bf16 ------------------------------------------
__global__ void row_norm_bf16(const ushort_t* __restrict__ X, float* __restrict__ out, int Kd) {
  int r = blockIdx.x;
  int t = threadIdx.x;
  float s = 0.f;
  for (int k = t; k < Kd; k += 64) { float v = bfu2f(X[(size_t)r * Kd + k]); s += v * v; }
  for (int off = 32; off; off >>= 1) s += __shfl_down(s, off);
  if (t == 0) out[r] = s;
}

// ---- mask scores ----------------------------------------------------------
__global__ void mask_score(const float* __restrict__ A3, const float* __restrict__ w4,
                           const float* __restrict__ b4, float* __restrict__ s) {
  int k = blockIdx.x * 256 + threadIdx.x;
  float acc = b4[0];
  for (int h = 0; h < 128; ++h) acc += A3[(size_t)h * 2048 + k] * w4[h];
  s[k] = acc;
}

// ---- stable descending-argsort rank via LDS-staged scores -----------------
__global__ void topk_rank(const float* __restrict__ s, int* __restrict__ idx, int K, int S) {
  __shared__ float sv[2048];
  int t = threadIdx.x;
  for (int i = t; i < K; i += 256) sv[i] = s[i];
  __syncthreads();
  int j = blockIdx.x * 256 + t;
  if (j >= K) return;
  float sj = sv[j];
  int rank = 0;
  #pragma unroll 8
  for (int i = 0; i < 2048; ++i) {
    float si = sv[i];
    rank += (si > sj) || (si == sj && i < j);
  }
  if (rank < S) idx[rank] = j;
}

// ---- build cat = [B_dt | softmax(aff_s[:,idx],axis=1) | 0pad], bf16 -------
__global__ void build_cat(const ushort_t* __restrict__ Bdt, const ushort_t* __restrict__ affs,
                          const int* __restrict__ idx, ushort_t* __restrict__ cat) {
  int r = blockIdx.x, t = threadIdx.x;
  __shared__ float vals[256];
  __shared__ float red[256];
  float v = -1e30f;
  if (t < 204) {
    int ix = idx[t];
    ix = ix < 0 ? 0 : (ix > 2047 ? 2047 : ix);
    v = bfu2f(affs[(size_t)r * 2048 + ix]);
  }
  vals[t] = v;
  red[t] = v;
  __syncthreads();
  for (int off = 128; off; off >>= 1) { if (t < off) red[t] = fmaxf(red[t], red[t + off]); __syncthreads(); }
  float m = red[0];
  __syncthreads();
  float e = (t < 204) ? expf(vals[t] - m) : 0.f;
  red[t] = e;
  __syncthreads();
  for (int off = 128; off; off >>= 1) { if (t < off) red[t] += red[t + off]; __syncthreads(); }
  float inv = 1.f / red[0];
  cat[(size_t)r * 512 + t] = Bdt[(size_t)r * 256 + t];
  cat[(size_t)r * 512 + 256 + t] = (t < 204) ? f2bfu(e * inv) : (ushort_t)0;
}

// ---- a = leaky((AV*AU) @ aww.T + awb), AVU combined [2048,256] ------------
__global__ void attn_gate(const float* __restrict__ AVU, const float* __restrict__ aww,
                          const float* __restrict__ awb, float* __restrict__ a, int n) {
  int wave = threadIdx.x >> 6, lane = threadIdx.x & 63;
  int r = blockIdx.x * 4 + wave;
  if (r >= n) return;
  float s = 0.f;
  #pragma unroll
  for (int j = 0; j < 2; ++j) {
    int d = lane + 64 * j;
    s += AVU[(size_t)r * 256 + d] * AVU[(size_t)r * 256 + 128 + d] * aww[d];
  }
  for (int off = 32; off; off >>= 1) s += __shfl_down(s, off);
  if (lane == 0) {
    float acc = s + awb[0];
    a[r] = LEAKY(acc);
  }
}

// ---- 1-D softmax (single block) -------------------------------------------
__global__ void softmax_vec(const float* __restrict__ x, float* __restrict__ y,
                            float* __restrict__ y2, int n) {
  __shared__ float red[256];
  int t = threadIdx.x;
  float m = -1e30f;
  for (int i = t; i < n; i += 256) m = fmaxf(m, x[i]);
  red[t] = m;
  __syncthreads();
  for (int off = 128; off; off >>= 1) { if (t < off) red[t] = fmaxf(red[t], red[t + off]); __syncthreads(); }
  m = red[0];
  __syncthreads();
  float s = 0.f;
  for (int i = t; i < n; i += 256) s += expf(x[i] - m);
  red[t] = s;
  __syncthreads();
  for (int off = 128; off; off >>= 1) { if (t < off) red[t] += red[t + off]; __syncthreads(); }
  float inv = 1.f / red[0];
  for (int i = t; i < n; i += 256) {
    float v = expf(x[i] - m) * inv;
    y[i] = v;
    if (y2) y2[i] = v;
  }
}

// ---- weighted column sum over bf16 H, two-stage ---------------------------
__global__ void colsum_part(const float* __restrict__ wv, const ushort_t* __restrict__ H,
                            float* __restrict__ part, int n) {
  int bk = blockIdx.x, c = threadIdx.x;
  float s = 0.f;
  for (int r = bk; r < n; r += 16) s += wv[r] * bfu2f(H[(size_t)r * 256 + c]);
  part[bk * 256 + c] = s;
}
__global__ void colsum_fin(const float* __restrict__ part, float* __restrict__ out) {
  int c = threadIdx.x;
  float s = 0.f;
  #pragma unroll
  for (int k = 0; k < 16; ++k) s += part[k * 256 + c];
  out[c] = s;
}

// ---- small gemv -----------------------------------------------------------
__global__ void gemv_act(const float* __restrict__ x, const float* __restrict__ W,
                         const float* __restrict__ b, float* __restrict__ out,
                         int O, int Kd, int act) {
  int o = blockIdx.x * blockDim.x + threadIdx.x;
  if (o >= O) return;
  float acc = b ? b[o] : 0.f;
  for (int k = 0; k < Kd; ++k) acc += x[k] * W[(size_t)o * Kd + k];
  if (act == 1) acc = LEAKY(acc);
  out[o] = acc;
}

// ---- cat2 = [B_fuse | tile(M1)], bf16 -------------------------------------
__global__ void build_cat2(const ushort_t* __restrict__ Bf, const float* __restrict__ M1,
                           ushort_t* __restrict__ cat2) {
  int r = blockIdx.x, t = threadIdx.x;
  cat2[(size_t)r * 512 + t] = (t < 256) ? Bf[(size_t)r * 256 + t] : f2bfu(M1[t - 256]);
}

// ---- final head -----------------------------------------------------------
__global__ void final_head(const float* __restrict__ AH2, const float* __restrict__ embw,
                           const float* __restrict__ embb, const float* __restrict__ sembw,
                           const float* __restrict__ sembb, const float* __restrict__ clsw,
                           const float* __restrict__ clsb, float* __restrict__ Yout) {
  __shared__ float bvec[512];
  __shared__ float red[512];
  int t = threadIdx.x;
  float acc = embb[t];
  for (int c = 0; c < 256; ++c) acc += AH2[c] * embw[(size_t)t * 256 + c];
  bvec[t] = LEAKY(acc);
  __syncthreads();
  float p = 0.f;
  if (t < 256) {
    float a2 = sembb[t];
    for (int c = 0; c < 512; ++c) a2 += bvec[c] * sembw[(size_t)t * 512 + c];
    a2 = LEAKY(a2);
    p = a2 * clsw[t];
  }
  red[t] = p;
  __syncthreads();
  for (int off = 256; off; off >>= 1) { if (t < off) red[t] += red[t + off]; __syncthreads(); }
  if (t == 0) {
    float y = red[0] + clsb[0];
    y = 1.f / (1.f + expf(-y));
    y = fminf(fmaxf(y, 1e-5f), 1.f - 1e-5f);
    Yout[0] = y;
  }
}

extern "C" void kernel_launch(void* const* d_in, const int* in_sizes, int n_in,
                              void* d_out, int out_size, void* d_ws, size_t ws_size,
                              hipStream_t stream) {
  auto IN = [&](int i) { return (const float*)d_in[i]; };
  (void)n_in; (void)in_sizes; (void)out_size;

  const int S = 204;
  float* out_f = (float*)d_out;

  float* W = (float*)d_ws;
  size_t off = 0;
  auto F = [&](size_t n) { float* p = W + off; off += n; return p; };
  auto FU = [&](size_t nus) { return (ushort_t*)F((nus + 1) / 2); };

  ushort_t* dt_b  = FU((size_t)4096 * 256);   // B_dt | KB_dt
  ushort_t* XsKs  = FU((size_t)4096 * 256);   // Xs | Ks
  ushort_t* X12b  = FU((size_t)4096 * 256);   // skip12 X1|X2 (also skip3 X12, mask X12m)
  ushort_t* X3sb  = FU((size_t)4096 * 256);   // skip12 X3 both halves
  ushort_t* aff_b = FU((size_t)2048 * 2048);
  float* AVU   = F((size_t)2048 * 256);
  ushort_t* Mm_b = FU((size_t)128 * 128);
  float* svec  = F(2048);
  int*   idxb  = (int*)F(256);
  float* avec  = F(2048);
  float* Awv   = F(2048);
  float* AH    = F(256);
  float* M1v   = F(256);
  float* AH2   = F(256);
  float* nxy   = F(4096);
  float* part  = F(4096);
  float* sm_pm = F((size_t)2 * 16 * 2048);
  float* sm_pl = F((size_t)2 * 16 * 2048);
  float* sm_gm = F(2 * 2048);
  float* sm_gi = F(2 * 2048);
  float* pbias = F(6 * 256);                  // packed: sk1, sk2, sk3, mask, a1vu, a2vu

  // bf16 weight arena (pairs that must be contiguous are allocated adjacently)
  size_t wo = 0;
  ushort_t* warena = (ushort_t*)F(3227872);
  auto WA = [&](size_t n) { ushort_t* p = warena + wo; wo = (wo + n + 15) & ~(size_t)15; return p; };
  ushort_t* w2b   = WA(25000);
  ushort_t* embb_ = WA(204800);
  ushort_t* s1w1 = WA(32768); ushort_t* s1w2 = WA(32768); ushort_t* s1w3 = WA(65536);
  ushort_t* s2w1 = WA(32768); ushort_t* s2w2 = WA(32768); ushort_t* s2w3 = WA(65536);
  ushort_t* s3w1 = WA(262144); ushort_t* s3w2 = WA(262144); ushort_t* s3w3 = WA(4194304);
  ushort_t* mw1 = WA(262144); ushort_t* mw2 = WA(262144); ushort_t* mw3 = WA(262144);
  ushort_t* fwp = WA(131072);
  ushort_t* a1fe = WA(65536); ushort_t* a1v = WA(32768); ushort_t* a1u = WA(32768);
  ushort_t* a2fe = WA(131072); ushort_t* a2v = WA(32768); ushort_t* a2u = WA(32768);
  (void)s1w2; (void)s2w2; (void)s3w2; (void)mw2; (void)a1u; (void)a2u;

  float* pool = F((size_t)4194304);           // 16 MB phase-shared

  const size_t NEED_BYTES = off * 4;
  if (ws_size < NEED_BYTES) {
    fill_out<<<9, 256, 0, stream>>>(out_f, 2049);
    return;
  }

  // pool phases
  ushort_t* h2h_b   = (ushort_t*)pool;               // conv: 4096*800 us
  ushort_t* SmatB   = (ushort_t*)pool;               // skip12: 2 x 2048^2 us (16MB); skip3 uses z=0 half
  ushort_t* X3b_b   = (ushort_t*)(pool + 2097152);   // skip3: 2048*2048 us
  float* A3   = pool;                                // mask: 128*2048 f
  float* tnpt = pool + 262144;                       // mask: 16*16384 f
  ushort_t* cat_b   = (ushort_t*)pool;               // fuse: 2048*512 us
  ushort_t* cat2_b  = (ushort_t*)(pool + 524288);
  ushort_t* Bfuse_b = (ushort_t*)(pool + 1048576);
  ushort_t* Hbuf_b  = (ushort_t*)(pool + 1310720);

  // ---- weight conversion + packing ----
  CvtArgs ca;
  const float* srcs[20] = { IN(4), IN(6), IN(8), IN(10), IN(12), IN(14), IN(16), IN(18),
                            IN(20), IN(22), IN(24), IN(26), IN(28), IN(30),
                            IN(36), IN(38), IN(40), IN(46), IN(48), IN(50) };
  ushort_t* dsts[20] = { w2b, embb_, s1w1, s1w2, s1w3, s2w1, s2w2, s2w3,
                         s3w1, s3w2, s3w3, mw1, mw2, mw3,
                         a1fe, a1v, a1u, a2fe, a2v, a2u };
  int lens[20] = { 25000, 204800, 32768, 32768, 65536, 32768, 32768, 65536,
                   262144, 262144, 4194304, 262144, 262144, 262144,
                   65536, 32768, 32768, 131072, 32768, 32768 };
  for (int i = 0; i < 20; ++i) { ca.src[i] = srcs[i]; ca.dst[i] = dsts[i]; ca.len[i] = lens[i]; }
  to_bf16_multi<<<1024, 256, 0, stream>>>(ca);
  pad_fuse_bf16<<<512, 256, 0, stream>>>(IN(34), fwp);
  BiasPk bp;
  const float* bsrc[12] = { IN(9), IN(11), IN(15), IN(17), IN(21), IN(23),
                            IN(27), IN(29), IN(39), IN(41), IN(49), IN(51) };
  for (int i = 0; i < 12; ++i) bp.a[i] = bsrc[i];
  bp.out = pbias;
  bias_pack<<<6, 256, 0, stream>>>(bp);
  float* pb_sk1 = pbias, *pb_sk2 = pbias + 256, *pb_sk3 = pbias + 512;
  float* pb_msk = pbias + 768, *pb_a1 = pbias + 1024, *pb_a2 = pbias + 1280;

  // ---- conv + embedding for B and KB in single dispatches ----
  conv12_mfma<<<2048, 256, 0, stream>>>(IN(0), IN(1), IN(2), IN(3), w2b, IN(5), h2h_b);
  gemm_bf16_nt64<EPI_LEAKY><<<dim3(4, 64), 256, 0, stream>>>(
      h2h_b, embb_, IN(7), nullptr, dt_b, 4096, 256, 800);

  // ---- skip1+skip2, both branches fused ----
  gemm_nt64_dual<EPI_LEAKY_BN><<<dim3(4, 64), 256, 0, stream>>>(
      dt_b, s1w1, s2w1, pb_sk1, pb_sk2, X12b, 4096, 256, 256, 2048);
  gemm_nt64_dual<EPI_LEAKY_BN><<<dim3(4, 64), 256, 0, stream>>>(
      dt_b, s1w3, s2w3, IN(13), IN(19), X3sb, 4096, 256, 256, 2048);
  gemm_smat_z<<<dim3(16, 16, 2), 256, 0, stream>>>(X12b, SmatB);
  smax_partA<<<dim3(32, 16, 2), 256, 0, stream>>>(SmatB, sm_pm, sm_pl, 2048);
  smax_partB<<<dim3(8, 2), 256, 0, stream>>>(sm_pm, sm_pl, sm_gm, sm_gi, 2048);
  smax_partC<<<dim3(32, 16, 2), 256, 0, stream>>>(SmatB, sm_gm, sm_gi, 2048);
  gemm_nn_res64_z<<<dim3(4, 32, 2), 256, 0, stream>>>(SmatB, X3sb, dt_b, XsKs);

  // ---- euclid -> aff_b ----
  row_norm_bf16<<<4096, 64, 0, stream>>>(XsKs, nxy, 256);
  gemm_bf16_nt<EPI_EUCLID><<<dim3(16, 16), 256, 0, stream>>>(
      XsKs, XsKs + (size_t)2048 * 256, nullptr, nullptr, aff_b, 2048, 2048, 256,
      nxy, nxy + 2048);

  // ---- skip3 (aff in-place) ----
  gemm_bf16_nt64<EPI_LEAKY_BN><<<dim3(4, 32), 256, 0, stream>>>(
      aff_b, s3w1, pb_sk3, nullptr, X12b, 2048, 256, 2048);
  gemm_smat_z<<<dim3(16, 16, 1), 256, 0, stream>>>(X12b, SmatB);
  gemm_bf16_nt<EPI_LEAKY_BN><<<dim3(16, 16), 256, 0, stream>>>(
      aff_b, s3w3, IN(25), nullptr, X3b_b, 2048, 2048, 2048, nullptr, nullptr);
  smax_partA<<<dim3(32, 16, 1), 256, 0, stream>>>(SmatB, sm_pm, sm_pl, 2048);
  smax_partB<<<dim3(8, 1), 256, 0, stream>>>(sm_pm, sm_pl, sm_gm, sm_gi, 2048);
  smax_partC<<<dim3(32, 16, 1), 256, 0, stream>>>(SmatB, sm_gm, sm_gi, 2048);
  gemm_bf16_nn_res<<<dim3(16, 16), 256, 0, stream>>>(SmatB, X3b_b, aff_b, aff_b, 2048, 2048, 2048);
  ushort_t* affs_b = aff_b;

  // ---- mask_scores -> top-S idx ----
  gemm_nt64_split<EPI_LEAKY, EPI_TANH><<<dim3(4, 32), 256, 0, stream>>>(
      affs_b, mw1, pb_msk, nullptr, X12b, 2048, 256, 2048, 128);
  gemm_tn_part<<<dim3(8, 8, 16), 256, 0, stream>>>(X12b, tnpt);
  gemm_tn_reduce<<<64, 256, 0, stream>>>(tnpt, Mm_b);
  gemm_bf16_nt64<EPI_LEAKY><<<dim3(32, 2), 256, 0, stream>>>(
      Mm_b, mw3, IN(31), A3, nullptr, 128, 2048, 128);
  mask_score<<<8, 256, 0, stream>>>(A3, IN(32), IN(33), svec);
  topk_rank<<<8, 256, 0, stream>>>(svec, idxb, 2048, S);

  // ---- B_bag + concat + fuse ----
  build_cat<<<2048, 256, 0, stream>>>(dt_b, affs_b, idxb, cat_b);
  gemm_bf16_nt64<EPI_LEAKY><<<dim3(4, 32), 256, 0, stream>>>(
      cat_b, fwp, IN(35), nullptr, Bfuse_b, 2048, 256, 512);

  // ---- attention 1 ----
  gemm_bf16_nt64<EPI_LEAKY><<<dim3(4, 32), 256, 0, stream>>>(
      Bfuse_b, a1fe, IN(37), nullptr, Hbuf_b, 2048, 256, 256);
  gemm_nt64_split<EPI_TANH, EPI_LEAKY><<<dim3(4, 32), 256, 0, stream>>>(
      Hbuf_b, a1v, pb_a1, AVU, nullptr, 2048, 256, 256, 128);
  attn_gate<<<512, 256, 0, stream>>>(AVU, IN(42), IN(43), avec, 2048);
  softmax_vec<<<1, 256, 0, stream>>>(avec, Awv, nullptr, 2048);
  colsum_part<<<16, 256, 0, stream>>>(Awv, Hbuf_b, part, 2048);
  colsum_fin<<<1, 256, 0, stream>>>(part, AH);
  gemv_act<<<1, 256, 0, stream>>>(AH, IN(44), IN(45), M1v, 256, 256, 1);
  build_cat2<<<2048, 512, 0, stream>>>(Bfuse_b, M1v, cat2_b);

  // ---- attention 2 (A -> output) ----
  gemm_bf16_nt64<EPI_LEAKY><<<dim3(4, 32), 256, 0, stream>>>(
      cat2_b, a2fe, IN(47), nullptr, Hbuf_b, 2048, 256, 512);
  gemm_nt64_split<EPI_TANH, EPI_LEAKY><<<dim3(4, 32), 256, 0, stream>>>(
      Hbuf_b, a2v, pb_a2, AVU, nullptr, 2048, 256, 256, 128);
  attn_gate<<<512, 256, 0, stream>>>(AVU, IN(52), IN(53), avec, 2048);
  softmax_vec<<<1, 256, 0, stream>>>(avec, Awv, out_f + 1, 2048);
  colsum_part<<<16, 256, 0, stream>>>(Awv, Hbuf_b, part, 2048);
  colsum_fin<<<1, 256, 0, stream>>>(part, AH2);

  // ---- final head -> Y ----
  final_head<<<1, 512, 0, stream>>>(AH2, IN(54), IN(55), IN(56), IN(57),
                                    IN(58), IN(59), out_f);
}